// Round 13
// baseline (134.961 us; speedup 1.0000x reference)
//
#include <hip/hip_runtime.h>
#include <math.h>

#define NSHOT 5
#define WAY 32
#define DIM 640
#define NQ 4096
#define RNEAR 10

// ---- workspace layout (float offsets), ~1.07 MB ----
constexpr int OFF_PROTOS = 0;        // 32*640
constexpr int OFF_QPART  = 20480;    // 128*640 column partial sums (incl. shot fold)
constexpr int OFF_C      = 102400;   // 32
constexpr int OFF_BETA   = 102432;   // 32
constexpr int OFF_S      = 102464;   // 32
constexpr int OFF_U      = 102496;   // 32
constexpr int OFF_NID    = 102528;   // 32*10
constexpr int OFF_RR     = 102848;   // 32*22
constexpr int OFF_SPC    = 103552;   // 32
constexpr int OFF_H1P    = 103584;   // 32*128 (per-way pr·W1a)
constexpr int OFF_TP     = 107680;   // 32*640
constexpr int OFF_G      = 128160;   // 32*4096 raw dots
constexpr int OFF_NIDX   = 259232;   // 32*10 ints
constexpr int OFF_CNT    = 259552;   // 1 int
constexpr int OFF_Q2D    = 259556;   // double[4096] (even -> 8B aligned)
constexpr int OFF_X2D    = 267748;   // double[32] (proto_p norm^2)
constexpr int OFF_X2D2   = 267812;   // double[32] (test_proto norm^2)
constexpr int OFF_P2RAW  = 267876;   // double[32] (raw proto norm^2)

__device__ __forceinline__ double wave_sum_d(double v) {
#pragma unroll
  for (int o = 32; o > 0; o >>= 1) v += __shfl_down(v, o, 64);
  return v;
}

__device__ __forceinline__ float aloadf(const float* p) {
  return __hip_atomic_load(p, __ATOMIC_RELAXED, __HIP_MEMORY_SCOPE_AGENT);
}
__device__ __forceinline__ int aloadi(const int* p) {
  return __hip_atomic_load(p, __ATOMIC_RELAXED, __HIP_MEMORY_SCOPE_AGENT);
}

__device__ __forceinline__ double dist_hyp(double c, double xdotq, double u2, double q2) {
  const double EPSd = 1e-5;
  double sc = sqrt(c);
  double nq = sqrt(q2);
  double nf = fmax(nq, EPSd);
  double th = tanh(sc * nf);
  double al = th / (sc * nf);
  double ny = fmax(al * nq, EPSd);
  double mx = 0.999 / sc;
  if (ny > mx) al *= mx / ny;
  double y2 = al * al * q2;
  double uy = -al * xdotq;
  double A = 1.0 + 2.0 * c * uy + c * y2;
  double B = 1.0 - c * u2;
  double den = fmax(1.0 + 2.0 * c * uy + c * c * u2 * y2, EPSd);
  double num2 = fmax(A * A * u2 + 2.0 * A * B * uy + B * B * y2, 0.0);
  double n = sqrt(num2) / den;
  double arg = sc * n;
  const double CLIP = (double)(1.0f - 1e-5f);
  arg = fmin(fmax(arg, 0.0), CLIP);
  return (1.0 / sc) * log((1.0 + arg) / (1.0 - arg));
}

__device__ __forceinline__ double expmap_scale(double c, double p2, double* u2out) {
  double sc = sqrt(c);
  double ntrue = sqrt(p2);
  double nf = fmax(ntrue, 1e-5);
  double th = tanh(sc * nf);
  double s0 = th / (sc * nf);
  double ny = fmax(s0 * ntrue, 1e-5);
  double mx = 0.999 / sc;
  if (ny > mx) s0 *= mx / ny;
  *u2out = s0 * s0 * p2;
  return s0;
}

// grid 128 x 640: protos + P2RAW + H1P (b<32), per-row q2, QPART (+shot fold), CNT reset
__global__ __launch_bounds__(640) void k_fuse1(const float* __restrict__ Qm,
                                               const float* __restrict__ shot,
                                               const float* __restrict__ W1, float* ws) {
  __shared__ double q2w[32][10];
  __shared__ double psred[10];
  __shared__ float pr[DIM];
  __shared__ float h1pp[5][128];
  int b = blockIdx.x, t = threadIdx.x;
  int lane = t & 63, wid = t >> 6;  // 10 waves
  float protoval = 0.f;
  if (b < WAY) {
    float s = 0.f;
#pragma unroll
    for (int s5 = 0; s5 < NSHOT; ++s5) s += shot[(size_t)(s5 * WAY + b) * DIM + t];
    protoval = s * 0.2f;
    pr[t] = protoval;
    ws[OFF_PROTOS + b * DIM + t] = protoval;
    double pv2 = (double)protoval * protoval;
    pv2 = wave_sum_d(pv2);
    if (lane == 0) psred[wid] = pv2;
  }
  int r0 = b * 32;
  float colacc = 0.f;
  for (int r = 0; r < 32; ++r) {
    float v = Qm[(size_t)(r0 + r) * DIM + t];
    colacc += v;
    double sq = (double)v * v;
    sq = wave_sum_d(sq);
    if (lane == 0) q2w[r][wid] = sq;
  }
  ws[OFF_QPART + b * DIM + t] = colacc + 5.f * protoval;
  __syncthreads();
  if (t < 32) {
    double s = 0.0;
#pragma unroll
    for (int k = 0; k < 10; ++k) s += q2w[t][k];
    ((double*)(ws + OFF_Q2D))[r0 + t] = s;
  }
  if (b < WAY) {
    // H1P[b][n] = sum_k pr[k]*W1[k*128+n], 5 k-slices of 128
    int n = t & 127, s = t >> 7;
    int k0 = s * 128;
    float acc = 0.f;
#pragma unroll 8
    for (int k = k0; k < k0 + 128; ++k) acc = fmaf(pr[k], W1[(size_t)k * 128 + n], acc);
    h1pp[s][n] = acc;
    __syncthreads();
    if (t < 128)
      ws[OFF_H1P + b * 128 + t] = h1pp[0][t] + h1pp[1][t] + h1pp[2][t] + h1pp[3][t] + h1pp[4][t];
    if (t == 0) {
      double p2 = 0.0;
#pragma unroll
      for (int k = 0; k < 10; ++k) p2 += psred[k];
      ((double*)(ws + OFF_P2RAW))[b] = p2;
    }
  }
  if (b == 0 && t == 0) ((int*)(ws + OFF_CNT))[0] = 0;
}

// grid 513 x 256: blocks 0..511 raw-dot GEMM G[w][q]=protos[w]·q; block 512 = ctrl-lite
struct GemmSm { float S[2][40][68]; };
struct CtrlSm {
  float am[DIM];
  float part[2][128];
  float h1s[WAY][128];
  float h2s[WAY][64];
  float lg[WAY][5];
};
union Sm1 { GemmSm g; CtrlSm c; };

__global__ __launch_bounds__(256) void k_gemm1(const float* __restrict__ Qm,
                                               const float* __restrict__ W1, const float* __restrict__ b1,
                                               const float* __restrict__ W2, const float* __restrict__ b2,
                                               const float* __restrict__ W3, const float* __restrict__ b3,
                                               float* __restrict__ ws) {
  __shared__ Sm1 sm;
  int t = threadIdx.x;
  if (blockIdx.x < 512) {
    const float* X = ws + OFF_PROTOS;
    int q0 = blockIdx.x * 8;
    int rowA = t >> 4, quadA = t & 15;
    int rowB = (t + 256) >> 4;
    int rowC = (t + 512) >> 4;
    bool hasC = (t < 128);
    const float* srcA = (rowA < 8 ? Qm + (size_t)(q0 + rowA) * DIM : X + (size_t)(rowA - 8) * DIM) + quadA * 4;
    const float* srcB = X + (size_t)(rowB - 8) * DIM + quadA * 4;
    const float* srcC = X + (size_t)(rowC - 8) * DIM + quadA * 4;
    float4 pA = *(const float4*)srcA;
    float4 pB = *(const float4*)srcB;
    float4 pC = {0.f, 0.f, 0.f, 0.f};
    if (hasC) pC = *(const float4*)srcC;
    *(float4*)&sm.g.S[0][rowA][quadA * 4] = pA;
    *(float4*)&sm.g.S[0][rowB][quadA * 4] = pB;
    if (hasC) *(float4*)&sm.g.S[0][rowC][quadA * 4] = pC;
    __syncthreads();
    int q = t & 7, w = t >> 3;
    float ax = 0.f, ay = 0.f, az = 0.f, aw = 0.f;
    for (int c = 0; c < 10; ++c) {
      int bsel = c & 1;
      if (c < 9) {
        size_t kc = (size_t)(c + 1) * 64;
        pA = *(const float4*)(srcA + kc);
        pB = *(const float4*)(srcB + kc);
        if (hasC) pC = *(const float4*)(srcC + kc);
      }
      const float* qr = &sm.g.S[bsel][q][0];
      const float* xr = &sm.g.S[bsel][8 + w][0];
#pragma unroll
      for (int kk = 0; kk < 64; kk += 4) {
        float4 qv = *(const float4*)(qr + kk);
        float4 xv = *(const float4*)(xr + kk);
        ax = fmaf(qv.x, xv.x, ax);
        ay = fmaf(qv.y, xv.y, ay);
        az = fmaf(qv.z, xv.z, az);
        aw = fmaf(qv.w, xv.w, aw);
      }
      if (c < 9) {
        int nb = bsel ^ 1;
        *(float4*)&sm.g.S[nb][rowA][quadA * 4] = pA;
        *(float4*)&sm.g.S[nb][rowB][quadA * 4] = pB;
        if (hasC) *(float4*)&sm.g.S[nb][rowC][quadA * 4] = pC;
        __syncthreads();
      }
    }
    ws[OFF_G + (size_t)w * NQ + q0 + q] = (ax + ay) + (az + aw);
  } else {
    // ---- ctrl-lite ----
    if (t < 160) {
      float4 a = {0.f, 0.f, 0.f, 0.f};
#pragma unroll 4
      for (int p = 0; p < 128; ++p) {
        float4 v = *(const float4*)&ws[OFF_QPART + p * DIM + t * 4];
        a.x += v.x; a.y += v.y; a.z += v.z; a.w += v.w;
      }
      sm.c.am[t * 4 + 0] = a.x / 4256.f;
      sm.c.am[t * 4 + 1] = a.y / 4256.f;
      sm.c.am[t * 4 + 2] = a.z / 4256.f;
      sm.c.am[t * 4 + 3] = a.w / 4256.f;
    }
    __syncthreads();
    {
      int n = t & 127, s = t >> 7;     // 2 k-slices of 320
      int k0 = s * 320;
      float acc = 0.f;
#pragma unroll 8
      for (int k = k0; k < k0 + 320; ++k)
        acc = fmaf(sm.c.am[k], W1[(size_t)(DIM + k) * 128 + n], acc);
      sm.c.part[s][n] = acc;
    }
    __syncthreads();
#pragma unroll
    for (int i = 0; i < 16; ++i) {
      int idx = i * 256 + t;
      int w = idx >> 7, n = idx & 127;
      sm.c.h1s[w][n] = fmaxf(ws[OFF_H1P + w * 128 + n] + sm.c.part[0][n] + sm.c.part[1][n] + b1[n], 0.f);
    }
    __syncthreads();
#pragma unroll
    for (int i = 0; i < 8; ++i) {
      int idx = i * 256 + t;
      int w = idx >> 6, n = idx & 63;
      float acc = 0.f;
      for (int k = 0; k < 128; ++k) acc = fmaf(sm.c.h1s[w][k], W2[(size_t)k * 64 + n], acc);
      sm.c.h2s[w][n] = fmaxf(acc + b2[n], 0.f);
    }
    __syncthreads();
    if (t < 160) {
      int w = t / 5, j = t - (t / 5) * 5;
      float acc = b3[j];
      for (int k = 0; k < 64; ++k) acc = fmaf(sm.c.h2s[w][k], W3[k * 5 + j], acc);
      sm.c.lg[w][j] = acc;
    }
    __syncthreads();
    if (t < WAY) {
      double m = sm.c.lg[t][0];
      for (int i = 1; i < 5; ++i) m = fmax(m, (double)sm.c.lg[t][i]);
      double se = 0.0, cv = 0.0;
      for (int i = 0; i < 5; ++i) { double e = exp((double)sm.c.lg[t][i] - m); se += e; cv += e * 0.2 * (double)(i + 1); }
      double c = cv / se;
      ws[OFF_C + t] = (float)c;
      double p2 = ((const double*)(ws + OFF_P2RAW))[t];
      double u2;
      double beta = expmap_scale(c, p2, &u2);
      ws[OFF_BETA + t] = (float)beta;
      ((double*)(ws + OFF_X2D))[t] = u2;
    }
  }
}

// grid 32 x 1024: inline f64 dist from raw G, S/U, stable top-10, per-way stats;
// last-done block: refine MLP + tmp/expmap -> TP (R5-proven tail pattern).
__global__ __launch_bounds__(1024) void k_topkref(const float* __restrict__ Qm,
                                                  const float* __restrict__ Wr1, const float* __restrict__ br1,
                                                  const float* __restrict__ Wr2, const float* __restrict__ br2,
                                                  float* __restrict__ ws) {
  __shared__ double sredS[16], sredU[16];
  __shared__ float cval[160];
  __shared__ int cidx[160];
  __shared__ float qvsh[RNEAR];
  __shared__ int qjsh[RNEAR];
  __shared__ float colsh[RNEAR][33];
  __shared__ float pcpart[RNEAR];
  __shared__ int tailflag;
  // tail-only
  __shared__ float rrsh[WAY][22];
  __shared__ float hrsh[WAY][RNEAR];
  __shared__ float orsh[WAY][11];
  __shared__ float iwsh[WAY][RNEAR];
  __shared__ float onwsh[WAY];
  __shared__ int nidxsh[WAY][RNEAR];
  __shared__ double p2sh[WAY];
  __shared__ float gsh[WAY];

  int w = blockIdx.x, t = threadIdx.x;
  int lane = t & 63, wid = t >> 6;
  int* nidx = (int*)(ws + OFF_NIDX);
  const double* q2d = (const double*)(ws + OFF_Q2D);
  const double* x2d = (const double*)(ws + OFF_X2D);
  double c = (double)ws[OFF_C + w];
  double beta = (double)ws[OFF_BETA + w];
  double u2 = x2d[w];
  const float* gb = ws + OFF_G + (size_t)w * NQ;
  float v0 = (float)dist_hyp(c, beta * (double)gb[t],        u2, q2d[t]);
  float v1 = (float)dist_hyp(c, beta * (double)gb[1024 + t], u2, q2d[1024 + t]);
  float v2 = (float)dist_hyp(c, beta * (double)gb[2048 + t], u2, q2d[2048 + t]);
  float v3 = (float)dist_hyp(c, beta * (double)gb[3072 + t], u2, q2d[3072 + t]);
  unsigned tk = 0;
  double s = (double)v0 + (double)v1 + (double)v2 + (double)v3;
  double u = (t < RNEAR) ? (double)v0 : 0.0;
  s = wave_sum_d(s);
  u = wave_sum_d(u);
  if (lane == 0) { sredS[wid] = s; sredU[wid] = u; }
  // stage 1: per-wave top-10
  for (int r = 0; r < RNEAR; ++r) {
    float lv = INFINITY; int li = 0x7fffffff;
    if (!(tk & 1u) && (v0 < lv || (v0 == lv && t < li)))        { lv = v0; li = t; }
    if (!(tk & 2u) && (v1 < lv || (v1 == lv && 1024 + t < li))) { lv = v1; li = 1024 + t; }
    if (!(tk & 4u) && (v2 < lv || (v2 == lv && 2048 + t < li))) { lv = v2; li = 2048 + t; }
    if (!(tk & 8u) && (v3 < lv || (v3 == lv && 3072 + t < li))) { lv = v3; li = 3072 + t; }
#pragma unroll
    for (int o = 32; o > 0; o >>= 1) {
      float ov = __shfl_xor(lv, o, 64);
      int oi = __shfl_xor(li, o, 64);
      if (ov < lv || (ov == lv && oi < li)) { lv = ov; li = oi; }
    }
    if (lane == 0) { cval[wid * RNEAR + r] = lv; cidx[wid * RNEAR + r] = li; }
    if ((li & 1023) == t) tk |= 1u << (li >> 10);
  }
  __syncthreads();
  if (t == 0) {
    double S = 0.0, U = 0.0;
    for (int k = 0; k < 16; ++k) { S += sredS[k]; U += sredU[k]; }
    ws[OFF_S + w] = (float)S;
    ws[OFF_U + w] = (float)U;
  }
  if (t < 64) {   // stage 2: wave 0 merges 160 candidates
    float c0 = cval[t], c1 = cval[t + 64];
    int i0 = cidx[t], i1 = cidx[t + 64];
    float c2 = (t < 32) ? cval[t + 128] : INFINITY;
    int i2 = (t < 32) ? cidx[t + 128] : 0x7fffffff;
    unsigned m = 0;
    for (int r = 0; r < RNEAR; ++r) {
      float lv = INFINITY; int li = 0x7fffffff;
      if (!(m & 1u) && (c0 < lv || (c0 == lv && i0 < li))) { lv = c0; li = i0; }
      if (!(m & 2u) && (c1 < lv || (c1 == lv && i1 < li))) { lv = c1; li = i1; }
      if (!(m & 4u) && (c2 < lv || (c2 == lv && i2 < li))) { lv = c2; li = i2; }
#pragma unroll
      for (int o = 32; o > 0; o >>= 1) {
        float ov = __shfl_xor(lv, o, 64);
        int oi = __shfl_xor(li, o, 64);
        if (ov < lv || (ov == lv && oi < li)) { lv = ov; li = oi; }
      }
      if (lane == 0) {
        ws[OFF_NID + w * RNEAR + r] = lv;
        nidx[w * RNEAR + r] = li;
        qvsh[r] = lv; qjsh[r] = li;
      }
      if (i0 == li) m |= 1u;
      if (i1 == li) m |= 2u;
      if (i2 == li) m |= 4u;
    }
  }
  __syncthreads();
  // per-way stats: colsh[j][w2] = dist(w2, qj[j]) from raw G
  if (t < WAY * RNEAR) {
    int j = t >> 5, w2 = t & 31;
    int q = qjsh[j];
    double c2_ = (double)ws[OFF_C + w2];
    double b2_ = (double)ws[OFF_BETA + w2];
    colsh[j][w2] = (float)dist_hyp(c2_, b2_ * (double)ws[OFF_G + (size_t)w2 * NQ + q], x2d[w2], q2d[q]);
  }
  __syncthreads();
  if (t < RNEAR) {
    double cs = 0.0, pc = 0.0;
    for (int w2 = 0; w2 < WAY; ++w2) {
      float dv = colsh[t][w2];
      cs += dv;
      if (w2 < w) pc += dv;
    }
    ws[OFF_RR + w * 22 + t] = qvsh[t];
    ws[OFF_RR + w * 22 + RNEAR + t] = (float)((cs - qvsh[t]) / (double)(WAY - 1));
    pcpart[t] = (float)pc;
  }
  __syncthreads();
  if (t == 0) {
    double spc = 0.0, sn = 0.0;
    for (int j = 0; j < RNEAR; ++j) { spc += pcpart[j]; sn += qvsh[j]; }
    double S = (double)ws[OFF_S + w];
    ws[OFF_RR + w * 22 + 20] = (float)((S - sn) / (double)(NQ - RNEAR));
    ws[OFF_SPC + w] = (float)spc;
  }
  __threadfence();
  __syncthreads();
  if (t == 0) {
    int old = atomicAdd((int*)(ws + OFF_CNT), 1);
    tailflag = (old == WAY - 1);
  }
  __syncthreads();
  if (!tailflag) return;
  __threadfence();
  // ================= tail: refine + tmp for ALL ways =================
  for (int i = t; i < WAY * 21; i += 1024) {
    int ww = i / 21, k = i - ww * 21;
    rrsh[ww][k] = aloadf(ws + OFF_RR + ww * 22 + k);
  }
  for (int i = t; i < WAY * RNEAR; i += 1024) {
    int ww = i / RNEAR, j = i - ww * RNEAR;
    nidxsh[ww][j] = aloadi(nidx + ww * RNEAR + j);
  }
  if (t < WAY) {
    double pref = 0.0, suf = 0.0;
    for (int j = 0; j < t; ++j) pref += (double)aloadf(ws + OFF_S + j);
    for (int j = t + 1; j < WAY; ++j) suf += (double)aloadf(ws + OFF_S + j) - (double)aloadf(ws + OFF_U + j);
    double spc = (double)aloadf(ws + OFF_SPC + t);
    rrsh[t][21] = (float)((pref - spc + suf) / ((double)(WAY - 1) * (double)(NQ - RNEAR)));
  }
  __syncthreads();
  if (t < WAY * RNEAR) {
    int ww = t / RNEAR, r = t - (t / RNEAR) * RNEAR;
    float a = br1[r];
    for (int k = 0; k < 22; ++k) a = fmaf(rrsh[ww][k], Wr1[k * RNEAR + r], a);
    hrsh[ww][r] = fmaxf(a, 0.f);
  }
  __syncthreads();
  if (t < WAY * 11) {
    int ww = t / 11, r = t - (t / 11) * 11;
    float a = br2[r];
    for (int k = 0; k < RNEAR; ++k) a = fmaf(hrsh[ww][k], Wr2[k * 11 + r], a);
    orsh[ww][r] = a;
  }
  __syncthreads();
  if (t < WAY) {
    double m = orsh[t][0];
    for (int i = 1; i < RNEAR; ++i) m = fmax(m, (double)orsh[t][i]);
    double se = 0.0; double e[RNEAR];
    for (int i = 0; i < RNEAR; ++i) { e[i] = exp((double)orsh[t][i] - m); se += e[i]; }
    for (int i = 0; i < RNEAR; ++i) iwsh[t][i] = (float)(e[i] / se);
    onwsh[t] = (float)(1.0 / (1.0 + exp(-(double)orsh[t][10])));
  }
  __syncthreads();
  {
    int ww = t >> 5, l = t & 31;
    float onwv = onwsh[ww];
    float areg[20];
    double ls = 0.0;
#pragma unroll
    for (int i = 0; i < 20; ++i) {
      int d = l + i * 32;
      float wd = 0.f;
#pragma unroll
      for (int j = 0; j < RNEAR; ++j)
        wd = fmaf(Qm[(size_t)nidxsh[ww][j] * DIM + d], iwsh[ww][j], wd);
      float a = ws[OFF_PROTOS + ww * DIM + d] * onwv + wd * (1.f - onwv);
      areg[i] = a;
      ls += (double)a * a;
    }
#pragma unroll
    for (int o = 16; o > 0; o >>= 1) ls += __shfl_xor(ls, o, 32);
    if (l == 0) p2sh[ww] = ls;
    __syncthreads();
    if (t < WAY) {
      double u22;
      double g = expmap_scale((double)ws[OFF_C + t], p2sh[t], &u22);
      gsh[t] = (float)g;
      ((double*)(ws + OFF_X2D2))[t] = u22;
    }
    __syncthreads();
    float g = gsh[ww];
#pragma unroll
    for (int i = 0; i < 20; ++i) ws[OFF_TP + ww * DIM + l + i * 32] = g * areg[i];
  }
}

// grid 512 x 256: TP·q GEMM + fused f64 dist epilogue -> out (R10/R11-proven)
__global__ __launch_bounds__(256) void k_gemm2(const float* __restrict__ Qm,
                                               float* __restrict__ ws, float* __restrict__ out) {
  __shared__ float S[2][40][68];
  const float* X = ws + OFF_TP;
  int t = threadIdx.x;
  int q0 = blockIdx.x * 8;
  int rowA = t >> 4, quadA = t & 15;
  int rowB = (t + 256) >> 4;
  int rowC = (t + 512) >> 4;
  bool hasC = (t < 128);
  const float* srcA = (rowA < 8 ? Qm + (size_t)(q0 + rowA) * DIM : X + (size_t)(rowA - 8) * DIM) + quadA * 4;
  const float* srcB = X + (size_t)(rowB - 8) * DIM + quadA * 4;
  const float* srcC = X + (size_t)(rowC - 8) * DIM + quadA * 4;
  float4 pA = *(const float4*)srcA;
  float4 pB = *(const float4*)srcB;
  float4 pC = {0.f, 0.f, 0.f, 0.f};
  if (hasC) pC = *(const float4*)srcC;
  *(float4*)&S[0][rowA][quadA * 4] = pA;
  *(float4*)&S[0][rowB][quadA * 4] = pB;
  if (hasC) *(float4*)&S[0][rowC][quadA * 4] = pC;
  __syncthreads();
  int q = t & 7, w = t >> 3;
  float ax = 0.f, ay = 0.f, az = 0.f, aw = 0.f;
  for (int c = 0; c < 10; ++c) {
    int bsel = c & 1;
    if (c < 9) {
      size_t kc = (size_t)(c + 1) * 64;
      pA = *(const float4*)(srcA + kc);
      pB = *(const float4*)(srcB + kc);
      if (hasC) pC = *(const float4*)(srcC + kc);
    }
    const float* qr = &S[bsel][q][0];
    const float* xr = &S[bsel][8 + w][0];
#pragma unroll
    for (int kk = 0; kk < 64; kk += 4) {
      float4 qv = *(const float4*)(qr + kk);
      float4 xv = *(const float4*)(xr + kk);
      ax = fmaf(qv.x, xv.x, ax);
      ay = fmaf(qv.y, xv.y, ay);
      az = fmaf(qv.z, xv.z, az);
      aw = fmaf(qv.w, xv.w, aw);
    }
    if (c < 9) {
      int nb = bsel ^ 1;
      *(float4*)&S[nb][rowA][quadA * 4] = pA;
      *(float4*)&S[nb][rowB][quadA * 4] = pB;
      if (hasC) *(float4*)&S[nb][rowC][quadA * 4] = pC;
      __syncthreads();
    }
  }
  float acc = (ax + ay) + (az + aw);
  const double* q2d = (const double*)(ws + OFF_Q2D);
  const double* u2arr = (const double*)(ws + OFF_X2D2);
  int qq = q0 + q;
  double d = dist_hyp((double)ws[OFF_C + w], (double)acc, u2arr[w], q2d[qq]);
  out[(size_t)qq * WAY + w] = (float)(-d / 16.0);
}

extern "C" void kernel_launch(void* const* d_in, const int* in_sizes, int n_in,
                              void* d_out, int out_size, void* d_ws, size_t ws_size,
                              hipStream_t stream) {
  (void)in_sizes; (void)n_in; (void)out_size; (void)ws_size;
  const float* shot = (const float*)d_in[0];
  const float* qry  = (const float*)d_in[1];
  const float* W1   = (const float*)d_in[2];
  const float* b1   = (const float*)d_in[3];
  const float* W2   = (const float*)d_in[4];
  const float* b2   = (const float*)d_in[5];
  const float* W3   = (const float*)d_in[6];
  const float* b3   = (const float*)d_in[7];
  const float* Wr1  = (const float*)d_in[8];
  const float* br1  = (const float*)d_in[9];
  const float* Wr2  = (const float*)d_in[10];
  const float* br2  = (const float*)d_in[11];
  float* ws = (float*)d_ws;
  float* out = (float*)d_out;

  hipLaunchKernelGGL(k_fuse1,   dim3(128), dim3(640), 0, stream, qry, shot, W1, ws);
  hipLaunchKernelGGL(k_gemm1,   dim3(513), dim3(256), 0, stream, qry, W1, b1, W2, b2, W3, b3, ws);
  hipLaunchKernelGGL(k_topkref, dim3(32), dim3(1024), 0, stream, qry, Wr1, br1, Wr2, br2, ws);
  hipLaunchKernelGGL(k_gemm2,   dim3(512), dim3(256), 0, stream, qry, ws, out);
}

// Round 14
// 127.464 us; speedup vs baseline: 1.0588x; 1.0588x over previous
//
#include <hip/hip_runtime.h>
#include <math.h>

#define NSHOT 5
#define WAY 32
#define DIM 640
#define NQ 4096
#define RNEAR 10

// ---- workspace layout (float offsets), ~1.07 MB ----
constexpr int OFF_PROTOS = 0;        // 32*640
constexpr int OFF_QPART  = 20480;    // 128*640 column partial sums (incl. shot fold)
constexpr int OFF_C      = 102400;   // 32
constexpr int OFF_BETA   = 102432;   // 32
constexpr int OFF_S      = 102464;   // 32
constexpr int OFF_U      = 102496;   // 32
constexpr int OFF_NID    = 102528;   // 32*10
constexpr int OFF_RR     = 102848;   // 32*22
constexpr int OFF_SPC    = 103552;   // 32
constexpr int OFF_H1P    = 103584;   // 32*128 (per-way pr·W1a)
constexpr int OFF_TP     = 107680;   // 32*640
constexpr int OFF_G      = 128160;   // 32*4096 raw dots
constexpr int OFF_NIDX   = 259232;   // 32*10 ints
constexpr int OFF_CNT    = 259552;   // 1 int
constexpr int OFF_Q2D    = 259556;   // double[4096] (even -> 8B aligned)
constexpr int OFF_X2D    = 267748;   // double[32] (proto_p norm^2)
constexpr int OFF_X2D2   = 267812;   // double[32] (test_proto norm^2)
constexpr int OFF_P2RAW  = 267876;   // double[32] (raw proto norm^2)

__device__ __forceinline__ double wave_sum_d(double v) {
#pragma unroll
  for (int o = 32; o > 0; o >>= 1) v += __shfl_down(v, o, 64);
  return v;
}

__device__ __forceinline__ float aloadf(const float* p) {
  return __hip_atomic_load(p, __ATOMIC_RELAXED, __HIP_MEMORY_SCOPE_AGENT);
}
__device__ __forceinline__ int aloadi(const int* p) {
  return __hip_atomic_load(p, __ATOMIC_RELAXED, __HIP_MEMORY_SCOPE_AGENT);
}

// f64 distance — used only in the OUTPUT path (gemm2 epilogue)
__device__ __forceinline__ double dist_hyp(double c, double xdotq, double u2, double q2) {
  const double EPSd = 1e-5;
  double sc = sqrt(c);
  double nq = sqrt(q2);
  double nf = fmax(nq, EPSd);
  double th = tanh(sc * nf);
  double al = th / (sc * nf);
  double ny = fmax(al * nq, EPSd);
  double mx = 0.999 / sc;
  if (ny > mx) al *= mx / ny;
  double y2 = al * al * q2;
  double uy = -al * xdotq;
  double A = 1.0 + 2.0 * c * uy + c * y2;
  double B = 1.0 - c * u2;
  double den = fmax(1.0 + 2.0 * c * uy + c * c * u2 * y2, EPSd);
  double num2 = fmax(A * A * u2 + 2.0 * A * B * uy + B * B * y2, 0.0);
  double n = sqrt(num2) / den;
  double arg = sc * n;
  const double CLIP = (double)(1.0f - 1e-5f);
  arg = fmin(fmax(arg, 0.0), CLIP);
  return (1.0 / sc) * log((1.0 + arg) / (1.0 - arg));
}

// f32 fast distance — mirrors the reference's own f32 formula; used for
// topk selection + S/U/colsh stats (HW tanhf/logf, ~15x cheaper than f64).
__device__ __forceinline__ float dist_f32(float c, float xdotq, float u2, float q2) {
  const float EPSf = 1e-5f;
  float sc = sqrtf(c);
  float nq = sqrtf(q2);
  float nf = fmaxf(nq, EPSf);
  float th = tanhf(sc * nf);
  float al = th / (sc * nf);
  float ny = fmaxf(al * nq, EPSf);
  float mx = 0.999f / sc;
  if (ny > mx) al *= mx / ny;
  float y2 = al * al * q2;
  float uy = -al * xdotq;
  float A = 1.f + 2.f * c * uy + c * y2;
  float B = 1.f - c * u2;
  float den = fmaxf(1.f + 2.f * c * uy + c * c * u2 * y2, EPSf);
  float num2 = fmaxf(A * A * u2 + 2.f * A * B * uy + B * B * y2, 0.f);
  float n = sqrtf(num2) / den;
  float arg = sc * n;
  arg = fminf(fmaxf(arg, 0.f), 1.f - 1e-5f);
  return (1.f / sc) * logf((1.f + arg) / (1.f - arg));
}

__device__ __forceinline__ double expmap_scale(double c, double p2, double* u2out) {
  double sc = sqrt(c);
  double ntrue = sqrt(p2);
  double nf = fmax(ntrue, 1e-5);
  double th = tanh(sc * nf);
  double s0 = th / (sc * nf);
  double ny = fmax(s0 * ntrue, 1e-5);
  double mx = 0.999 / sc;
  if (ny > mx) s0 *= mx / ny;
  *u2out = s0 * s0 * p2;
  return s0;
}

// grid 128 x 640: protos + P2RAW + H1P (b<32), per-row q2, QPART (+shot fold), CNT reset
__global__ __launch_bounds__(640) void k_fuse1(const float* __restrict__ Qm,
                                               const float* __restrict__ shot,
                                               const float* __restrict__ W1, float* ws) {
  __shared__ double q2w[32][10];
  __shared__ double psred[10];
  __shared__ float pr[DIM];
  __shared__ float h1pp[5][128];
  int b = blockIdx.x, t = threadIdx.x;
  int lane = t & 63, wid = t >> 6;  // 10 waves
  float protoval = 0.f;
  if (b < WAY) {
    float s = 0.f;
#pragma unroll
    for (int s5 = 0; s5 < NSHOT; ++s5) s += shot[(size_t)(s5 * WAY + b) * DIM + t];
    protoval = s * 0.2f;
    pr[t] = protoval;
    ws[OFF_PROTOS + b * DIM + t] = protoval;
    double pv2 = (double)protoval * protoval;
    pv2 = wave_sum_d(pv2);
    if (lane == 0) psred[wid] = pv2;
  }
  int r0 = b * 32;
  float colacc = 0.f;
  for (int r = 0; r < 32; ++r) {
    float v = Qm[(size_t)(r0 + r) * DIM + t];
    colacc += v;
    double sq = (double)v * v;
    sq = wave_sum_d(sq);
    if (lane == 0) q2w[r][wid] = sq;
  }
  ws[OFF_QPART + b * DIM + t] = colacc + 5.f * protoval;
  __syncthreads();
  if (t < 32) {
    double s = 0.0;
#pragma unroll
    for (int k = 0; k < 10; ++k) s += q2w[t][k];
    ((double*)(ws + OFF_Q2D))[r0 + t] = s;
  }
  if (b < WAY) {
    int n = t & 127, s = t >> 7;
    int k0 = s * 128;
    float acc = 0.f;
#pragma unroll 8
    for (int k = k0; k < k0 + 128; ++k) acc = fmaf(pr[k], W1[(size_t)k * 128 + n], acc);
    h1pp[s][n] = acc;
    __syncthreads();
    if (t < 128)
      ws[OFF_H1P + b * 128 + t] = h1pp[0][t] + h1pp[1][t] + h1pp[2][t] + h1pp[3][t] + h1pp[4][t];
    if (t == 0) {
      double p2 = 0.0;
#pragma unroll
      for (int k = 0; k < 10; ++k) p2 += psred[k];
      ((double*)(ws + OFF_P2RAW))[b] = p2;
    }
  }
  if (b == 0 && t == 0) ((int*)(ws + OFF_CNT))[0] = 0;
}

// grid 513 x 256: blocks 0..511 raw-dot GEMM G[w][q]=protos[w]·q; block 512 = ctrl-lite
struct GemmSm { float S[2][40][68]; };
struct CtrlSm {
  float am[DIM];
  float part[2][128];
  float h1s[WAY][128];
  float h2s[WAY][64];
  float lg[WAY][5];
};
union Sm1 { GemmSm g; CtrlSm c; };

__global__ __launch_bounds__(256) void k_gemm1(const float* __restrict__ Qm,
                                               const float* __restrict__ W1, const float* __restrict__ b1,
                                               const float* __restrict__ W2, const float* __restrict__ b2,
                                               const float* __restrict__ W3, const float* __restrict__ b3,
                                               float* __restrict__ ws) {
  __shared__ Sm1 sm;
  int t = threadIdx.x;
  if (blockIdx.x < 512) {
    const float* X = ws + OFF_PROTOS;
    int q0 = blockIdx.x * 8;
    int rowA = t >> 4, quadA = t & 15;
    int rowB = (t + 256) >> 4;
    int rowC = (t + 512) >> 4;
    bool hasC = (t < 128);
    const float* srcA = (rowA < 8 ? Qm + (size_t)(q0 + rowA) * DIM : X + (size_t)(rowA - 8) * DIM) + quadA * 4;
    const float* srcB = X + (size_t)(rowB - 8) * DIM + quadA * 4;
    const float* srcC = X + (size_t)(rowC - 8) * DIM + quadA * 4;
    float4 pA = *(const float4*)srcA;
    float4 pB = *(const float4*)srcB;
    float4 pC = {0.f, 0.f, 0.f, 0.f};
    if (hasC) pC = *(const float4*)srcC;
    *(float4*)&sm.g.S[0][rowA][quadA * 4] = pA;
    *(float4*)&sm.g.S[0][rowB][quadA * 4] = pB;
    if (hasC) *(float4*)&sm.g.S[0][rowC][quadA * 4] = pC;
    __syncthreads();
    int q = t & 7, w = t >> 3;
    float ax = 0.f, ay = 0.f, az = 0.f, aw = 0.f;
    for (int c = 0; c < 10; ++c) {
      int bsel = c & 1;
      if (c < 9) {
        size_t kc = (size_t)(c + 1) * 64;
        pA = *(const float4*)(srcA + kc);
        pB = *(const float4*)(srcB + kc);
        if (hasC) pC = *(const float4*)(srcC + kc);
      }
      const float* qr = &sm.g.S[bsel][q][0];
      const float* xr = &sm.g.S[bsel][8 + w][0];
#pragma unroll
      for (int kk = 0; kk < 64; kk += 4) {
        float4 qv = *(const float4*)(qr + kk);
        float4 xv = *(const float4*)(xr + kk);
        ax = fmaf(qv.x, xv.x, ax);
        ay = fmaf(qv.y, xv.y, ay);
        az = fmaf(qv.z, xv.z, az);
        aw = fmaf(qv.w, xv.w, aw);
      }
      if (c < 9) {
        int nb = bsel ^ 1;
        *(float4*)&sm.g.S[nb][rowA][quadA * 4] = pA;
        *(float4*)&sm.g.S[nb][rowB][quadA * 4] = pB;
        if (hasC) *(float4*)&sm.g.S[nb][rowC][quadA * 4] = pC;
        __syncthreads();
      }
    }
    ws[OFF_G + (size_t)w * NQ + q0 + q] = (ax + ay) + (az + aw);
  } else {
    // ---- ctrl-lite ----
    if (t < 160) {
      float4 a = {0.f, 0.f, 0.f, 0.f};
#pragma unroll 4
      for (int p = 0; p < 128; ++p) {
        float4 v = *(const float4*)&ws[OFF_QPART + p * DIM + t * 4];
        a.x += v.x; a.y += v.y; a.z += v.z; a.w += v.w;
      }
      sm.c.am[t * 4 + 0] = a.x / 4256.f;
      sm.c.am[t * 4 + 1] = a.y / 4256.f;
      sm.c.am[t * 4 + 2] = a.z / 4256.f;
      sm.c.am[t * 4 + 3] = a.w / 4256.f;
    }
    __syncthreads();
    {
      int n = t & 127, s = t >> 7;     // 2 k-slices of 320
      int k0 = s * 320;
      float acc = 0.f;
#pragma unroll 8
      for (int k = k0; k < k0 + 320; ++k)
        acc = fmaf(sm.c.am[k], W1[(size_t)(DIM + k) * 128 + n], acc);
      sm.c.part[s][n] = acc;
    }
    __syncthreads();
#pragma unroll
    for (int i = 0; i < 16; ++i) {
      int idx = i * 256 + t;
      int w = idx >> 7, n = idx & 127;
      sm.c.h1s[w][n] = fmaxf(ws[OFF_H1P + w * 128 + n] + sm.c.part[0][n] + sm.c.part[1][n] + b1[n], 0.f);
    }
    __syncthreads();
#pragma unroll
    for (int i = 0; i < 8; ++i) {
      int idx = i * 256 + t;
      int w = idx >> 6, n = idx & 63;
      float acc = 0.f;
      for (int k = 0; k < 128; ++k) acc = fmaf(sm.c.h1s[w][k], W2[(size_t)k * 64 + n], acc);
      sm.c.h2s[w][n] = fmaxf(acc + b2[n], 0.f);
    }
    __syncthreads();
    if (t < 160) {
      int w = t / 5, j = t - (t / 5) * 5;
      float acc = b3[j];
      for (int k = 0; k < 64; ++k) acc = fmaf(sm.c.h2s[w][k], W3[k * 5 + j], acc);
      sm.c.lg[w][j] = acc;
    }
    __syncthreads();
    if (t < WAY) {
      double m = sm.c.lg[t][0];
      for (int i = 1; i < 5; ++i) m = fmax(m, (double)sm.c.lg[t][i]);
      double se = 0.0, cv = 0.0;
      for (int i = 0; i < 5; ++i) { double e = exp((double)sm.c.lg[t][i] - m); se += e; cv += e * 0.2 * (double)(i + 1); }
      double c = cv / se;
      ws[OFF_C + t] = (float)c;
      double p2 = ((const double*)(ws + OFF_P2RAW))[t];
      double u2;
      double beta = expmap_scale(c, p2, &u2);
      ws[OFF_BETA + t] = (float)beta;
      ((double*)(ws + OFF_X2D))[t] = u2;
    }
  }
}

// grid 32 x 1024: f32 fast dist from raw G, S/U, stable top-10, per-way stats;
// last-done block: refine MLP + tmp/expmap -> TP.
__global__ __launch_bounds__(1024) void k_topkref(const float* __restrict__ Qm,
                                                  const float* __restrict__ Wr1, const float* __restrict__ br1,
                                                  const float* __restrict__ Wr2, const float* __restrict__ br2,
                                                  float* __restrict__ ws) {
  __shared__ double sredS[16], sredU[16];
  __shared__ float cval[160];
  __shared__ int cidx[160];
  __shared__ float qvsh[RNEAR];
  __shared__ int qjsh[RNEAR];
  __shared__ float colsh[RNEAR][33];
  __shared__ float pcpart[RNEAR];
  __shared__ int tailflag;
  // tail-only
  __shared__ float rrsh[WAY][22];
  __shared__ float hrsh[WAY][RNEAR];
  __shared__ float orsh[WAY][11];
  __shared__ float iwsh[WAY][RNEAR];
  __shared__ float onwsh[WAY];
  __shared__ int nidxsh[WAY][RNEAR];
  __shared__ double p2sh[WAY];
  __shared__ float gsh[WAY];

  int w = blockIdx.x, t = threadIdx.x;
  int lane = t & 63, wid = t >> 6;
  int* nidx = (int*)(ws + OFF_NIDX);
  const double* q2d = (const double*)(ws + OFF_Q2D);
  const double* x2d = (const double*)(ws + OFF_X2D);
  float cf = ws[OFF_C + w];
  float betaf = ws[OFF_BETA + w];
  float u2f = (float)x2d[w];
  const float* gb = ws + OFF_G + (size_t)w * NQ;
  float v0 = dist_f32(cf, betaf * gb[t],        u2f, (float)q2d[t]);
  float v1 = dist_f32(cf, betaf * gb[1024 + t], u2f, (float)q2d[1024 + t]);
  float v2 = dist_f32(cf, betaf * gb[2048 + t], u2f, (float)q2d[2048 + t]);
  float v3 = dist_f32(cf, betaf * gb[3072 + t], u2f, (float)q2d[3072 + t]);
  unsigned tk = 0;
  double s = (double)v0 + (double)v1 + (double)v2 + (double)v3;
  double u = (t < RNEAR) ? (double)v0 : 0.0;
  s = wave_sum_d(s);
  u = wave_sum_d(u);
  if (lane == 0) { sredS[wid] = s; sredU[wid] = u; }
  // stage 1: per-wave top-10
  for (int r = 0; r < RNEAR; ++r) {
    float lv = INFINITY; int li = 0x7fffffff;
    if (!(tk & 1u) && (v0 < lv || (v0 == lv && t < li)))        { lv = v0; li = t; }
    if (!(tk & 2u) && (v1 < lv || (v1 == lv && 1024 + t < li))) { lv = v1; li = 1024 + t; }
    if (!(tk & 4u) && (v2 < lv || (v2 == lv && 2048 + t < li))) { lv = v2; li = 2048 + t; }
    if (!(tk & 8u) && (v3 < lv || (v3 == lv && 3072 + t < li))) { lv = v3; li = 3072 + t; }
#pragma unroll
    for (int o = 32; o > 0; o >>= 1) {
      float ov = __shfl_xor(lv, o, 64);
      int oi = __shfl_xor(li, o, 64);
      if (ov < lv || (ov == lv && oi < li)) { lv = ov; li = oi; }
    }
    if (lane == 0) { cval[wid * RNEAR + r] = lv; cidx[wid * RNEAR + r] = li; }
    if ((li & 1023) == t) tk |= 1u << (li >> 10);
  }
  __syncthreads();
  if (t == 0) {
    double S = 0.0, U = 0.0;
    for (int k = 0; k < 16; ++k) { S += sredS[k]; U += sredU[k]; }
    ws[OFF_S + w] = (float)S;
    ws[OFF_U + w] = (float)U;
  }
  if (t < 64) {   // stage 2: wave 0 merges 160 candidates
    float c0 = cval[t], c1 = cval[t + 64];
    int i0 = cidx[t], i1 = cidx[t + 64];
    float c2 = (t < 32) ? cval[t + 128] : INFINITY;
    int i2 = (t < 32) ? cidx[t + 128] : 0x7fffffff;
    unsigned m = 0;
    for (int r = 0; r < RNEAR; ++r) {
      float lv = INFINITY; int li = 0x7fffffff;
      if (!(m & 1u) && (c0 < lv || (c0 == lv && i0 < li))) { lv = c0; li = i0; }
      if (!(m & 2u) && (c1 < lv || (c1 == lv && i1 < li))) { lv = c1; li = i1; }
      if (!(m & 4u) && (c2 < lv || (c2 == lv && i2 < li))) { lv = c2; li = i2; }
#pragma unroll
      for (int o = 32; o > 0; o >>= 1) {
        float ov = __shfl_xor(lv, o, 64);
        int oi = __shfl_xor(li, o, 64);
        if (ov < lv || (ov == lv && oi < li)) { lv = ov; li = oi; }
      }
      if (lane == 0) {
        ws[OFF_NID + w * RNEAR + r] = lv;
        nidx[w * RNEAR + r] = li;
        qvsh[r] = lv; qjsh[r] = li;
      }
      if (i0 == li) m |= 1u;
      if (i1 == li) m |= 2u;
      if (i2 == li) m |= 4u;
    }
  }
  __syncthreads();
  // per-way stats: colsh[j][w2] = dist(w2, qj[j]) from raw G (f32 fast path)
  if (t < WAY * RNEAR) {
    int j = t >> 5, w2 = t & 31;
    int q = qjsh[j];
    colsh[j][w2] = dist_f32(ws[OFF_C + w2], ws[OFF_BETA + w2] * ws[OFF_G + (size_t)w2 * NQ + q],
                            (float)x2d[w2], (float)q2d[q]);
  }
  __syncthreads();
  if (t < RNEAR) {
    double cs = 0.0, pc = 0.0;
    for (int w2 = 0; w2 < WAY; ++w2) {
      float dv = colsh[t][w2];
      cs += dv;
      if (w2 < w) pc += dv;
    }
    ws[OFF_RR + w * 22 + t] = qvsh[t];
    ws[OFF_RR + w * 22 + RNEAR + t] = (float)((cs - qvsh[t]) / (double)(WAY - 1));
    pcpart[t] = (float)pc;
  }
  __syncthreads();
  if (t == 0) {
    double spc = 0.0, sn = 0.0;
    for (int j = 0; j < RNEAR; ++j) { spc += pcpart[j]; sn += qvsh[j]; }
    double S = (double)ws[OFF_S + w];
    ws[OFF_RR + w * 22 + 20] = (float)((S - sn) / (double)(NQ - RNEAR));
    ws[OFF_SPC + w] = (float)spc;
  }
  __threadfence();
  __syncthreads();
  if (t == 0) {
    int old = atomicAdd((int*)(ws + OFF_CNT), 1);
    tailflag = (old == WAY - 1);
  }
  __syncthreads();
  if (!tailflag) return;
  __threadfence();
  // ================= tail: refine + tmp for ALL ways =================
  for (int i = t; i < WAY * 21; i += 1024) {
    int ww = i / 21, k = i - ww * 21;
    rrsh[ww][k] = aloadf(ws + OFF_RR + ww * 22 + k);
  }
  for (int i = t; i < WAY * RNEAR; i += 1024) {
    int ww = i / RNEAR, j = i - ww * RNEAR;
    nidxsh[ww][j] = aloadi(nidx + ww * RNEAR + j);
  }
  if (t < WAY) {
    double pref = 0.0, suf = 0.0;
    for (int j = 0; j < t; ++j) pref += (double)aloadf(ws + OFF_S + j);
    for (int j = t + 1; j < WAY; ++j) suf += (double)aloadf(ws + OFF_S + j) - (double)aloadf(ws + OFF_U + j);
    double spc = (double)aloadf(ws + OFF_SPC + t);
    rrsh[t][21] = (float)((pref - spc + suf) / ((double)(WAY - 1) * (double)(NQ - RNEAR)));
  }
  __syncthreads();
  if (t < WAY * RNEAR) {
    int ww = t / RNEAR, r = t - (t / RNEAR) * RNEAR;
    float a = br1[r];
    for (int k = 0; k < 22; ++k) a = fmaf(rrsh[ww][k], Wr1[k * RNEAR + r], a);
    hrsh[ww][r] = fmaxf(a, 0.f);
  }
  __syncthreads();
  if (t < WAY * 11) {
    int ww = t / 11, r = t - (t / 11) * 11;
    float a = br2[r];
    for (int k = 0; k < RNEAR; ++k) a = fmaf(hrsh[ww][k], Wr2[k * 11 + r], a);
    orsh[ww][r] = a;
  }
  __syncthreads();
  if (t < WAY) {
    double m = orsh[t][0];
    for (int i = 1; i < RNEAR; ++i) m = fmax(m, (double)orsh[t][i]);
    double se = 0.0; double e[RNEAR];
    for (int i = 0; i < RNEAR; ++i) { e[i] = exp((double)orsh[t][i] - m); se += e[i]; }
    for (int i = 0; i < RNEAR; ++i) iwsh[t][i] = (float)(e[i] / se);
    onwsh[t] = (float)(1.0 / (1.0 + exp(-(double)orsh[t][10])));
  }
  __syncthreads();
  {
    int ww = t >> 5, l = t & 31;
    float onwv = onwsh[ww];
    float areg[20];
    double ls = 0.0;
#pragma unroll
    for (int i = 0; i < 20; ++i) {
      int d = l + i * 32;
      float wd = 0.f;
#pragma unroll
      for (int j = 0; j < RNEAR; ++j)
        wd = fmaf(Qm[(size_t)nidxsh[ww][j] * DIM + d], iwsh[ww][j], wd);
      float a = ws[OFF_PROTOS + ww * DIM + d] * onwv + wd * (1.f - onwv);
      areg[i] = a;
      ls += (double)a * a;
    }
#pragma unroll
    for (int o = 16; o > 0; o >>= 1) ls += __shfl_xor(ls, o, 32);
    if (l == 0) p2sh[ww] = ls;
    __syncthreads();
    if (t < WAY) {
      double u22;
      double g = expmap_scale((double)ws[OFF_C + t], p2sh[t], &u22);
      gsh[t] = (float)g;
      ((double*)(ws + OFF_X2D2))[t] = u22;
    }
    __syncthreads();
    float g = gsh[ww];
#pragma unroll
    for (int i = 0; i < 20; ++i) ws[OFF_TP + ww * DIM + l + i * 32] = g * areg[i];
  }
}

// grid 512 x 256: TP·q GEMM + fused f64 dist epilogue -> out (R10/R11-proven)
__global__ __launch_bounds__(256) void k_gemm2(const float* __restrict__ Qm,
                                               float* __restrict__ ws, float* __restrict__ out) {
  __shared__ float S[2][40][68];
  const float* X = ws + OFF_TP;
  int t = threadIdx.x;
  int q0 = blockIdx.x * 8;
  int rowA = t >> 4, quadA = t & 15;
  int rowB = (t + 256) >> 4;
  int rowC = (t + 512) >> 4;
  bool hasC = (t < 128);
  const float* srcA = (rowA < 8 ? Qm + (size_t)(q0 + rowA) * DIM : X + (size_t)(rowA - 8) * DIM) + quadA * 4;
  const float* srcB = X + (size_t)(rowB - 8) * DIM + quadA * 4;
  const float* srcC = X + (size_t)(rowC - 8) * DIM + quadA * 4;
  float4 pA = *(const float4*)srcA;
  float4 pB = *(const float4*)srcB;
  float4 pC = {0.f, 0.f, 0.f, 0.f};
  if (hasC) pC = *(const float4*)srcC;
  *(float4*)&S[0][rowA][quadA * 4] = pA;
  *(float4*)&S[0][rowB][quadA * 4] = pB;
  if (hasC) *(float4*)&S[0][rowC][quadA * 4] = pC;
  __syncthreads();
  int q = t & 7, w = t >> 3;
  float ax = 0.f, ay = 0.f, az = 0.f, aw = 0.f;
  for (int c = 0; c < 10; ++c) {
    int bsel = c & 1;
    if (c < 9) {
      size_t kc = (size_t)(c + 1) * 64;
      pA = *(const float4*)(srcA + kc);
      pB = *(const float4*)(srcB + kc);
      if (hasC) pC = *(const float4*)(srcC + kc);
    }
    const float* qr = &S[bsel][q][0];
    const float* xr = &S[bsel][8 + w][0];
#pragma unroll
    for (int kk = 0; kk < 64; kk += 4) {
      float4 qv = *(const float4*)(qr + kk);
      float4 xv = *(const float4*)(xr + kk);
      ax = fmaf(qv.x, xv.x, ax);
      ay = fmaf(qv.y, xv.y, ay);
      az = fmaf(qv.z, xv.z, az);
      aw = fmaf(qv.w, xv.w, aw);
    }
    if (c < 9) {
      int nb = bsel ^ 1;
      *(float4*)&S[nb][rowA][quadA * 4] = pA;
      *(float4*)&S[nb][rowB][quadA * 4] = pB;
      if (hasC) *(float4*)&S[nb][rowC][quadA * 4] = pC;
      __syncthreads();
    }
  }
  float acc = (ax + ay) + (az + aw);
  const double* q2d = (const double*)(ws + OFF_Q2D);
  const double* u2arr = (const double*)(ws + OFF_X2D2);
  int qq = q0 + q;
  double d = dist_hyp((double)ws[OFF_C + w], (double)acc, u2arr[w], q2d[qq]);
  out[(size_t)qq * WAY + w] = (float)(-d / 16.0);
}

extern "C" void kernel_launch(void* const* d_in, const int* in_sizes, int n_in,
                              void* d_out, int out_size, void* d_ws, size_t ws_size,
                              hipStream_t stream) {
  (void)in_sizes; (void)n_in; (void)out_size; (void)ws_size;
  const float* shot = (const float*)d_in[0];
  const float* qry  = (const float*)d_in[1];
  const float* W1   = (const float*)d_in[2];
  const float* b1   = (const float*)d_in[3];
  const float* W2   = (const float*)d_in[4];
  const float* b2   = (const float*)d_in[5];
  const float* W3   = (const float*)d_in[6];
  const float* b3   = (const float*)d_in[7];
  const float* Wr1  = (const float*)d_in[8];
  const float* br1  = (const float*)d_in[9];
  const float* Wr2  = (const float*)d_in[10];
  const float* br2  = (const float*)d_in[11];
  float* ws = (float*)d_ws;
  float* out = (float*)d_out;

  hipLaunchKernelGGL(k_fuse1,   dim3(128), dim3(640), 0, stream, qry, shot, W1, ws);
  hipLaunchKernelGGL(k_gemm1,   dim3(513), dim3(256), 0, stream, qry, W1, b1, W2, b2, W3, b3, ws);
  hipLaunchKernelGGL(k_topkref, dim3(32), dim3(1024), 0, stream, qry, Wr1, br1, Wr2, br2, ws);
  hipLaunchKernelGGL(k_gemm2,   dim3(512), dim3(256), 0, stream, qry, ws, out);
}

// Round 15
// 116.331 us; speedup vs baseline: 1.1601x; 1.0957x over previous
//
#include <hip/hip_runtime.h>
#include <math.h>

#define NSHOT 5
#define WAY 32
#define DIM 640
#define NQ 4096
#define RNEAR 10

// ---- workspace layout (float offsets), ~1.07 MB ----
constexpr int OFF_PROTOS = 0;        // 32*640
constexpr int OFF_QPART  = 20480;    // 128*640 column partial sums (incl. shot fold)
constexpr int OFF_C      = 102400;   // 32
constexpr int OFF_BETA   = 102432;   // 32
constexpr int OFF_S      = 102464;   // 32
constexpr int OFF_U      = 102496;   // 32
constexpr int OFF_H1P    = 103584;   // 32*128 (per-way pr·W1a)
constexpr int OFF_TP     = 107680;   // 32*640
constexpr int OFF_G      = 128160;   // 32*4096 raw dots
constexpr int OFF_CNT    = 259552;   // 1 int
constexpr int OFF_Q2D    = 259556;   // double[4096] (even -> 8B aligned)
constexpr int OFF_X2D    = 267748;   // double[32] (proto_p norm^2)
constexpr int OFF_X2D2   = 267812;   // double[32] (test_proto norm^2)
constexpr int OFF_P2RAW  = 267876;   // double[32] (raw proto norm^2)

__device__ __forceinline__ double wave_sum_d(double v) {
#pragma unroll
  for (int o = 32; o > 0; o >>= 1) v += __shfl_down(v, o, 64);
  return v;
}

__device__ __forceinline__ float aloadf(const float* p) {
  return __hip_atomic_load(p, __ATOMIC_RELAXED, __HIP_MEMORY_SCOPE_AGENT);
}
__device__ __forceinline__ int aloadi(const int* p) {
  return __hip_atomic_load(p, __ATOMIC_RELAXED, __HIP_MEMORY_SCOPE_AGENT);
}

// f64 distance — used only in the OUTPUT path (gemm2 epilogue)
__device__ __forceinline__ double dist_hyp(double c, double xdotq, double u2, double q2) {
  const double EPSd = 1e-5;
  double sc = sqrt(c);
  double nq = sqrt(q2);
  double nf = fmax(nq, EPSd);
  double th = tanh(sc * nf);
  double al = th / (sc * nf);
  double ny = fmax(al * nq, EPSd);
  double mx = 0.999 / sc;
  if (ny > mx) al *= mx / ny;
  double y2 = al * al * q2;
  double uy = -al * xdotq;
  double A = 1.0 + 2.0 * c * uy + c * y2;
  double B = 1.0 - c * u2;
  double den = fmax(1.0 + 2.0 * c * uy + c * c * u2 * y2, EPSd);
  double num2 = fmax(A * A * u2 + 2.0 * A * B * uy + B * B * y2, 0.0);
  double n = sqrt(num2) / den;
  double arg = sc * n;
  const double CLIP = (double)(1.0f - 1e-5f);
  arg = fmin(fmax(arg, 0.0), CLIP);
  return (1.0 / sc) * log((1.0 + arg) / (1.0 - arg));
}

// f32 fast distance — selection/stats only
__device__ __forceinline__ float dist_f32(float c, float xdotq, float u2, float q2) {
  const float EPSf = 1e-5f;
  float sc = sqrtf(c);
  float nq = sqrtf(q2);
  float nf = fmaxf(nq, EPSf);
  float th = tanhf(sc * nf);
  float al = th / (sc * nf);
  float ny = fmaxf(al * nq, EPSf);
  float mx = 0.999f / sc;
  if (ny > mx) al *= mx / ny;
  float y2 = al * al * q2;
  float uy = -al * xdotq;
  float A = 1.f + 2.f * c * uy + c * y2;
  float B = 1.f - c * u2;
  float den = fmaxf(1.f + 2.f * c * uy + c * c * u2 * y2, EPSf);
  float num2 = fmaxf(A * A * u2 + 2.f * A * B * uy + B * B * y2, 0.f);
  float n = sqrtf(num2) / den;
  float arg = sc * n;
  arg = fminf(fmaxf(arg, 0.f), 1.f - 1e-5f);
  return (1.f / sc) * logf((1.f + arg) / (1.f - arg));
}

__device__ __forceinline__ double expmap_scale(double c, double p2, double* u2out) {
  double sc = sqrt(c);
  double ntrue = sqrt(p2);
  double nf = fmax(ntrue, 1e-5);
  double th = tanh(sc * nf);
  double s0 = th / (sc * nf);
  double ny = fmax(s0 * ntrue, 1e-5);
  double mx = 0.999 / sc;
  if (ny > mx) s0 *= mx / ny;
  *u2out = s0 * s0 * p2;
  return s0;
}

// grid 128 x 640: protos + P2RAW + H1P (b<32), per-row q2, QPART (+shot fold), CNT reset
__global__ __launch_bounds__(640) void k_fuse1(const float* __restrict__ Qm,
                                               const float* __restrict__ shot,
                                               const float* __restrict__ W1, float* ws) {
  __shared__ double q2w[32][10];
  __shared__ double psred[10];
  __shared__ float pr[DIM];
  __shared__ float h1pp[5][128];
  int b = blockIdx.x, t = threadIdx.x;
  int lane = t & 63, wid = t >> 6;  // 10 waves
  float protoval = 0.f;
  if (b < WAY) {
    float s = 0.f;
#pragma unroll
    for (int s5 = 0; s5 < NSHOT; ++s5) s += shot[(size_t)(s5 * WAY + b) * DIM + t];
    protoval = s * 0.2f;
    pr[t] = protoval;
    ws[OFF_PROTOS + b * DIM + t] = protoval;
    double pv2 = (double)protoval * protoval;
    pv2 = wave_sum_d(pv2);
    if (lane == 0) psred[wid] = pv2;
  }
  int r0 = b * 32;
  float colacc = 0.f;
  for (int r = 0; r < 32; ++r) {
    float v = Qm[(size_t)(r0 + r) * DIM + t];
    colacc += v;
    double sq = (double)v * v;
    sq = wave_sum_d(sq);
    if (lane == 0) q2w[r][wid] = sq;
  }
  ws[OFF_QPART + b * DIM + t] = colacc + 5.f * protoval;
  __syncthreads();
  if (t < 32) {
    double s = 0.0;
#pragma unroll
    for (int k = 0; k < 10; ++k) s += q2w[t][k];
    ((double*)(ws + OFF_Q2D))[r0 + t] = s;
  }
  if (b < WAY) {
    int n = t & 127, s = t >> 7;
    int k0 = s * 128;
    float acc = 0.f;
#pragma unroll 8
    for (int k = k0; k < k0 + 128; ++k) acc = fmaf(pr[k], W1[(size_t)k * 128 + n], acc);
    h1pp[s][n] = acc;
    __syncthreads();
    if (t < 128)
      ws[OFF_H1P + b * 128 + t] = h1pp[0][t] + h1pp[1][t] + h1pp[2][t] + h1pp[3][t] + h1pp[4][t];
    if (t == 0) {
      double p2 = 0.0;
#pragma unroll
      for (int k = 0; k < 10; ++k) p2 += psred[k];
      ((double*)(ws + OFF_P2RAW))[b] = p2;
    }
  }
  if (b == 0 && t == 0) ((int*)(ws + OFF_CNT))[0] = 0;
}

// grid 513 x 256: blocks 0..511 raw-dot GEMM G[w][q]=protos[w]·q; block 512 = ctrl-lite
struct GemmSm { float S[2][40][68]; };
struct CtrlSm {
  float am[DIM];
  float part[2][128];
  float h1s[WAY][128];
  float h2s[WAY][64];
  float lg[WAY][5];
};
union Sm1 { GemmSm g; CtrlSm c; };

__global__ __launch_bounds__(256) void k_gemm1(const float* __restrict__ Qm,
                                               const float* __restrict__ W1, const float* __restrict__ b1,
                                               const float* __restrict__ W2, const float* __restrict__ b2,
                                               const float* __restrict__ W3, const float* __restrict__ b3,
                                               float* __restrict__ ws) {
  __shared__ Sm1 sm;
  int t = threadIdx.x;
  if (blockIdx.x < 512) {
    const float* X = ws + OFF_PROTOS;
    int q0 = blockIdx.x * 8;
    int rowA = t >> 4, quadA = t & 15;
    int rowB = (t + 256) >> 4;
    int rowC = (t + 512) >> 4;
    bool hasC = (t < 128);
    const float* srcA = (rowA < 8 ? Qm + (size_t)(q0 + rowA) * DIM : X + (size_t)(rowA - 8) * DIM) + quadA * 4;
    const float* srcB = X + (size_t)(rowB - 8) * DIM + quadA * 4;
    const float* srcC = X + (size_t)(rowC - 8) * DIM + quadA * 4;
    float4 pA = *(const float4*)srcA;
    float4 pB = *(const float4*)srcB;
    float4 pC = {0.f, 0.f, 0.f, 0.f};
    if (hasC) pC = *(const float4*)srcC;
    *(float4*)&sm.g.S[0][rowA][quadA * 4] = pA;
    *(float4*)&sm.g.S[0][rowB][quadA * 4] = pB;
    if (hasC) *(float4*)&sm.g.S[0][rowC][quadA * 4] = pC;
    __syncthreads();
    int q = t & 7, w = t >> 3;
    float ax = 0.f, ay = 0.f, az = 0.f, aw = 0.f;
    for (int c = 0; c < 10; ++c) {
      int bsel = c & 1;
      if (c < 9) {
        size_t kc = (size_t)(c + 1) * 64;
        pA = *(const float4*)(srcA + kc);
        pB = *(const float4*)(srcB + kc);
        if (hasC) pC = *(const float4*)(srcC + kc);
      }
      const float* qr = &sm.g.S[bsel][q][0];
      const float* xr = &sm.g.S[bsel][8 + w][0];
#pragma unroll
      for (int kk = 0; kk < 64; kk += 4) {
        float4 qv = *(const float4*)(qr + kk);
        float4 xv = *(const float4*)(xr + kk);
        ax = fmaf(qv.x, xv.x, ax);
        ay = fmaf(qv.y, xv.y, ay);
        az = fmaf(qv.z, xv.z, az);
        aw = fmaf(qv.w, xv.w, aw);
      }
      if (c < 9) {
        int nb = bsel ^ 1;
        *(float4*)&sm.g.S[nb][rowA][quadA * 4] = pA;
        *(float4*)&sm.g.S[nb][rowB][quadA * 4] = pB;
        if (hasC) *(float4*)&sm.g.S[nb][rowC][quadA * 4] = pC;
        __syncthreads();
      }
    }
    ws[OFF_G + (size_t)w * NQ + q0 + q] = (ax + ay) + (az + aw);
  } else {
    // ---- ctrl-lite ----
    if (t < 160) {
      float4 a = {0.f, 0.f, 0.f, 0.f};
#pragma unroll 4
      for (int p = 0; p < 128; ++p) {
        float4 v = *(const float4*)&ws[OFF_QPART + p * DIM + t * 4];
        a.x += v.x; a.y += v.y; a.z += v.z; a.w += v.w;
      }
      sm.c.am[t * 4 + 0] = a.x / 4256.f;
      sm.c.am[t * 4 + 1] = a.y / 4256.f;
      sm.c.am[t * 4 + 2] = a.z / 4256.f;
      sm.c.am[t * 4 + 3] = a.w / 4256.f;
    }
    __syncthreads();
    {
      int n = t & 127, s = t >> 7;     // 2 k-slices of 320
      int k0 = s * 320;
      float acc = 0.f;
#pragma unroll 8
      for (int k = k0; k < k0 + 320; ++k)
        acc = fmaf(sm.c.am[k], W1[(size_t)(DIM + k) * 128 + n], acc);
      sm.c.part[s][n] = acc;
    }
    __syncthreads();
#pragma unroll
    for (int i = 0; i < 16; ++i) {
      int idx = i * 256 + t;
      int w = idx >> 7, n = idx & 127;
      sm.c.h1s[w][n] = fmaxf(ws[OFF_H1P + w * 128 + n] + sm.c.part[0][n] + sm.c.part[1][n] + b1[n], 0.f);
    }
    __syncthreads();
#pragma unroll
    for (int i = 0; i < 8; ++i) {
      int idx = i * 256 + t;
      int w = idx >> 6, n = idx & 63;
      float acc = 0.f;
      for (int k = 0; k < 128; ++k) acc = fmaf(sm.c.h1s[w][k], W2[(size_t)k * 64 + n], acc);
      sm.c.h2s[w][n] = fmaxf(acc + b2[n], 0.f);
    }
    __syncthreads();
    if (t < 160) {
      int w = t / 5, j = t - (t / 5) * 5;
      float acc = b3[j];
      for (int k = 0; k < 64; ++k) acc = fmaf(sm.c.h2s[w][k], W3[k * 5 + j], acc);
      sm.c.lg[w][j] = acc;
    }
    __syncthreads();
    if (t < WAY) {
      double m = sm.c.lg[t][0];
      for (int i = 1; i < 5; ++i) m = fmax(m, (double)sm.c.lg[t][i]);
      double se = 0.0, cv = 0.0;
      for (int i = 0; i < 5; ++i) { double e = exp((double)sm.c.lg[t][i] - m); se += e; cv += e * 0.2 * (double)(i + 1); }
      double c = cv / se;
      ws[OFF_C + t] = (float)c;
      double p2 = ((const double*)(ws + OFF_P2RAW))[t];
      double u2;
      double beta = expmap_scale(c, p2, &u2);
      ws[OFF_BETA + t] = (float)beta;
      ((double*)(ws + OFF_X2D))[t] = u2;
    }
  }
}

// grid 32 x 1024: per-way dists + stable top-10 + S/U + stats; 32-block spin
// barrier; then EACH block does its own way's refine + tmp -> TP (parallel).
__global__ __launch_bounds__(1024) void k_topkref(const float* __restrict__ Qm,
                                                  const float* __restrict__ Wr1, const float* __restrict__ br1,
                                                  const float* __restrict__ Wr2, const float* __restrict__ br2,
                                                  float* __restrict__ ws) {
  __shared__ double sredS[16], sredU[16];
  __shared__ float cval[160];
  __shared__ int cidx[160];
  __shared__ float qvsh[RNEAR];
  __shared__ int qjsh[RNEAR];
  __shared__ float colsh[RNEAR][33];
  __shared__ float pcpart[RNEAR];
  __shared__ float rrl[22];
  __shared__ float Ssh[WAY], Ush[WAY];
  __shared__ float hr[RNEAR], orsh[11], iw[RNEAR];
  __shared__ float onw_sh;
  __shared__ double p2red[10];
  __shared__ double gshd;

  int w = blockIdx.x, t = threadIdx.x;
  int lane = t & 63, wid = t >> 6;
  const double* q2d = (const double*)(ws + OFF_Q2D);
  const double* x2d = (const double*)(ws + OFF_X2D);
  float cf = ws[OFF_C + w];
  float betaf = ws[OFF_BETA + w];
  float u2f = (float)x2d[w];
  const float* gb = ws + OFF_G + (size_t)w * NQ;
  float v0 = dist_f32(cf, betaf * gb[t],        u2f, (float)q2d[t]);
  float v1 = dist_f32(cf, betaf * gb[1024 + t], u2f, (float)q2d[1024 + t]);
  float v2 = dist_f32(cf, betaf * gb[2048 + t], u2f, (float)q2d[2048 + t]);
  float v3 = dist_f32(cf, betaf * gb[3072 + t], u2f, (float)q2d[3072 + t]);
  unsigned tk = 0;
  double s = (double)v0 + (double)v1 + (double)v2 + (double)v3;
  double u = (t < RNEAR) ? (double)v0 : 0.0;
  s = wave_sum_d(s);
  u = wave_sum_d(u);
  if (lane == 0) { sredS[wid] = s; sredU[wid] = u; }
  // stage 1: per-wave top-10
  for (int r = 0; r < RNEAR; ++r) {
    float lv = INFINITY; int li = 0x7fffffff;
    if (!(tk & 1u) && (v0 < lv || (v0 == lv && t < li)))        { lv = v0; li = t; }
    if (!(tk & 2u) && (v1 < lv || (v1 == lv && 1024 + t < li))) { lv = v1; li = 1024 + t; }
    if (!(tk & 4u) && (v2 < lv || (v2 == lv && 2048 + t < li))) { lv = v2; li = 2048 + t; }
    if (!(tk & 8u) && (v3 < lv || (v3 == lv && 3072 + t < li))) { lv = v3; li = 3072 + t; }
#pragma unroll
    for (int o = 32; o > 0; o >>= 1) {
      float ov = __shfl_xor(lv, o, 64);
      int oi = __shfl_xor(li, o, 64);
      if (ov < lv || (ov == lv && oi < li)) { lv = ov; li = oi; }
    }
    if (lane == 0) { cval[wid * RNEAR + r] = lv; cidx[wid * RNEAR + r] = li; }
    if ((li & 1023) == t) tk |= 1u << (li >> 10);
  }
  __syncthreads();
  if (t == 0) {
    double S = 0.0, U = 0.0;
    for (int k = 0; k < 16; ++k) { S += sredS[k]; U += sredU[k]; }
    ws[OFF_S + w] = (float)S;
    ws[OFF_U + w] = (float)U;
  }
  if (t < 64) {   // stage 2: wave 0 merges 160 candidates
    float c0 = cval[t], c1 = cval[t + 64];
    int i0 = cidx[t], i1 = cidx[t + 64];
    float c2 = (t < 32) ? cval[t + 128] : INFINITY;
    int i2 = (t < 32) ? cidx[t + 128] : 0x7fffffff;
    unsigned m = 0;
    for (int r = 0; r < RNEAR; ++r) {
      float lv = INFINITY; int li = 0x7fffffff;
      if (!(m & 1u) && (c0 < lv || (c0 == lv && i0 < li))) { lv = c0; li = i0; }
      if (!(m & 2u) && (c1 < lv || (c1 == lv && i1 < li))) { lv = c1; li = i1; }
      if (!(m & 4u) && (c2 < lv || (c2 == lv && i2 < li))) { lv = c2; li = i2; }
#pragma unroll
      for (int o = 32; o > 0; o >>= 1) {
        float ov = __shfl_xor(lv, o, 64);
        int oi = __shfl_xor(li, o, 64);
        if (ov < lv || (ov == lv && oi < li)) { lv = ov; li = oi; }
      }
      if (lane == 0) { qvsh[r] = lv; qjsh[r] = li; }
      if (i0 == li) m |= 1u;
      if (i1 == li) m |= 2u;
      if (i2 == li) m |= 4u;
    }
  }
  __syncthreads();
  // per-way stats: colsh[j][w2] = dist(w2, qj[j]) from raw G (f32 fast path)
  if (t < WAY * RNEAR) {
    int j = t >> 5, w2 = t & 31;
    int q = qjsh[j];
    colsh[j][w2] = dist_f32(ws[OFF_C + w2], ws[OFF_BETA + w2] * ws[OFF_G + (size_t)w2 * NQ + q],
                            (float)x2d[w2], (float)q2d[q]);
  }
  __syncthreads();
  if (t < RNEAR) {
    double cs = 0.0, pc = 0.0;
    for (int w2 = 0; w2 < WAY; ++w2) {
      float dv = colsh[t][w2];
      cs += dv;
      if (w2 < w) pc += dv;
    }
    rrl[t] = qvsh[t];
    rrl[RNEAR + t] = (float)((cs - qvsh[t]) / (double)(WAY - 1));
    pcpart[t] = (float)pc;
  }
  __syncthreads();
  if (t == 0) {
    double sn = 0.0;
    for (int j = 0; j < RNEAR; ++j) sn += qvsh[j];
    double S = (double)ws[OFF_S + w];
    rrl[20] = (float)((S - sn) / (double)(NQ - RNEAR));
  }
  // ---- 32-block spin barrier (all blocks co-resident: grid=32 << 256 CUs) ----
  __threadfence();
  __syncthreads();
  if (t == 0) {
    atomicAdd((int*)(ws + OFF_CNT), 1);
    while (aloadi((const int*)(ws + OFF_CNT)) < WAY) __builtin_amdgcn_s_sleep(8);
  }
  __syncthreads();
  __threadfence();
  // ---- parallel tail: this block handles its OWN way ----
  if (t < WAY) { Ssh[t] = aloadf(ws + OFF_S + t); Ush[t] = aloadf(ws + OFF_U + t); }
  __syncthreads();
  if (t == 0) {
    double pref = 0.0, suf = 0.0;
    for (int j = 0; j < w; ++j) pref += (double)Ssh[j];
    for (int j = w + 1; j < WAY; ++j) suf += (double)Ssh[j] - (double)Ush[j];
    double spc = 0.0;
    for (int j = 0; j < RNEAR; ++j) spc += (double)pcpart[j];
    rrl[21] = (float)((pref - spc + suf) / ((double)(WAY - 1) * (double)(NQ - RNEAR)));
  }
  __syncthreads();
  if (t < RNEAR) {
    float a = br1[t];
    for (int k = 0; k < 22; ++k) a = fmaf(rrl[k], Wr1[k * RNEAR + t], a);
    hr[t] = fmaxf(a, 0.f);
  }
  __syncthreads();
  if (t < 11) {
    float a = br2[t];
    for (int k = 0; k < RNEAR; ++k) a = fmaf(hr[k], Wr2[k * 11 + t], a);
    orsh[t] = a;
  }
  __syncthreads();
  if (t == 0) {
    double m = orsh[0];
    for (int i = 1; i < RNEAR; ++i) m = fmax(m, (double)orsh[i]);
    double se = 0.0; double e[RNEAR];
    for (int i = 0; i < RNEAR; ++i) { e[i] = exp((double)orsh[i] - m); se += e[i]; }
    for (int i = 0; i < RNEAR; ++i) iw[i] = (float)(e[i] / se);
    onw_sh = (float)(1.0 / (1.0 + exp(-(double)orsh[10])));
  }
  __syncthreads();
  float a0 = 0.f;
  double ls = 0.0;
  if (t < DIM) {
    float onwv = onw_sh;
    float wd = 0.f;
#pragma unroll
    for (int j = 0; j < RNEAR; ++j)
      wd = fmaf(Qm[(size_t)qjsh[j] * DIM + t], iw[j], wd);
    a0 = ws[OFF_PROTOS + w * DIM + t] * onwv + wd * (1.f - onwv);
    ls = (double)a0 * a0;
  }
  ls = wave_sum_d(ls);
  if (lane == 0 && wid < 10) p2red[wid] = ls;
  __syncthreads();
  if (t == 0) {
    double p2 = 0.0;
#pragma unroll
    for (int k = 0; k < 10; ++k) p2 += p2red[k];
    double u22;
    gshd = expmap_scale((double)ws[OFF_C + w], p2, &u22);
    ((double*)(ws + OFF_X2D2))[w] = u22;
  }
  __syncthreads();
  if (t < DIM) ws[OFF_TP + w * DIM + t] = (float)gshd * a0;
}

// grid 512 x 256: TP·q GEMM + fused f64 dist epilogue -> out (R10/R11-proven)
__global__ __launch_bounds__(256) void k_gemm2(const float* __restrict__ Qm,
                                               float* __restrict__ ws, float* __restrict__ out) {
  __shared__ float S[2][40][68];
  const float* X = ws + OFF_TP;
  int t = threadIdx.x;
  int q0 = blockIdx.x * 8;
  int rowA = t >> 4, quadA = t & 15;
  int rowB = (t + 256) >> 4;
  int rowC = (t + 512) >> 4;
  bool hasC = (t < 128);
  const float* srcA = (rowA < 8 ? Qm + (size_t)(q0 + rowA) * DIM : X + (size_t)(rowA - 8) * DIM) + quadA * 4;
  const float* srcB = X + (size_t)(rowB - 8) * DIM + quadA * 4;
  const float* srcC = X + (size_t)(rowC - 8) * DIM + quadA * 4;
  float4 pA = *(const float4*)srcA;
  float4 pB = *(const float4*)srcB;
  float4 pC = {0.f, 0.f, 0.f, 0.f};
  if (hasC) pC = *(const float4*)srcC;
  *(float4*)&S[0][rowA][quadA * 4] = pA;
  *(float4*)&S[0][rowB][quadA * 4] = pB;
  if (hasC) *(float4*)&S[0][rowC][quadA * 4] = pC;
  __syncthreads();
  int q = t & 7, w = t >> 3;
  float ax = 0.f, ay = 0.f, az = 0.f, aw = 0.f;
  for (int c = 0; c < 10; ++c) {
    int bsel = c & 1;
    if (c < 9) {
      size_t kc = (size_t)(c + 1) * 64;
      pA = *(const float4*)(srcA + kc);
      pB = *(const float4*)(srcB + kc);
      if (hasC) pC = *(const float4*)(srcC + kc);
    }
    const float* qr = &S[bsel][q][0];
    const float* xr = &S[bsel][8 + w][0];
#pragma unroll
    for (int kk = 0; kk < 64; kk += 4) {
      float4 qv = *(const float4*)(qr + kk);
      float4 xv = *(const float4*)(xr + kk);
      ax = fmaf(qv.x, xv.x, ax);
      ay = fmaf(qv.y, xv.y, ay);
      az = fmaf(qv.z, xv.z, az);
      aw = fmaf(qv.w, xv.w, aw);
    }
    if (c < 9) {
      int nb = bsel ^ 1;
      *(float4*)&S[nb][rowA][quadA * 4] = pA;
      *(float4*)&S[nb][rowB][quadA * 4] = pB;
      if (hasC) *(float4*)&S[nb][rowC][quadA * 4] = pC;
      __syncthreads();
    }
  }
  float acc = (ax + ay) + (az + aw);
  const double* q2d = (const double*)(ws + OFF_Q2D);
  const double* u2arr = (const double*)(ws + OFF_X2D2);
  int qq = q0 + q;
  double d = dist_hyp((double)ws[OFF_C + w], (double)acc, u2arr[w], q2d[qq]);
  out[(size_t)qq * WAY + w] = (float)(-d / 16.0);
}

extern "C" void kernel_launch(void* const* d_in, const int* in_sizes, int n_in,
                              void* d_out, int out_size, void* d_ws, size_t ws_size,
                              hipStream_t stream) {
  (void)in_sizes; (void)n_in; (void)out_size; (void)ws_size;
  const float* shot = (const float*)d_in[0];
  const float* qry  = (const float*)d_in[1];
  const float* W1   = (const float*)d_in[2];
  const float* b1   = (const float*)d_in[3];
  const float* W2   = (const float*)d_in[4];
  const float* b2   = (const float*)d_in[5];
  const float* W3   = (const float*)d_in[6];
  const float* b3   = (const float*)d_in[7];
  const float* Wr1  = (const float*)d_in[8];
  const float* br1  = (const float*)d_in[9];
  const float* Wr2  = (const float*)d_in[10];
  const float* br2  = (const float*)d_in[11];
  float* ws = (float*)d_ws;
  float* out = (float*)d_out;

  hipLaunchKernelGGL(k_fuse1,   dim3(128), dim3(640), 0, stream, qry, shot, W1, ws);
  hipLaunchKernelGGL(k_gemm1,   dim3(513), dim3(256), 0, stream, qry, W1, b1, W2, b2, W3, b3, ws);
  hipLaunchKernelGGL(k_topkref, dim3(32), dim3(1024), 0, stream, qry, Wr1, br1, Wr2, br2, ws);
  hipLaunchKernelGGL(k_gemm2,   dim3(512), dim3(256), 0, stream, qry, ws, out);
}

// Round 16
// 102.651 us; speedup vs baseline: 1.3147x; 1.1333x over previous
//
#include <hip/hip_runtime.h>
#include <math.h>

#define NSHOT 5
#define WAY 32
#define DIM 640
#define NQ 4096
#define RNEAR 10

// ---- workspace layout (float offsets), ~1.07 MB ----
constexpr int OFF_PROTOS = 0;        // 32*640
constexpr int OFF_QPART  = 20480;    // 128*640 column partial sums (incl. shot fold)
constexpr int OFF_C      = 102400;   // 32
constexpr int OFF_BETA   = 102432;   // 32
constexpr int OFF_S      = 102464;   // 32
constexpr int OFF_U      = 102496;   // 32
constexpr int OFF_NID    = 102528;   // 32*10
constexpr int OFF_RR     = 102848;   // 32*22
constexpr int OFF_SPC    = 103552;   // 32
constexpr int OFF_H1P    = 103584;   // 32*128 (per-way pr·W1a)
constexpr int OFF_TP     = 107680;   // 32*640
constexpr int OFF_G      = 128160;   // 32*4096 raw dots
constexpr int OFF_NIDX   = 259232;   // 32*10 ints
constexpr int OFF_Q2D    = 259556;   // double[4096] (byte-offset %8 == 0)
constexpr int OFF_X2D    = 267748;   // double[32] (proto_p norm^2)
constexpr int OFF_X2D2   = 267812;   // double[32] (test_proto norm^2)
constexpr int OFF_P2RAW  = 267876;   // double[32] (raw proto norm^2)

__device__ __forceinline__ double wave_sum_d(double v) {
#pragma unroll
  for (int o = 32; o > 0; o >>= 1) v += __shfl_down(v, o, 64);
  return v;
}

// f64 distance — OUTPUT path only (gemm2 epilogue)
__device__ __forceinline__ double dist_hyp(double c, double xdotq, double u2, double q2) {
  const double EPSd = 1e-5;
  double sc = sqrt(c);
  double nq = sqrt(q2);
  double nf = fmax(nq, EPSd);
  double th = tanh(sc * nf);
  double al = th / (sc * nf);
  double ny = fmax(al * nq, EPSd);
  double mx = 0.999 / sc;
  if (ny > mx) al *= mx / ny;
  double y2 = al * al * q2;
  double uy = -al * xdotq;
  double A = 1.0 + 2.0 * c * uy + c * y2;
  double B = 1.0 - c * u2;
  double den = fmax(1.0 + 2.0 * c * uy + c * c * u2 * y2, EPSd);
  double num2 = fmax(A * A * u2 + 2.0 * A * B * uy + B * B * y2, 0.0);
  double n = sqrt(num2) / den;
  double arg = sc * n;
  const double CLIP = (double)(1.0f - 1e-5f);
  arg = fmin(fmax(arg, 0.0), CLIP);
  return (1.0 / sc) * log((1.0 + arg) / (1.0 - arg));
}

// f32 fast distance — selection/stats only
__device__ __forceinline__ float dist_f32(float c, float xdotq, float u2, float q2) {
  const float EPSf = 1e-5f;
  float sc = sqrtf(c);
  float nq = sqrtf(q2);
  float nf = fmaxf(nq, EPSf);
  float th = tanhf(sc * nf);
  float al = th / (sc * nf);
  float ny = fmaxf(al * nq, EPSf);
  float mx = 0.999f / sc;
  if (ny > mx) al *= mx / ny;
  float y2 = al * al * q2;
  float uy = -al * xdotq;
  float A = 1.f + 2.f * c * uy + c * y2;
  float B = 1.f - c * u2;
  float den = fmaxf(1.f + 2.f * c * uy + c * c * u2 * y2, EPSf);
  float num2 = fmaxf(A * A * u2 + 2.f * A * B * uy + B * B * y2, 0.f);
  float n = sqrtf(num2) / den;
  float arg = sc * n;
  arg = fminf(fmaxf(arg, 0.f), 1.f - 1e-5f);
  return (1.f / sc) * logf((1.f + arg) / (1.f - arg));
}

__device__ __forceinline__ double expmap_scale(double c, double p2, double* u2out) {
  double sc = sqrt(c);
  double ntrue = sqrt(p2);
  double nf = fmax(ntrue, 1e-5);
  double th = tanh(sc * nf);
  double s0 = th / (sc * nf);
  double ny = fmax(s0 * ntrue, 1e-5);
  double mx = 0.999 / sc;
  if (ny > mx) s0 *= mx / ny;
  *u2out = s0 * s0 * p2;
  return s0;
}

// grid 128 x 640: protos + P2RAW + H1P (b<32), per-row q2, QPART (+shot fold)
__global__ __launch_bounds__(640) void k_fuse1(const float* __restrict__ Qm,
                                               const float* __restrict__ shot,
                                               const float* __restrict__ W1, float* ws) {
  __shared__ double q2w[32][10];
  __shared__ double psred[10];
  __shared__ float pr[DIM];
  __shared__ float h1pp[5][128];
  int b = blockIdx.x, t = threadIdx.x;
  int lane = t & 63, wid = t >> 6;  // 10 waves
  float protoval = 0.f;
  if (b < WAY) {
    float s = 0.f;
#pragma unroll
    for (int s5 = 0; s5 < NSHOT; ++s5) s += shot[(size_t)(s5 * WAY + b) * DIM + t];
    protoval = s * 0.2f;
    pr[t] = protoval;
    ws[OFF_PROTOS + b * DIM + t] = protoval;
    double pv2 = (double)protoval * protoval;
    pv2 = wave_sum_d(pv2);
    if (lane == 0) psred[wid] = pv2;
  }
  int r0 = b * 32;
  float colacc = 0.f;
  for (int r = 0; r < 32; ++r) {
    float v = Qm[(size_t)(r0 + r) * DIM + t];
    colacc += v;
    double sq = (double)v * v;
    sq = wave_sum_d(sq);
    if (lane == 0) q2w[r][wid] = sq;
  }
  ws[OFF_QPART + b * DIM + t] = colacc + 5.f * protoval;
  __syncthreads();
  if (t < 32) {
    double s = 0.0;
#pragma unroll
    for (int k = 0; k < 10; ++k) s += q2w[t][k];
    ((double*)(ws + OFF_Q2D))[r0 + t] = s;
  }
  if (b < WAY) {
    int n = t & 127, s = t >> 7;
    int k0 = s * 128;
    float acc = 0.f;
#pragma unroll 8
    for (int k = k0; k < k0 + 128; ++k) acc = fmaf(pr[k], W1[(size_t)k * 128 + n], acc);
    h1pp[s][n] = acc;
    __syncthreads();
    if (t < 128)
      ws[OFF_H1P + b * 128 + t] = h1pp[0][t] + h1pp[1][t] + h1pp[2][t] + h1pp[3][t] + h1pp[4][t];
    if (t == 0) {
      double p2 = 0.0;
#pragma unroll
      for (int k = 0; k < 10; ++k) p2 += psred[k];
      ((double*)(ws + OFF_P2RAW))[b] = p2;
    }
  }
}

// grid 32 x 256: per-way ctrl MLP. Each block redundantly reduces QPART->am
// (parallel across ways; R11-proven pattern), then its own way's MLP via H1P.
__global__ __launch_bounds__(256) void k_ctrl(const float* __restrict__ W1, const float* __restrict__ b1,
                                              const float* __restrict__ W2, const float* __restrict__ b2,
                                              const float* __restrict__ W3, const float* __restrict__ b3,
                                              float* ws) {
  __shared__ float am[DIM];
  __shared__ float part[2][128];
  __shared__ float h1s[128], h2s[64], lg[5];
  int w = blockIdx.x, t = threadIdx.x;
  if (t < 160) {
    float4 a = {0.f, 0.f, 0.f, 0.f};
#pragma unroll 4
    for (int p = 0; p < 128; ++p) {
      float4 v = *(const float4*)&ws[OFF_QPART + p * DIM + t * 4];
      a.x += v.x; a.y += v.y; a.z += v.z; a.w += v.w;
    }
    am[t * 4 + 0] = a.x / 4256.f;
    am[t * 4 + 1] = a.y / 4256.f;
    am[t * 4 + 2] = a.z / 4256.f;
    am[t * 4 + 3] = a.w / 4256.f;
  }
  __syncthreads();
  {
    int n = t & 127, s = t >> 7;     // 2 k-slices of 320
    int k0 = s * 320;
    float acc = 0.f;
#pragma unroll 8
    for (int k = k0; k < k0 + 320; ++k)
      acc = fmaf(am[k], W1[(size_t)(DIM + k) * 128 + n], acc);
    part[s][n] = acc;
  }
  __syncthreads();
  if (t < 128) h1s[t] = fmaxf(ws[OFF_H1P + w * 128 + t] + part[0][t] + part[1][t] + b1[t], 0.f);
  __syncthreads();
  if (t < 64) {
    float acc = b2[t];
    for (int k = 0; k < 128; ++k) acc = fmaf(h1s[k], W2[(size_t)k * 64 + t], acc);
    h2s[t] = fmaxf(acc, 0.f);
  }
  __syncthreads();
  if (t < 5) {
    float acc = b3[t];
    for (int k = 0; k < 64; ++k) acc = fmaf(h2s[k], W3[k * 5 + t], acc);
    lg[t] = acc;
  }
  __syncthreads();
  if (t == 0) {
    double m = lg[0];
    for (int i = 1; i < 5; ++i) m = fmax(m, (double)lg[i]);
    double se = 0.0, cv = 0.0;
    for (int i = 0; i < 5; ++i) { double e = exp((double)lg[i] - m); se += e; cv += e * 0.2 * (double)(i + 1); }
    double c = cv / se;
    ws[OFF_C + w] = (float)c;
    double p2 = ((const double*)(ws + OFF_P2RAW))[w];
    double u2;
    double beta = expmap_scale(c, p2, &u2);
    ws[OFF_BETA + w] = (float)beta;
    ((double*)(ws + OFF_X2D))[w] = u2;
  }
}

// grid 512 x 256: GEMM (X rows 0..31) vs 8 q-rows; mode 0: raw G; mode 1: f64 dist -> out
__global__ __launch_bounds__(256) void k_gemm(const float* __restrict__ X, const float* __restrict__ Qm,
                                              float* __restrict__ ws, int mode, float* __restrict__ out) {
  __shared__ float S[2][40][68];
  int t = threadIdx.x;
  int q0 = blockIdx.x * 8;
  int rowA = t >> 4, quadA = t & 15;
  int rowB = (t + 256) >> 4;
  int rowC = (t + 512) >> 4;
  bool hasC = (t < 128);
  const float* srcA = (rowA < 8 ? Qm + (size_t)(q0 + rowA) * DIM : X + (size_t)(rowA - 8) * DIM) + quadA * 4;
  const float* srcB = X + (size_t)(rowB - 8) * DIM + quadA * 4;
  const float* srcC = X + (size_t)(rowC - 8) * DIM + quadA * 4;
  float4 pA = *(const float4*)srcA;
  float4 pB = *(const float4*)srcB;
  float4 pC = {0.f, 0.f, 0.f, 0.f};
  if (hasC) pC = *(const float4*)srcC;
  *(float4*)&S[0][rowA][quadA * 4] = pA;
  *(float4*)&S[0][rowB][quadA * 4] = pB;
  if (hasC) *(float4*)&S[0][rowC][quadA * 4] = pC;
  __syncthreads();
  int q = t & 7, w = t >> 3;
  float ax = 0.f, ay = 0.f, az = 0.f, aw = 0.f;
  for (int c = 0; c < 10; ++c) {
    int bsel = c & 1;
    if (c < 9) {
      size_t kc = (size_t)(c + 1) * 64;
      pA = *(const float4*)(srcA + kc);
      pB = *(const float4*)(srcB + kc);
      if (hasC) pC = *(const float4*)(srcC + kc);
    }
    const float* qr = &S[bsel][q][0];
    const float* xr = &S[bsel][8 + w][0];
#pragma unroll
    for (int kk = 0; kk < 64; kk += 4) {
      float4 qv = *(const float4*)(qr + kk);
      float4 xv = *(const float4*)(xr + kk);
      ax = fmaf(qv.x, xv.x, ax);
      ay = fmaf(qv.y, xv.y, ay);
      az = fmaf(qv.z, xv.z, az);
      aw = fmaf(qv.w, xv.w, aw);
    }
    if (c < 9) {
      int nb = bsel ^ 1;
      *(float4*)&S[nb][rowA][quadA * 4] = pA;
      *(float4*)&S[nb][rowB][quadA * 4] = pB;
      if (hasC) *(float4*)&S[nb][rowC][quadA * 4] = pC;
      __syncthreads();
    }
  }
  float acc = (ax + ay) + (az + aw);
  int qq = q0 + q;
  if (mode == 0) {
    ws[OFF_G + (size_t)w * NQ + qq] = acc;
  } else {
    const double* q2d = (const double*)(ws + OFF_Q2D);
    const double* u2arr = (const double*)(ws + OFF_X2D2);
    double d = dist_hyp((double)ws[OFF_C + w], (double)acc, u2arr[w], q2d[qq]);
    out[(size_t)qq * WAY + w] = (float)(-d / 16.0);
  }
}

// grid 32 x 1024: per-way f32 dists + stable top-10 + S/U + stats -> ws (no barrier/tail)
__global__ __launch_bounds__(1024) void k_topkA(float* __restrict__ ws) {
  __shared__ double sredS[16], sredU[16];
  __shared__ float cval[160];
  __shared__ int cidx[160];
  __shared__ float qvsh[RNEAR];
  __shared__ int qjsh[RNEAR];
  __shared__ float colsh[RNEAR][33];
  __shared__ float pcpart[RNEAR];
  int w = blockIdx.x, t = threadIdx.x;
  int lane = t & 63, wid = t >> 6;
  int* nidx = (int*)(ws + OFF_NIDX);
  const double* q2d = (const double*)(ws + OFF_Q2D);
  const double* x2d = (const double*)(ws + OFF_X2D);
  float cf = ws[OFF_C + w];
  float betaf = ws[OFF_BETA + w];
  float u2f = (float)x2d[w];
  const float* gb = ws + OFF_G + (size_t)w * NQ;
  float v0 = dist_f32(cf, betaf * gb[t],        u2f, (float)q2d[t]);
  float v1 = dist_f32(cf, betaf * gb[1024 + t], u2f, (float)q2d[1024 + t]);
  float v2 = dist_f32(cf, betaf * gb[2048 + t], u2f, (float)q2d[2048 + t]);
  float v3 = dist_f32(cf, betaf * gb[3072 + t], u2f, (float)q2d[3072 + t]);
  unsigned tk = 0;
  double s = (double)v0 + (double)v1 + (double)v2 + (double)v3;
  double u = (t < RNEAR) ? (double)v0 : 0.0;
  s = wave_sum_d(s);
  u = wave_sum_d(u);
  if (lane == 0) { sredS[wid] = s; sredU[wid] = u; }
  for (int r = 0; r < RNEAR; ++r) {
    float lv = INFINITY; int li = 0x7fffffff;
    if (!(tk & 1u) && (v0 < lv || (v0 == lv && t < li)))        { lv = v0; li = t; }
    if (!(tk & 2u) && (v1 < lv || (v1 == lv && 1024 + t < li))) { lv = v1; li = 1024 + t; }
    if (!(tk & 4u) && (v2 < lv || (v2 == lv && 2048 + t < li))) { lv = v2; li = 2048 + t; }
    if (!(tk & 8u) && (v3 < lv || (v3 == lv && 3072 + t < li))) { lv = v3; li = 3072 + t; }
#pragma unroll
    for (int o = 32; o > 0; o >>= 1) {
      float ov = __shfl_xor(lv, o, 64);
      int oi = __shfl_xor(li, o, 64);
      if (ov < lv || (ov == lv && oi < li)) { lv = ov; li = oi; }
    }
    if (lane == 0) { cval[wid * RNEAR + r] = lv; cidx[wid * RNEAR + r] = li; }
    if ((li & 1023) == t) tk |= 1u << (li >> 10);
  }
  __syncthreads();
  if (t == 0) {
    double S = 0.0, U = 0.0;
    for (int k = 0; k < 16; ++k) { S += sredS[k]; U += sredU[k]; }
    ws[OFF_S + w] = (float)S;
    ws[OFF_U + w] = (float)U;
  }
  if (t < 64) {
    float c0 = cval[t], c1 = cval[t + 64];
    int i0 = cidx[t], i1 = cidx[t + 64];
    float c2 = (t < 32) ? cval[t + 128] : INFINITY;
    int i2 = (t < 32) ? cidx[t + 128] : 0x7fffffff;
    unsigned m = 0;
    for (int r = 0; r < RNEAR; ++r) {
      float lv = INFINITY; int li = 0x7fffffff;
      if (!(m & 1u) && (c0 < lv || (c0 == lv && i0 < li))) { lv = c0; li = i0; }
      if (!(m & 2u) && (c1 < lv || (c1 == lv && i1 < li))) { lv = c1; li = i1; }
      if (!(m & 4u) && (c2 < lv || (c2 == lv && i2 < li))) { lv = c2; li = i2; }
#pragma unroll
      for (int o = 32; o > 0; o >>= 1) {
        float ov = __shfl_xor(lv, o, 64);
        int oi = __shfl_xor(li, o, 64);
        if (ov < lv || (ov == lv && oi < li)) { lv = ov; li = oi; }
      }
      if (lane == 0) { qvsh[r] = lv; qjsh[r] = li; }
      if (i0 == li) m |= 1u;
      if (i1 == li) m |= 2u;
      if (i2 == li) m |= 4u;
    }
  }
  __syncthreads();
  if (t < WAY * RNEAR) {
    int j = t >> 5, w2 = t & 31;
    int q = qjsh[j];
    colsh[j][w2] = dist_f32(ws[OFF_C + w2], ws[OFF_BETA + w2] * ws[OFF_G + (size_t)w2 * NQ + q],
                            (float)x2d[w2], (float)q2d[q]);
  }
  __syncthreads();
  if (t < RNEAR) {
    double cs = 0.0, pc = 0.0;
    for (int w2 = 0; w2 < WAY; ++w2) {
      float dv = colsh[t][w2];
      cs += dv;
      if (w2 < w) pc += dv;
    }
    ws[OFF_RR + w * 22 + t] = qvsh[t];
    ws[OFF_RR + w * 22 + RNEAR + t] = (float)((cs - qvsh[t]) / (double)(WAY - 1));
    ws[OFF_NID + w * RNEAR + t] = qvsh[t];
    nidx[w * RNEAR + t] = qjsh[t];
    pcpart[t] = (float)pc;
  }
  __syncthreads();
  if (t == 0) {
    double spc = 0.0, sn = 0.0;
    for (int j = 0; j < RNEAR; ++j) { spc += pcpart[j]; sn += qvsh[j]; }
    double S = (double)ws[OFF_S + w];
    ws[OFF_RR + w * 22 + 20] = (float)((S - sn) / (double)(NQ - RNEAR));
    ws[OFF_SPC + w] = (float)spc;
  }
}

// grid 32 x 640: per-way refine MLP + tmp/expmap -> TP
__global__ __launch_bounds__(640) void k_refB(const float* __restrict__ Qm,
                                              const float* __restrict__ Wr1, const float* __restrict__ br1,
                                              const float* __restrict__ Wr2, const float* __restrict__ br2,
                                              float* __restrict__ ws) {
  __shared__ float Ssh[WAY], Ush[WAY];
  __shared__ float rrl[22];
  __shared__ int qj[RNEAR];
  __shared__ float hr[RNEAR], orsh[11], iw[RNEAR];
  __shared__ float onw_sh;
  __shared__ double p2red[10];
  __shared__ double gshd;
  int w = blockIdx.x, t = threadIdx.x;
  int lane = t & 63, wid = t >> 6;  // 10 waves
  const int* nidx = (const int*)(ws + OFF_NIDX);
  if (t < WAY) { Ssh[t] = ws[OFF_S + t]; Ush[t] = ws[OFF_U + t]; }
  if (t >= 64 && t < 64 + 22) rrl[t - 64] = ws[OFF_RR + w * 22 + (t - 64)];
  if (t >= 96 && t < 96 + RNEAR) qj[t - 96] = nidx[w * RNEAR + (t - 96)];
  __syncthreads();
  if (t == 0) {
    double pref = 0.0, suf = 0.0;
    for (int j = 0; j < w; ++j) pref += (double)Ssh[j];
    for (int j = w + 1; j < WAY; ++j) suf += (double)Ssh[j] - (double)Ush[j];
    double spc = (double)ws[OFF_SPC + w];
    rrl[21] = (float)((pref - spc + suf) / ((double)(WAY - 1) * (double)(NQ - RNEAR)));
  }
  __syncthreads();
  if (t < RNEAR) {
    float a = br1[t];
    for (int k = 0; k < 22; ++k) a = fmaf(rrl[k], Wr1[k * RNEAR + t], a);
    hr[t] = fmaxf(a, 0.f);
  }
  __syncthreads();
  if (t < 11) {
    float a = br2[t];
    for (int k = 0; k < RNEAR; ++k) a = fmaf(hr[k], Wr2[k * 11 + t], a);
    orsh[t] = a;
  }
  __syncthreads();
  if (t == 0) {
    double m = orsh[0];
    for (int i = 1; i < RNEAR; ++i) m = fmax(m, (double)orsh[i]);
    double se = 0.0; double e[RNEAR];
    for (int i = 0; i < RNEAR; ++i) { e[i] = exp((double)orsh[i] - m); se += e[i]; }
    for (int i = 0; i < RNEAR; ++i) iw[i] = (float)(e[i] / se);
    onw_sh = (float)(1.0 / (1.0 + exp(-(double)orsh[10])));
  }
  __syncthreads();
  float onwv = onw_sh;
  float wd = 0.f;
#pragma unroll
  for (int j = 0; j < RNEAR; ++j)
    wd = fmaf(Qm[(size_t)qj[j] * DIM + t], iw[j], wd);
  float a0 = ws[OFF_PROTOS + w * DIM + t] * onwv + wd * (1.f - onwv);
  double ls = (double)a0 * a0;
  ls = wave_sum_d(ls);
  if (lane == 0) p2red[wid] = ls;
  __syncthreads();
  if (t == 0) {
    double p2 = 0.0;
#pragma unroll
    for (int k = 0; k < 10; ++k) p2 += p2red[k];
    double u22;
    gshd = expmap_scale((double)ws[OFF_C + w], p2, &u22);
    ((double*)(ws + OFF_X2D2))[w] = u22;
  }
  __syncthreads();
  ws[OFF_TP + w * DIM + t] = (float)gshd * a0;
}

extern "C" void kernel_launch(void* const* d_in, const int* in_sizes, int n_in,
                              void* d_out, int out_size, void* d_ws, size_t ws_size,
                              hipStream_t stream) {
  (void)in_sizes; (void)n_in; (void)out_size; (void)ws_size;
  const float* shot = (const float*)d_in[0];
  const float* qry  = (const float*)d_in[1];
  const float* W1   = (const float*)d_in[2];
  const float* b1   = (const float*)d_in[3];
  const float* W2   = (const float*)d_in[4];
  const float* b2   = (const float*)d_in[5];
  const float* W3   = (const float*)d_in[6];
  const float* b3   = (const float*)d_in[7];
  const float* Wr1  = (const float*)d_in[8];
  const float* br1  = (const float*)d_in[9];
  const float* Wr2  = (const float*)d_in[10];
  const float* br2  = (const float*)d_in[11];
  float* ws = (float*)d_ws;
  float* out = (float*)d_out;

  hipLaunchKernelGGL(k_fuse1, dim3(128), dim3(640), 0, stream, qry, shot, W1, ws);
  hipLaunchKernelGGL(k_ctrl,  dim3(32), dim3(256), 0, stream, W1, b1, W2, b2, W3, b3, ws);
  hipLaunchKernelGGL(k_gemm,  dim3(512), dim3(256), 0, stream, ws + OFF_PROTOS, qry, ws, 0, out);
  hipLaunchKernelGGL(k_topkA, dim3(32), dim3(1024), 0, stream, ws);
  hipLaunchKernelGGL(k_refB,  dim3(32), dim3(640), 0, stream, qry, Wr1, br1, Wr2, br2, ws);
  hipLaunchKernelGGL(k_gemm,  dim3(512), dim3(256), 0, stream, ws + OFF_TP, qry, ws, 1, out);
}

// Round 17
// 89.806 us; speedup vs baseline: 1.5028x; 1.1430x over previous
//
#include <hip/hip_runtime.h>
#include <math.h>

#define NSHOT 5
#define WAY 32
#define DIM 640
#define NQ 4096
#define RNEAR 10

// ---- workspace layout (float offsets), ~1.07 MB ----
constexpr int OFF_PROTOS = 0;        // 32*640
constexpr int OFF_QPART  = 20480;    // 128*640 column partial sums (incl. shot fold)
constexpr int OFF_C      = 102400;   // 32
constexpr int OFF_BETA   = 102432;   // 32
constexpr int OFF_S      = 102464;   // 32
constexpr int OFF_U      = 102496;   // 32
constexpr int OFF_NID    = 102528;   // 32*10
constexpr int OFF_RR     = 102848;   // 32*22
constexpr int OFF_SPC    = 103552;   // 32
constexpr int OFF_H1P    = 103584;   // 32*128 (per-way pr·W1a)
constexpr int OFF_TP     = 107680;   // 32*640
constexpr int OFF_G      = 128160;   // 32*4096 raw dots
constexpr int OFF_NIDX   = 259232;   // 32*10 ints
constexpr int OFF_Q2D    = 259556;   // double[4096] (byte-offset %8 == 0)
constexpr int OFF_X2D    = 267748;   // double[32] (proto_p norm^2)
constexpr int OFF_X2D2   = 267812;   // double[32] (test_proto norm^2)
constexpr int OFF_P2RAW  = 267876;   // double[32] (raw proto norm^2)

__device__ __forceinline__ double wave_sum_d(double v) {
#pragma unroll
  for (int o = 32; o > 0; o >>= 1) v += __shfl_down(v, o, 64);
  return v;
}

// f64 distance — OUTPUT path only (gemm2 epilogue)
__device__ __forceinline__ double dist_hyp(double c, double xdotq, double u2, double q2) {
  const double EPSd = 1e-5;
  double sc = sqrt(c);
  double nq = sqrt(q2);
  double nf = fmax(nq, EPSd);
  double th = tanh(sc * nf);
  double al = th / (sc * nf);
  double ny = fmax(al * nq, EPSd);
  double mx = 0.999 / sc;
  if (ny > mx) al *= mx / ny;
  double y2 = al * al * q2;
  double uy = -al * xdotq;
  double A = 1.0 + 2.0 * c * uy + c * y2;
  double B = 1.0 - c * u2;
  double den = fmax(1.0 + 2.0 * c * uy + c * c * u2 * y2, EPSd);
  double num2 = fmax(A * A * u2 + 2.0 * A * B * uy + B * B * y2, 0.0);
  double n = sqrt(num2) / den;
  double arg = sc * n;
  const double CLIP = (double)(1.0f - 1e-5f);
  arg = fmin(fmax(arg, 0.0), CLIP);
  return (1.0 / sc) * log((1.0 + arg) / (1.0 - arg));
}

// f32 fast distance — selection/stats only
__device__ __forceinline__ float dist_f32(float c, float xdotq, float u2, float q2) {
  const float EPSf = 1e-5f;
  float sc = sqrtf(c);
  float nq = sqrtf(q2);
  float nf = fmaxf(nq, EPSf);
  float th = tanhf(sc * nf);
  float al = th / (sc * nf);
  float ny = fmaxf(al * nq, EPSf);
  float mx = 0.999f / sc;
  if (ny > mx) al *= mx / ny;
  float y2 = al * al * q2;
  float uy = -al * xdotq;
  float A = 1.f + 2.f * c * uy + c * y2;
  float B = 1.f - c * u2;
  float den = fmaxf(1.f + 2.f * c * uy + c * c * u2 * y2, EPSf);
  float num2 = fmaxf(A * A * u2 + 2.f * A * B * uy + B * B * y2, 0.f);
  float n = sqrtf(num2) / den;
  float arg = sc * n;
  arg = fminf(fmaxf(arg, 0.f), 1.f - 1e-5f);
  return (1.f / sc) * logf((1.f + arg) / (1.f - arg));
}

__device__ __forceinline__ double expmap_scale(double c, double p2, double* u2out) {
  double sc = sqrt(c);
  double ntrue = sqrt(p2);
  double nf = fmax(ntrue, 1e-5);
  double th = tanh(sc * nf);
  double s0 = th / (sc * nf);
  double ny = fmax(s0 * ntrue, 1e-5);
  double mx = 0.999 / sc;
  if (ny > mx) s0 *= mx / ny;
  *u2out = s0 * s0 * p2;
  return s0;
}

// grid 128 x 640: protos + P2RAW + H1P (b<32), per-row q2, QPART (+shot fold)
__global__ __launch_bounds__(640) void k_fuse1(const float* __restrict__ Qm,
                                               const float* __restrict__ shot,
                                               const float* __restrict__ W1, float* ws) {
  __shared__ double q2w[32][10];
  __shared__ double psred[10];
  __shared__ float pr[DIM];
  __shared__ float h1pp[5][128];
  int b = blockIdx.x, t = threadIdx.x;
  int lane = t & 63, wid = t >> 6;  // 10 waves
  float protoval = 0.f;
  if (b < WAY) {
    float s = 0.f;
#pragma unroll
    for (int s5 = 0; s5 < NSHOT; ++s5) s += shot[(size_t)(s5 * WAY + b) * DIM + t];
    protoval = s * 0.2f;
    pr[t] = protoval;
    ws[OFF_PROTOS + b * DIM + t] = protoval;
    double pv2 = (double)protoval * protoval;
    pv2 = wave_sum_d(pv2);
    if (lane == 0) psred[wid] = pv2;
  }
  int r0 = b * 32;
  float colacc = 0.f;
  for (int r = 0; r < 32; ++r) {
    float v = Qm[(size_t)(r0 + r) * DIM + t];
    colacc += v;
    double sq = (double)v * v;
    sq = wave_sum_d(sq);
    if (lane == 0) q2w[r][wid] = sq;
  }
  ws[OFF_QPART + b * DIM + t] = colacc + 5.f * protoval;
  __syncthreads();
  if (t < 32) {
    double s = 0.0;
#pragma unroll
    for (int k = 0; k < 10; ++k) s += q2w[t][k];
    ((double*)(ws + OFF_Q2D))[r0 + t] = s;
  }
  if (b < WAY) {
    int n = t & 127, s = t >> 7;
    int k0 = s * 128;
    float acc = 0.f;
#pragma unroll 8
    for (int k = k0; k < k0 + 128; ++k) acc = fmaf(pr[k], W1[(size_t)k * 128 + n], acc);
    h1pp[s][n] = acc;
    __syncthreads();
    if (t < 128)
      ws[OFF_H1P + b * 128 + t] = h1pp[0][t] + h1pp[1][t] + h1pp[2][t] + h1pp[3][t] + h1pp[4][t];
    if (t == 0) {
      double p2 = 0.0;
#pragma unroll
      for (int k = 0; k < 10; ++k) p2 += psred[k];
      ((double*)(ws + OFF_P2RAW))[b] = p2;
    }
  }
}

// grid 32 x 1024: per-way ctrl MLP, high-ILP. Each block redundantly reduces
// QPART->am (640 thr x 4 accumulators), W1b in 8 k-slices, h2 in 8 k-slices.
__global__ __launch_bounds__(1024) void k_ctrl(const float* __restrict__ W1, const float* __restrict__ b1,
                                               const float* __restrict__ W2, const float* __restrict__ b2,
                                               const float* __restrict__ W3, const float* __restrict__ b3,
                                               float* ws) {
  __shared__ float am[DIM];
  __shared__ float part[8][128];
  __shared__ float part2[8][64];
  __shared__ float h1s[128], h2s[64], lg[5];
  int w = blockIdx.x, t = threadIdx.x;
  if (t < DIM) {
    const float* base = ws + OFF_QPART + t;
    float a0 = 0.f, a1 = 0.f, a2 = 0.f, a3 = 0.f;
#pragma unroll 8
    for (int p = 0; p < 128; p += 4) {
      a0 += base[(size_t)(p + 0) * DIM];
      a1 += base[(size_t)(p + 1) * DIM];
      a2 += base[(size_t)(p + 2) * DIM];
      a3 += base[(size_t)(p + 3) * DIM];
    }
    am[t] = ((a0 + a1) + (a2 + a3)) * (1.f / 4256.f);
  }
  __syncthreads();
  {
    int n = t & 127, s = t >> 7;     // 8 k-slices of 80
    int k0 = s * 80;
    float acc = 0.f;
#pragma unroll 8
    for (int k = k0; k < k0 + 80; ++k)
      acc = fmaf(am[k], W1[(size_t)(DIM + k) * 128 + n], acc);
    part[s][n] = acc;
  }
  __syncthreads();
  if (t < 128) {
    float a = ws[OFF_H1P + w * 128 + t] + b1[t];
#pragma unroll
    for (int s = 0; s < 8; ++s) a += part[s][t];
    h1s[t] = fmaxf(a, 0.f);
  }
  __syncthreads();
  if (t < 512) {
    int n = t & 63, s = t >> 6;      // 8 k-slices of 16
    int k0 = s * 16;
    float acc = 0.f;
#pragma unroll
    for (int k = 0; k < 16; ++k) acc = fmaf(h1s[k0 + k], W2[(size_t)(k0 + k) * 64 + n], acc);
    part2[s][n] = acc;
  }
  __syncthreads();
  if (t < 64) {
    float a = b2[t];
#pragma unroll
    for (int s = 0; s < 8; ++s) a += part2[s][t];
    h2s[t] = fmaxf(a, 0.f);
  }
  __syncthreads();
  if (t < 5) {
    float acc = b3[t];
    for (int k = 0; k < 64; ++k) acc = fmaf(h2s[k], W3[k * 5 + t], acc);
    lg[t] = acc;
  }
  __syncthreads();
  if (t == 0) {
    double m = lg[0];
    for (int i = 1; i < 5; ++i) m = fmax(m, (double)lg[i]);
    double se = 0.0, cv = 0.0;
    for (int i = 0; i < 5; ++i) { double e = exp((double)lg[i] - m); se += e; cv += e * 0.2 * (double)(i + 1); }
    double c = cv / se;
    ws[OFF_C + w] = (float)c;
    double p2 = ((const double*)(ws + OFF_P2RAW))[w];
    double u2;
    double beta = expmap_scale(c, p2, &u2);
    ws[OFF_BETA + w] = (float)beta;
    ((double*)(ws + OFF_X2D))[w] = u2;
  }
}

// grid 512 x 256: GEMM (X rows 0..31) vs 8 q-rows; mode 0: raw G; mode 1: f64 dist -> out
__global__ __launch_bounds__(256) void k_gemm(const float* __restrict__ X, const float* __restrict__ Qm,
                                              float* __restrict__ ws, int mode, float* __restrict__ out) {
  __shared__ float S[2][40][68];
  int t = threadIdx.x;
  int q0 = blockIdx.x * 8;
  int rowA = t >> 4, quadA = t & 15;
  int rowB = (t + 256) >> 4;
  int rowC = (t + 512) >> 4;
  bool hasC = (t < 128);
  const float* srcA = (rowA < 8 ? Qm + (size_t)(q0 + rowA) * DIM : X + (size_t)(rowA - 8) * DIM) + quadA * 4;
  const float* srcB = X + (size_t)(rowB - 8) * DIM + quadA * 4;
  const float* srcC = X + (size_t)(rowC - 8) * DIM + quadA * 4;
  float4 pA = *(const float4*)srcA;
  float4 pB = *(const float4*)srcB;
  float4 pC = {0.f, 0.f, 0.f, 0.f};
  if (hasC) pC = *(const float4*)srcC;
  *(float4*)&S[0][rowA][quadA * 4] = pA;
  *(float4*)&S[0][rowB][quadA * 4] = pB;
  if (hasC) *(float4*)&S[0][rowC][quadA * 4] = pC;
  __syncthreads();
  int q = t & 7, w = t >> 3;
  float ax = 0.f, ay = 0.f, az = 0.f, aw = 0.f;
  for (int c = 0; c < 10; ++c) {
    int bsel = c & 1;
    if (c < 9) {
      size_t kc = (size_t)(c + 1) * 64;
      pA = *(const float4*)(srcA + kc);
      pB = *(const float4*)(srcB + kc);
      if (hasC) pC = *(const float4*)(srcC + kc);
    }
    const float* qr = &S[bsel][q][0];
    const float* xr = &S[bsel][8 + w][0];
#pragma unroll
    for (int kk = 0; kk < 64; kk += 4) {
      float4 qv = *(const float4*)(qr + kk);
      float4 xv = *(const float4*)(xr + kk);
      ax = fmaf(qv.x, xv.x, ax);
      ay = fmaf(qv.y, xv.y, ay);
      az = fmaf(qv.z, xv.z, az);
      aw = fmaf(qv.w, xv.w, aw);
    }
    if (c < 9) {
      int nb = bsel ^ 1;
      *(float4*)&S[nb][rowA][quadA * 4] = pA;
      *(float4*)&S[nb][rowB][quadA * 4] = pB;
      if (hasC) *(float4*)&S[nb][rowC][quadA * 4] = pC;
      __syncthreads();
    }
  }
  float acc = (ax + ay) + (az + aw);
  int qq = q0 + q;
  if (mode == 0) {
    ws[OFF_G + (size_t)w * NQ + qq] = acc;
  } else {
    const double* q2d = (const double*)(ws + OFF_Q2D);
    const double* u2arr = (const double*)(ws + OFF_X2D2);
    double d = dist_hyp((double)ws[OFF_C + w], (double)acc, u2arr[w], q2d[qq]);
    out[(size_t)qq * WAY + w] = (float)(-d / 16.0);
  }
}

// grid 32 x 1024: per-way f32 dists + stable top-10 + S/U + stats -> ws
__global__ __launch_bounds__(1024) void k_topkA(float* __restrict__ ws) {
  __shared__ double sredS[16], sredU[16];
  __shared__ float cval[160];
  __shared__ int cidx[160];
  __shared__ float qvsh[RNEAR];
  __shared__ int qjsh[RNEAR];
  __shared__ float colsh[RNEAR][33];
  __shared__ float pcpart[RNEAR];
  int w = blockIdx.x, t = threadIdx.x;
  int lane = t & 63, wid = t >> 6;
  int* nidx = (int*)(ws + OFF_NIDX);
  const double* q2d = (const double*)(ws + OFF_Q2D);
  const double* x2d = (const double*)(ws + OFF_X2D);
  float cf = ws[OFF_C + w];
  float betaf = ws[OFF_BETA + w];
  float u2f = (float)x2d[w];
  const float* gb = ws + OFF_G + (size_t)w * NQ;
  float v0 = dist_f32(cf, betaf * gb[t],        u2f, (float)q2d[t]);
  float v1 = dist_f32(cf, betaf * gb[1024 + t], u2f, (float)q2d[1024 + t]);
  float v2 = dist_f32(cf, betaf * gb[2048 + t], u2f, (float)q2d[2048 + t]);
  float v3 = dist_f32(cf, betaf * gb[3072 + t], u2f, (float)q2d[3072 + t]);
  unsigned tk = 0;
  double s = (double)v0 + (double)v1 + (double)v2 + (double)v3;
  double u = (t < RNEAR) ? (double)v0 : 0.0;
  s = wave_sum_d(s);
  u = wave_sum_d(u);
  if (lane == 0) { sredS[wid] = s; sredU[wid] = u; }
  for (int r = 0; r < RNEAR; ++r) {
    float lv = INFINITY; int li = 0x7fffffff;
    if (!(tk & 1u) && (v0 < lv || (v0 == lv && t < li)))        { lv = v0; li = t; }
    if (!(tk & 2u) && (v1 < lv || (v1 == lv && 1024 + t < li))) { lv = v1; li = 1024 + t; }
    if (!(tk & 4u) && (v2 < lv || (v2 == lv && 2048 + t < li))) { lv = v2; li = 2048 + t; }
    if (!(tk & 8u) && (v3 < lv || (v3 == lv && 3072 + t < li))) { lv = v3; li = 3072 + t; }
#pragma unroll
    for (int o = 32; o > 0; o >>= 1) {
      float ov = __shfl_xor(lv, o, 64);
      int oi = __shfl_xor(li, o, 64);
      if (ov < lv || (ov == lv && oi < li)) { lv = ov; li = oi; }
    }
    if (lane == 0) { cval[wid * RNEAR + r] = lv; cidx[wid * RNEAR + r] = li; }
    if ((li & 1023) == t) tk |= 1u << (li >> 10);
  }
  __syncthreads();
  if (t == 0) {
    double S = 0.0, U = 0.0;
    for (int k = 0; k < 16; ++k) { S += sredS[k]; U += sredU[k]; }
    ws[OFF_S + w] = (float)S;
    ws[OFF_U + w] = (float)U;
  }
  if (t < 64) {
    float c0 = cval[t], c1 = cval[t + 64];
    int i0 = cidx[t], i1 = cidx[t + 64];
    float c2 = (t < 32) ? cval[t + 128] : INFINITY;
    int i2 = (t < 32) ? cidx[t + 128] : 0x7fffffff;
    unsigned m = 0;
    for (int r = 0; r < RNEAR; ++r) {
      float lv = INFINITY; int li = 0x7fffffff;
      if (!(m & 1u) && (c0 < lv || (c0 == lv && i0 < li))) { lv = c0; li = i0; }
      if (!(m & 2u) && (c1 < lv || (c1 == lv && i1 < li))) { lv = c1; li = i1; }
      if (!(m & 4u) && (c2 < lv || (c2 == lv && i2 < li))) { lv = c2; li = i2; }
#pragma unroll
      for (int o = 32; o > 0; o >>= 1) {
        float ov = __shfl_xor(lv, o, 64);
        int oi = __shfl_xor(li, o, 64);
        if (ov < lv || (ov == lv && oi < li)) { lv = ov; li = oi; }
      }
      if (lane == 0) { qvsh[r] = lv; qjsh[r] = li; }
      if (i0 == li) m |= 1u;
      if (i1 == li) m |= 2u;
      if (i2 == li) m |= 4u;
    }
  }
  __syncthreads();
  if (t < WAY * RNEAR) {
    int j = t >> 5, w2 = t & 31;
    int q = qjsh[j];
    colsh[j][w2] = dist_f32(ws[OFF_C + w2], ws[OFF_BETA + w2] * ws[OFF_G + (size_t)w2 * NQ + q],
                            (float)x2d[w2], (float)q2d[q]);
  }
  __syncthreads();
  if (t < RNEAR) {
    double cs = 0.0, pc = 0.0;
    for (int w2 = 0; w2 < WAY; ++w2) {
      float dv = colsh[t][w2];
      cs += dv;
      if (w2 < w) pc += dv;
    }
    ws[OFF_RR + w * 22 + t] = qvsh[t];
    ws[OFF_RR + w * 22 + RNEAR + t] = (float)((cs - qvsh[t]) / (double)(WAY - 1));
    ws[OFF_NID + w * RNEAR + t] = qvsh[t];
    nidx[w * RNEAR + t] = qjsh[t];
    pcpart[t] = (float)pc;
  }
  __syncthreads();
  if (t == 0) {
    double spc = 0.0, sn = 0.0;
    for (int j = 0; j < RNEAR; ++j) { spc += pcpart[j]; sn += qvsh[j]; }
    double S = (double)ws[OFF_S + w];
    ws[OFF_RR + w * 22 + 20] = (float)((S - sn) / (double)(NQ - RNEAR));
    ws[OFF_SPC + w] = (float)spc;
  }
}

// grid 32 x 640: per-way refine MLP + tmp/expmap -> TP
__global__ __launch_bounds__(640) void k_refB(const float* __restrict__ Qm,
                                              const float* __restrict__ Wr1, const float* __restrict__ br1,
                                              const float* __restrict__ Wr2, const float* __restrict__ br2,
                                              float* __restrict__ ws) {
  __shared__ float Ssh[WAY], Ush[WAY];
  __shared__ float rrl[22];
  __shared__ int qj[RNEAR];
  __shared__ float hr[RNEAR], orsh[11], iw[RNEAR];
  __shared__ float onw_sh;
  __shared__ double p2red[10];
  __shared__ double gshd;
  int w = blockIdx.x, t = threadIdx.x;
  int lane = t & 63, wid = t >> 6;  // 10 waves
  const int* nidx = (const int*)(ws + OFF_NIDX);
  if (t < WAY) { Ssh[t] = ws[OFF_S + t]; Ush[t] = ws[OFF_U + t]; }
  if (t >= 64 && t < 64 + 22) rrl[t - 64] = ws[OFF_RR + w * 22 + (t - 64)];
  if (t >= 96 && t < 96 + RNEAR) qj[t - 96] = nidx[w * RNEAR + (t - 96)];
  __syncthreads();
  if (t == 0) {
    double pref = 0.0, suf = 0.0;
    for (int j = 0; j < w; ++j) pref += (double)Ssh[j];
    for (int j = w + 1; j < WAY; ++j) suf += (double)Ssh[j] - (double)Ush[j];
    double spc = (double)ws[OFF_SPC + w];
    rrl[21] = (float)((pref - spc + suf) / ((double)(WAY - 1) * (double)(NQ - RNEAR)));
  }
  __syncthreads();
  if (t < RNEAR) {
    float a = br1[t];
    for (int k = 0; k < 22; ++k) a = fmaf(rrl[k], Wr1[k * RNEAR + t], a);
    hr[t] = fmaxf(a, 0.f);
  }
  __syncthreads();
  if (t < 11) {
    float a = br2[t];
    for (int k = 0; k < RNEAR; ++k) a = fmaf(hr[k], Wr2[k * 11 + t], a);
    orsh[t] = a;
  }
  __syncthreads();
  if (t == 0) {
    double m = orsh[0];
    for (int i = 1; i < RNEAR; ++i) m = fmax(m, (double)orsh[i]);
    double se = 0.0; double e[RNEAR];
    for (int i = 0; i < RNEAR; ++i) { e[i] = exp((double)orsh[i] - m); se += e[i]; }
    for (int i = 0; i < RNEAR; ++i) iw[i] = (float)(e[i] / se);
    onw_sh = (float)(1.0 / (1.0 + exp(-(double)orsh[10])));
  }
  __syncthreads();
  float onwv = onw_sh;
  float wd = 0.f;
#pragma unroll
  for (int j = 0; j < RNEAR; ++j)
    wd = fmaf(Qm[(size_t)qj[j] * DIM + t], iw[j], wd);
  float a0 = ws[OFF_PROTOS + w * DIM + t] * onwv + wd * (1.f - onwv);
  double ls = (double)a0 * a0;
  ls = wave_sum_d(ls);
  if (lane == 0) p2red[wid] = ls;
  __syncthreads();
  if (t == 0) {
    double p2 = 0.0;
#pragma unroll
    for (int k = 0; k < 10; ++k) p2 += p2red[k];
    double u22;
    gshd = expmap_scale((double)ws[OFF_C + w], p2, &u22);
    ((double*)(ws + OFF_X2D2))[w] = u22;
  }
  __syncthreads();
  ws[OFF_TP + w * DIM + t] = (float)gshd * a0;
}

extern "C" void kernel_launch(void* const* d_in, const int* in_sizes, int n_in,
                              void* d_out, int out_size, void* d_ws, size_t ws_size,
                              hipStream_t stream) {
  (void)in_sizes; (void)n_in; (void)out_size; (void)ws_size;
  const float* shot = (const float*)d_in[0];
  const float* qry  = (const float*)d_in[1];
  const float* W1   = (const float*)d_in[2];
  const float* b1   = (const float*)d_in[3];
  const float* W2   = (const float*)d_in[4];
  const float* b2   = (const float*)d_in[5];
  const float* W3   = (const float*)d_in[6];
  const float* b3   = (const float*)d_in[7];
  const float* Wr1  = (const float*)d_in[8];
  const float* br1  = (const float*)d_in[9];
  const float* Wr2  = (const float*)d_in[10];
  const float* br2  = (const float*)d_in[11];
  float* ws = (float*)d_ws;
  float* out = (float*)d_out;

  hipLaunchKernelGGL(k_fuse1, dim3(128), dim3(640), 0, stream, qry, shot, W1, ws);
  hipLaunchKernelGGL(k_ctrl,  dim3(32), dim3(1024), 0, stream, W1, b1, W2, b2, W3, b3, ws);
  hipLaunchKernelGGL(k_gemm,  dim3(512), dim3(256), 0, stream, ws + OFF_PROTOS, qry, ws, 0, out);
  hipLaunchKernelGGL(k_topkA, dim3(32), dim3(1024), 0, stream, ws);
  hipLaunchKernelGGL(k_refB,  dim3(32), dim3(640), 0, stream, qry, Wr1, br1, Wr2, br2, ws);
  hipLaunchKernelGGL(k_gemm,  dim3(512), dim3(256), 0, stream, ws + OFF_TP, qry, ws, 1, out);
}

// Round 18
// 85.184 us; speedup vs baseline: 1.5843x; 1.0543x over previous
//
#include <hip/hip_runtime.h>
#include <math.h>

#define NSHOT 5
#define WAY 32
#define DIM 640
#define NQ 4096
#define RNEAR 10

// ---- workspace layout (float offsets), ~1.07 MB ----
constexpr int OFF_PROTOS = 0;        // 32*640
constexpr int OFF_QPART  = 20480;    // 128*640 column partial sums (incl. shot fold)
constexpr int OFF_C      = 102400;   // 32
constexpr int OFF_BETA   = 102432;   // 32
constexpr int OFF_S      = 102464;   // 32
constexpr int OFF_U      = 102496;   // 32
constexpr int OFF_NID    = 102528;   // 32*10
constexpr int OFF_RR     = 102848;   // 32*22
constexpr int OFF_SPC    = 103552;   // 32
constexpr int OFF_H1P    = 103584;   // 32*128 (per-way pr·W1a)
constexpr int OFF_TP     = 107680;   // 32*640
constexpr int OFF_G      = 128160;   // 32*4096 f32 DISTANCES (written by gemm mode 0)
constexpr int OFF_NIDX   = 259232;   // 32*10 ints
constexpr int OFF_Q2D    = 259556;   // double[4096] (byte-offset %8 == 0)
constexpr int OFF_X2D    = 267748;   // double[32] (proto_p norm^2)
constexpr int OFF_X2D2   = 267812;   // double[32] (test_proto norm^2)
constexpr int OFF_P2RAW  = 267876;   // double[32] (raw proto norm^2)

__device__ __forceinline__ double wave_sum_d(double v) {
#pragma unroll
  for (int o = 32; o > 0; o >>= 1) v += __shfl_down(v, o, 64);
  return v;
}

// f64 distance — OUTPUT path only (gemm mode 1 epilogue)
__device__ __forceinline__ double dist_hyp(double c, double xdotq, double u2, double q2) {
  const double EPSd = 1e-5;
  double sc = sqrt(c);
  double nq = sqrt(q2);
  double nf = fmax(nq, EPSd);
  double th = tanh(sc * nf);
  double al = th / (sc * nf);
  double ny = fmax(al * nq, EPSd);
  double mx = 0.999 / sc;
  if (ny > mx) al *= mx / ny;
  double y2 = al * al * q2;
  double uy = -al * xdotq;
  double A = 1.0 + 2.0 * c * uy + c * y2;
  double B = 1.0 - c * u2;
  double den = fmax(1.0 + 2.0 * c * uy + c * c * u2 * y2, EPSd);
  double num2 = fmax(A * A * u2 + 2.0 * A * B * uy + B * B * y2, 0.0);
  double n = sqrt(num2) / den;
  double arg = sc * n;
  const double CLIP = (double)(1.0f - 1e-5f);
  arg = fmin(fmax(arg, 0.0), CLIP);
  return (1.0 / sc) * log((1.0 + arg) / (1.0 - arg));
}

// f32 fast distance — selection/stats path (gemm mode 0 epilogue)
__device__ __forceinline__ float dist_f32(float c, float xdotq, float u2, float q2) {
  const float EPSf = 1e-5f;
  float sc = sqrtf(c);
  float nq = sqrtf(q2);
  float nf = fmaxf(nq, EPSf);
  float th = tanhf(sc * nf);
  float al = th / (sc * nf);
  float ny = fmaxf(al * nq, EPSf);
  float mx = 0.999f / sc;
  if (ny > mx) al *= mx / ny;
  float y2 = al * al * q2;
  float uy = -al * xdotq;
  float A = 1.f + 2.f * c * uy + c * y2;
  float B = 1.f - c * u2;
  float den = fmaxf(1.f + 2.f * c * uy + c * c * u2 * y2, EPSf);
  float num2 = fmaxf(A * A * u2 + 2.f * A * B * uy + B * B * y2, 0.f);
  float n = sqrtf(num2) / den;
  float arg = sc * n;
  arg = fminf(fmaxf(arg, 0.f), 1.f - 1e-5f);
  return (1.f / sc) * logf((1.f + arg) / (1.f - arg));
}

__device__ __forceinline__ double expmap_scale(double c, double p2, double* u2out) {
  double sc = sqrt(c);
  double ntrue = sqrt(p2);
  double nf = fmax(ntrue, 1e-5);
  double th = tanh(sc * nf);
  double s0 = th / (sc * nf);
  double ny = fmax(s0 * ntrue, 1e-5);
  double mx = 0.999 / sc;
  if (ny > mx) s0 *= mx / ny;
  *u2out = s0 * s0 * p2;
  return s0;
}

// grid 128 x 640: protos + P2RAW + H1P (b<32), per-row q2, QPART (+shot fold)
__global__ __launch_bounds__(640) void k_fuse1(const float* __restrict__ Qm,
                                               const float* __restrict__ shot,
                                               const float* __restrict__ W1, float* ws) {
  __shared__ double q2w[32][10];
  __shared__ double psred[10];
  __shared__ float pr[DIM];
  __shared__ float h1pp[5][128];
  int b = blockIdx.x, t = threadIdx.x;
  int lane = t & 63, wid = t >> 6;  // 10 waves
  float protoval = 0.f;
  if (b < WAY) {
    float s = 0.f;
#pragma unroll
    for (int s5 = 0; s5 < NSHOT; ++s5) s += shot[(size_t)(s5 * WAY + b) * DIM + t];
    protoval = s * 0.2f;
    pr[t] = protoval;
    ws[OFF_PROTOS + b * DIM + t] = protoval;
    double pv2 = (double)protoval * protoval;
    pv2 = wave_sum_d(pv2);
    if (lane == 0) psred[wid] = pv2;
  }
  int r0 = b * 32;
  float colacc = 0.f;
  for (int r = 0; r < 32; ++r) {
    float v = Qm[(size_t)(r0 + r) * DIM + t];
    colacc += v;
    double sq = (double)v * v;
    sq = wave_sum_d(sq);
    if (lane == 0) q2w[r][wid] = sq;
  }
  ws[OFF_QPART + b * DIM + t] = colacc + 5.f * protoval;
  __syncthreads();
  if (t < 32) {
    double s = 0.0;
#pragma unroll
    for (int k = 0; k < 10; ++k) s += q2w[t][k];
    ((double*)(ws + OFF_Q2D))[r0 + t] = s;
  }
  if (b < WAY) {
    int n = t & 127, s = t >> 7;
    int k0 = s * 128;
    float acc = 0.f;
#pragma unroll 8
    for (int k = k0; k < k0 + 128; ++k) acc = fmaf(pr[k], W1[(size_t)k * 128 + n], acc);
    h1pp[s][n] = acc;
    __syncthreads();
    if (t < 128)
      ws[OFF_H1P + b * 128 + t] = h1pp[0][t] + h1pp[1][t] + h1pp[2][t] + h1pp[3][t] + h1pp[4][t];
    if (t == 0) {
      double p2 = 0.0;
#pragma unroll
      for (int k = 0; k < 10; ++k) p2 += psred[k];
      ((double*)(ws + OFF_P2RAW))[b] = p2;
    }
  }
}

// grid 32 x 1024: per-way ctrl MLP, high-ILP (R17-proven)
__global__ __launch_bounds__(1024) void k_ctrl(const float* __restrict__ W1, const float* __restrict__ b1,
                                               const float* __restrict__ W2, const float* __restrict__ b2,
                                               const float* __restrict__ W3, const float* __restrict__ b3,
                                               float* ws) {
  __shared__ float am[DIM];
  __shared__ float part[8][128];
  __shared__ float part2[8][64];
  __shared__ float h1s[128], h2s[64], lg[5];
  int w = blockIdx.x, t = threadIdx.x;
  if (t < DIM) {
    const float* base = ws + OFF_QPART + t;
    float a0 = 0.f, a1 = 0.f, a2 = 0.f, a3 = 0.f;
#pragma unroll 8
    for (int p = 0; p < 128; p += 4) {
      a0 += base[(size_t)(p + 0) * DIM];
      a1 += base[(size_t)(p + 1) * DIM];
      a2 += base[(size_t)(p + 2) * DIM];
      a3 += base[(size_t)(p + 3) * DIM];
    }
    am[t] = ((a0 + a1) + (a2 + a3)) * (1.f / 4256.f);
  }
  __syncthreads();
  {
    int n = t & 127, s = t >> 7;     // 8 k-slices of 80
    int k0 = s * 80;
    float acc = 0.f;
#pragma unroll 8
    for (int k = k0; k < k0 + 80; ++k)
      acc = fmaf(am[k], W1[(size_t)(DIM + k) * 128 + n], acc);
    part[s][n] = acc;
  }
  __syncthreads();
  if (t < 128) {
    float a = ws[OFF_H1P + w * 128 + t] + b1[t];
#pragma unroll
    for (int s = 0; s < 8; ++s) a += part[s][t];
    h1s[t] = fmaxf(a, 0.f);
  }
  __syncthreads();
  if (t < 512) {
    int n = t & 63, s = t >> 6;      // 8 k-slices of 16
    int k0 = s * 16;
    float acc = 0.f;
#pragma unroll
    for (int k = 0; k < 16; ++k) acc = fmaf(h1s[k0 + k], W2[(size_t)(k0 + k) * 64 + n], acc);
    part2[s][n] = acc;
  }
  __syncthreads();
  if (t < 64) {
    float a = b2[t];
#pragma unroll
    for (int s = 0; s < 8; ++s) a += part2[s][t];
    h2s[t] = fmaxf(a, 0.f);
  }
  __syncthreads();
  if (t < 5) {
    float acc = b3[t];
    for (int k = 0; k < 64; ++k) acc = fmaf(h2s[k], W3[k * 5 + t], acc);
    lg[t] = acc;
  }
  __syncthreads();
  if (t == 0) {
    double m = lg[0];
    for (int i = 1; i < 5; ++i) m = fmax(m, (double)lg[i]);
    double se = 0.0, cv = 0.0;
    for (int i = 0; i < 5; ++i) { double e = exp((double)lg[i] - m); se += e; cv += e * 0.2 * (double)(i + 1); }
    double c = cv / se;
    ws[OFF_C + w] = (float)c;
    double p2 = ((const double*)(ws + OFF_P2RAW))[w];
    double u2;
    double beta = expmap_scale(c, p2, &u2);
    ws[OFF_BETA + w] = (float)beta;
    ((double*)(ws + OFF_X2D))[w] = u2;
  }
}

// grid 512 x 256: GEMM (X rows 0..31) vs 8 q-rows.
// mode 0: f32 dist epilogue -> DIS (selection path). mode 1: f64 dist -> out.
__global__ __launch_bounds__(256) void k_gemm(const float* __restrict__ X, const float* __restrict__ Qm,
                                              float* __restrict__ ws, int mode, float* __restrict__ out) {
  __shared__ float S[2][40][68];
  int t = threadIdx.x;
  int q0 = blockIdx.x * 8;
  int rowA = t >> 4, quadA = t & 15;
  int rowB = (t + 256) >> 4;
  int rowC = (t + 512) >> 4;
  bool hasC = (t < 128);
  const float* srcA = (rowA < 8 ? Qm + (size_t)(q0 + rowA) * DIM : X + (size_t)(rowA - 8) * DIM) + quadA * 4;
  const float* srcB = X + (size_t)(rowB - 8) * DIM + quadA * 4;
  const float* srcC = X + (size_t)(rowC - 8) * DIM + quadA * 4;
  float4 pA = *(const float4*)srcA;
  float4 pB = *(const float4*)srcB;
  float4 pC = {0.f, 0.f, 0.f, 0.f};
  if (hasC) pC = *(const float4*)srcC;
  *(float4*)&S[0][rowA][quadA * 4] = pA;
  *(float4*)&S[0][rowB][quadA * 4] = pB;
  if (hasC) *(float4*)&S[0][rowC][quadA * 4] = pC;
  __syncthreads();
  int q = t & 7, w = t >> 3;
  float ax = 0.f, ay = 0.f, az = 0.f, aw = 0.f;
  for (int c = 0; c < 10; ++c) {
    int bsel = c & 1;
    if (c < 9) {
      size_t kc = (size_t)(c + 1) * 64;
      pA = *(const float4*)(srcA + kc);
      pB = *(const float4*)(srcB + kc);
      if (hasC) pC = *(const float4*)(srcC + kc);
    }
    const float* qr = &S[bsel][q][0];
    const float* xr = &S[bsel][8 + w][0];
#pragma unroll
    for (int kk = 0; kk < 64; kk += 4) {
      float4 qv = *(const float4*)(qr + kk);
      float4 xv = *(const float4*)(xr + kk);
      ax = fmaf(qv.x, xv.x, ax);
      ay = fmaf(qv.y, xv.y, ay);
      az = fmaf(qv.z, xv.z, az);
      aw = fmaf(qv.w, xv.w, aw);
    }
    if (c < 9) {
      int nb = bsel ^ 1;
      *(float4*)&S[nb][rowA][quadA * 4] = pA;
      *(float4*)&S[nb][rowB][quadA * 4] = pB;
      if (hasC) *(float4*)&S[nb][rowC][quadA * 4] = pC;
      __syncthreads();
    }
  }
  float acc = (ax + ay) + (az + aw);
  int qq = q0 + q;
  const double* q2d = (const double*)(ws + OFF_Q2D);
  if (mode == 0) {
    const double* x2d = (const double*)(ws + OFF_X2D);
    float d = dist_f32(ws[OFF_C + w], ws[OFF_BETA + w] * acc, (float)x2d[w], (float)q2d[qq]);
    ws[OFF_G + (size_t)w * NQ + qq] = d;
  } else {
    const double* u2arr = (const double*)(ws + OFF_X2D2);
    double d = dist_hyp((double)ws[OFF_C + w], (double)acc, u2arr[w], q2d[qq]);
    out[(size_t)qq * WAY + w] = (float)(-d / 16.0);
  }
}

// grid 32 x 1024: per-way top-10 + S/U + stats from precomputed DIS (no transcendentals)
__global__ __launch_bounds__(1024) void k_topkA(float* __restrict__ ws) {
  __shared__ double sredS[16], sredU[16];
  __shared__ float cval[160];
  __shared__ int cidx[160];
  __shared__ float qvsh[RNEAR];
  __shared__ int qjsh[RNEAR];
  __shared__ float colsh[RNEAR][33];
  __shared__ float pcpart[RNEAR];
  int w = blockIdx.x, t = threadIdx.x;
  int lane = t & 63, wid = t >> 6;
  int* nidx = (int*)(ws + OFF_NIDX);
  const float* gb = ws + OFF_G + (size_t)w * NQ;
  float v0 = gb[t], v1 = gb[1024 + t], v2 = gb[2048 + t], v3 = gb[3072 + t];
  unsigned tk = 0;
  double s = (double)v0 + (double)v1 + (double)v2 + (double)v3;
  double u = (t < RNEAR) ? (double)v0 : 0.0;
  s = wave_sum_d(s);
  u = wave_sum_d(u);
  if (lane == 0) { sredS[wid] = s; sredU[wid] = u; }
  for (int r = 0; r < RNEAR; ++r) {
    float lv = INFINITY; int li = 0x7fffffff;
    if (!(tk & 1u) && (v0 < lv || (v0 == lv && t < li)))        { lv = v0; li = t; }
    if (!(tk & 2u) && (v1 < lv || (v1 == lv && 1024 + t < li))) { lv = v1; li = 1024 + t; }
    if (!(tk & 4u) && (v2 < lv || (v2 == lv && 2048 + t < li))) { lv = v2; li = 2048 + t; }
    if (!(tk & 8u) && (v3 < lv || (v3 == lv && 3072 + t < li))) { lv = v3; li = 3072 + t; }
#pragma unroll
    for (int o = 32; o > 0; o >>= 1) {
      float ov = __shfl_xor(lv, o, 64);
      int oi = __shfl_xor(li, o, 64);
      if (ov < lv || (ov == lv && oi < li)) { lv = ov; li = oi; }
    }
    if (lane == 0) { cval[wid * RNEAR + r] = lv; cidx[wid * RNEAR + r] = li; }
    if ((li & 1023) == t) tk |= 1u << (li >> 10);
  }
  __syncthreads();
  if (t == 0) {
    double S = 0.0, U = 0.0;
    for (int k = 0; k < 16; ++k) { S += sredS[k]; U += sredU[k]; }
    ws[OFF_S + w] = (float)S;
    ws[OFF_U + w] = (float)U;
  }
  if (t < 64) {
    float c0 = cval[t], c1 = cval[t + 64];
    int i0 = cidx[t], i1 = cidx[t + 64];
    float c2 = (t < 32) ? cval[t + 128] : INFINITY;
    int i2 = (t < 32) ? cidx[t + 128] : 0x7fffffff;
    unsigned m = 0;
    for (int r = 0; r < RNEAR; ++r) {
      float lv = INFINITY; int li = 0x7fffffff;
      if (!(m & 1u) && (c0 < lv || (c0 == lv && i0 < li))) { lv = c0; li = i0; }
      if (!(m & 2u) && (c1 < lv || (c1 == lv && i1 < li))) { lv = c1; li = i1; }
      if (!(m & 4u) && (c2 < lv || (c2 == lv && i2 < li))) { lv = c2; li = i2; }
#pragma unroll
      for (int o = 32; o > 0; o >>= 1) {
        float ov = __shfl_xor(lv, o, 64);
        int oi = __shfl_xor(li, o, 64);
        if (ov < lv || (ov == lv && oi < li)) { lv = ov; li = oi; }
      }
      if (lane == 0) { qvsh[r] = lv; qjsh[r] = li; }
      if (i0 == li) m |= 1u;
      if (i1 == li) m |= 2u;
      if (i2 == li) m |= 4u;
    }
  }
  __syncthreads();
  // colsh[j][w2] = DIS[w2][qj[j]] (direct gather, values identical to recompute)
  if (t < WAY * RNEAR) {
    int j = t >> 5, w2 = t & 31;
    colsh[j][w2] = ws[OFF_G + (size_t)w2 * NQ + qjsh[j]];
  }
  __syncthreads();
  if (t < RNEAR) {
    double cs = 0.0, pc = 0.0;
    for (int w2 = 0; w2 < WAY; ++w2) {
      float dv = colsh[t][w2];
      cs += dv;
      if (w2 < w) pc += dv;
    }
    ws[OFF_RR + w * 22 + t] = qvsh[t];
    ws[OFF_RR + w * 22 + RNEAR + t] = (float)((cs - qvsh[t]) / (double)(WAY - 1));
    ws[OFF_NID + w * RNEAR + t] = qvsh[t];
    nidx[w * RNEAR + t] = qjsh[t];
    pcpart[t] = (float)pc;
  }
  __syncthreads();
  if (t == 0) {
    double spc = 0.0, sn = 0.0;
    for (int j = 0; j < RNEAR; ++j) { spc += pcpart[j]; sn += qvsh[j]; }
    double S = (double)ws[OFF_S + w];
    ws[OFF_RR + w * 22 + 20] = (float)((S - sn) / (double)(NQ - RNEAR));
    ws[OFF_SPC + w] = (float)spc;
  }
}

// grid 32 x 640: per-way refine MLP + tmp/expmap -> TP
__global__ __launch_bounds__(640) void k_refB(const float* __restrict__ Qm,
                                              const float* __restrict__ Wr1, const float* __restrict__ br1,
                                              const float* __restrict__ Wr2, const float* __restrict__ br2,
                                              float* __restrict__ ws) {
  __shared__ float Ssh[WAY], Ush[WAY];
  __shared__ float rrl[22];
  __shared__ int qj[RNEAR];
  __shared__ float hr[RNEAR], orsh[11], iw[RNEAR];
  __shared__ float onw_sh;
  __shared__ double p2red[10];
  __shared__ double gshd;
  int w = blockIdx.x, t = threadIdx.x;
  int lane = t & 63, wid = t >> 6;  // 10 waves
  const int* nidx = (const int*)(ws + OFF_NIDX);
  if (t < WAY) { Ssh[t] = ws[OFF_S + t]; Ush[t] = ws[OFF_U + t]; }
  if (t >= 64 && t < 64 + 22) rrl[t - 64] = ws[OFF_RR + w * 22 + (t - 64)];
  if (t >= 96 && t < 96 + RNEAR) qj[t - 96] = nidx[w * RNEAR + (t - 96)];
  __syncthreads();
  if (t == 0) {
    double pref = 0.0, suf = 0.0;
    for (int j = 0; j < w; ++j) pref += (double)Ssh[j];
    for (int j = w + 1; j < WAY; ++j) suf += (double)Ssh[j] - (double)Ush[j];
    double spc = (double)ws[OFF_SPC + w];
    rrl[21] = (float)((pref - spc + suf) / ((double)(WAY - 1) * (double)(NQ - RNEAR)));
  }
  __syncthreads();
  if (t < RNEAR) {
    float a = br1[t];
    for (int k = 0; k < 22; ++k) a = fmaf(rrl[k], Wr1[k * RNEAR + t], a);
    hr[t] = fmaxf(a, 0.f);
  }
  __syncthreads();
  if (t < 11) {
    float a = br2[t];
    for (int k = 0; k < RNEAR; ++k) a = fmaf(hr[k], Wr2[k * 11 + t], a);
    orsh[t] = a;
  }
  __syncthreads();
  if (t == 0) {
    double m = orsh[0];
    for (int i = 1; i < RNEAR; ++i) m = fmax(m, (double)orsh[i]);
    double se = 0.0; double e[RNEAR];
    for (int i = 0; i < RNEAR; ++i) { e[i] = exp((double)orsh[i] - m); se += e[i]; }
    for (int i = 0; i < RNEAR; ++i) iw[i] = (float)(e[i] / se);
    onw_sh = (float)(1.0 / (1.0 + exp(-(double)orsh[10])));
  }
  __syncthreads();
  float onwv = onw_sh;
  float wd = 0.f;
#pragma unroll
  for (int j = 0; j < RNEAR; ++j)
    wd = fmaf(Qm[(size_t)qj[j] * DIM + t], iw[j], wd);
  float a0 = ws[OFF_PROTOS + w * DIM + t] * onwv + wd * (1.f - onwv);
  double ls = (double)a0 * a0;
  ls = wave_sum_d(ls);
  if (lane == 0) p2red[wid] = ls;
  __syncthreads();
  if (t == 0) {
    double p2 = 0.0;
#pragma unroll
    for (int k = 0; k < 10; ++k) p2 += p2red[k];
    double u22;
    gshd = expmap_scale((double)ws[OFF_C + w], p2, &u22);
    ((double*)(ws + OFF_X2D2))[w] = u22;
  }
  __syncthreads();
  ws[OFF_TP + w * DIM + t] = (float)gshd * a0;
}

extern "C" void kernel_launch(void* const* d_in, const int* in_sizes, int n_in,
                              void* d_out, int out_size, void* d_ws, size_t ws_size,
                              hipStream_t stream) {
  (void)in_sizes; (void)n_in; (void)out_size; (void)ws_size;
  const float* shot = (const float*)d_in[0];
  const float* qry  = (const float*)d_in[1];
  const float* W1   = (const float*)d_in[2];
  const float* b1   = (const float*)d_in[3];
  const float* W2   = (const float*)d_in[4];
  const float* b2   = (const float*)d_in[5];
  const float* W3   = (const float*)d_in[6];
  const float* b3   = (const float*)d_in[7];
  const float* Wr1  = (const float*)d_in[8];
  const float* br1  = (const float*)d_in[9];
  const float* Wr2  = (const float*)d_in[10];
  const float* br2  = (const float*)d_in[11];
  float* ws = (float*)d_ws;
  float* out = (float*)d_out;

  hipLaunchKernelGGL(k_fuse1, dim3(128), dim3(640), 0, stream, qry, shot, W1, ws);
  hipLaunchKernelGGL(k_ctrl,  dim3(32), dim3(1024), 0, stream, W1, b1, W2, b2, W3, b3, ws);
  hipLaunchKernelGGL(k_gemm,  dim3(512), dim3(256), 0, stream, ws + OFF_PROTOS, qry, ws, 0, out);
  hipLaunchKernelGGL(k_topkA, dim3(32), dim3(1024), 0, stream, ws);
  hipLaunchKernelGGL(k_refB,  dim3(32), dim3(640), 0, stream, qry, Wr1, br1, Wr2, br2, ws);
  hipLaunchKernelGGL(k_gemm,  dim3(512), dim3(256), 0, stream, ws + OFF_TP, qry, ws, 1, out);
}

// Round 19
// 81.652 us; speedup vs baseline: 1.6529x; 1.0433x over previous
//
#include <hip/hip_runtime.h>
#include <math.h>

#define NSHOT 5
#define WAY 32
#define DIM 640
#define NQ 4096
#define RNEAR 10

// ---- workspace layout (float offsets), ~1.08 MB ----
constexpr int OFF_PROTOS = 0;        // 32*640
constexpr int OFF_QPART  = 20480;    // 128*640 column partial sums (incl. shot fold)
constexpr int OFF_C      = 102400;   // 32
constexpr int OFF_BETA   = 102432;   // 32
constexpr int OFF_S      = 102464;   // 32
constexpr int OFF_U      = 102496;   // 32
constexpr int OFF_NID    = 102528;   // 32*10
constexpr int OFF_RR     = 102848;   // 32*22
constexpr int OFF_SPC    = 103552;   // 32
constexpr int OFF_H1P    = 103584;   // 32*128 (per-way pr·W1a)
constexpr int OFF_TP     = 107680;   // 32*640
constexpr int OFF_G      = 128160;   // 32*4096 f32 DISTANCES (written by gemm mode 0)
constexpr int OFF_NIDX   = 259232;   // 32*10 ints
constexpr int OFF_Q2D    = 259556;   // double[4096] (byte-offset %8 == 0)
constexpr int OFF_X2D    = 267748;   // double[32] (proto_p norm^2)
constexpr int OFF_X2D2   = 267812;   // double[32] (test_proto norm^2)
constexpr int OFF_P2RAW  = 267876;   // double[32] (raw proto norm^2)
constexpr int OFF_H1PART = 268000;   // 8*128 way-independent h1 partials

__device__ __forceinline__ double wave_sum_d(double v) {
#pragma unroll
  for (int o = 32; o > 0; o >>= 1) v += __shfl_down(v, o, 64);
  return v;
}

// f64 distance — OUTPUT path only (gemm mode 1 epilogue)
__device__ __forceinline__ double dist_hyp(double c, double xdotq, double u2, double q2) {
  const double EPSd = 1e-5;
  double sc = sqrt(c);
  double nq = sqrt(q2);
  double nf = fmax(nq, EPSd);
  double th = tanh(sc * nf);
  double al = th / (sc * nf);
  double ny = fmax(al * nq, EPSd);
  double mx = 0.999 / sc;
  if (ny > mx) al *= mx / ny;
  double y2 = al * al * q2;
  double uy = -al * xdotq;
  double A = 1.0 + 2.0 * c * uy + c * y2;
  double B = 1.0 - c * u2;
  double den = fmax(1.0 + 2.0 * c * uy + c * c * u2 * y2, EPSd);
  double num2 = fmax(A * A * u2 + 2.0 * A * B * uy + B * B * y2, 0.0);
  double n = sqrt(num2) / den;
  double arg = sc * n;
  const double CLIP = (double)(1.0f - 1e-5f);
  arg = fmin(fmax(arg, 0.0), CLIP);
  return (1.0 / sc) * log((1.0 + arg) / (1.0 - arg));
}

// f32 fast distance — selection/stats path (gemm mode 0 epilogue)
__device__ __forceinline__ float dist_f32(float c, float xdotq, float u2, float q2) {
  const float EPSf = 1e-5f;
  float sc = sqrtf(c);
  float nq = sqrtf(q2);
  float nf = fmaxf(nq, EPSf);
  float th = tanhf(sc * nf);
  float al = th / (sc * nf);
  float ny = fmaxf(al * nq, EPSf);
  float mx = 0.999f / sc;
  if (ny > mx) al *= mx / ny;
  float y2 = al * al * q2;
  float uy = -al * xdotq;
  float A = 1.f + 2.f * c * uy + c * y2;
  float B = 1.f - c * u2;
  float den = fmaxf(1.f + 2.f * c * uy + c * c * u2 * y2, EPSf);
  float num2 = fmaxf(A * A * u2 + 2.f * A * B * uy + B * B * y2, 0.f);
  float n = sqrtf(num2) / den;
  float arg = sc * n;
  arg = fminf(fmaxf(arg, 0.f), 1.f - 1e-5f);
  return (1.f / sc) * logf((1.f + arg) / (1.f - arg));
}

__device__ __forceinline__ double expmap_scale(double c, double p2, double* u2out) {
  double sc = sqrt(c);
  double ntrue = sqrt(p2);
  double nf = fmax(ntrue, 1e-5);
  double th = tanh(sc * nf);
  double s0 = th / (sc * nf);
  double ny = fmax(s0 * ntrue, 1e-5);
  double mx = 0.999 / sc;
  if (ny > mx) s0 *= mx / ny;
  *u2out = s0 * s0 * p2;
  return s0;
}

// grid 128 x 640: protos + P2RAW + H1P (b<32), per-row q2, QPART (+shot fold)
__global__ __launch_bounds__(640) void k_fuse1(const float* __restrict__ Qm,
                                               const float* __restrict__ shot,
                                               const float* __restrict__ W1, float* ws) {
  __shared__ double q2w[32][10];
  __shared__ double psred[10];
  __shared__ float pr[DIM];
  __shared__ float h1pp[5][128];
  int b = blockIdx.x, t = threadIdx.x;
  int lane = t & 63, wid = t >> 6;  // 10 waves
  float protoval = 0.f;
  if (b < WAY) {
    float s = 0.f;
#pragma unroll
    for (int s5 = 0; s5 < NSHOT; ++s5) s += shot[(size_t)(s5 * WAY + b) * DIM + t];
    protoval = s * 0.2f;
    pr[t] = protoval;
    ws[OFF_PROTOS + b * DIM + t] = protoval;
    double pv2 = (double)protoval * protoval;
    pv2 = wave_sum_d(pv2);
    if (lane == 0) psred[wid] = pv2;
  }
  int r0 = b * 32;
  float colacc = 0.f;
  for (int r = 0; r < 32; ++r) {
    float v = Qm[(size_t)(r0 + r) * DIM + t];
    colacc += v;
    double sq = (double)v * v;
    sq = wave_sum_d(sq);
    if (lane == 0) q2w[r][wid] = sq;
  }
  ws[OFF_QPART + b * DIM + t] = colacc + 5.f * protoval;
  __syncthreads();
  if (t < 32) {
    double s = 0.0;
#pragma unroll
    for (int k = 0; k < 10; ++k) s += q2w[t][k];
    ((double*)(ws + OFF_Q2D))[r0 + t] = s;
  }
  if (b < WAY) {
    int n = t & 127, s = t >> 7;
    int k0 = s * 128;
    float acc = 0.f;
#pragma unroll 8
    for (int k = k0; k < k0 + 128; ++k) acc = fmaf(pr[k], W1[(size_t)k * 128 + n], acc);
    h1pp[s][n] = acc;
    __syncthreads();
    if (t < 128)
      ws[OFF_H1P + b * 128 + t] = h1pp[0][t] + h1pp[1][t] + h1pp[2][t] + h1pp[3][t] + h1pp[4][t];
    if (t == 0) {
      double p2 = 0.0;
#pragma unroll
      for (int k = 0; k < 10; ++k) p2 += psred[k];
      ((double*)(ws + OFF_P2RAW))[b] = p2;
    }
  }
}

// grid 8 x 320: way-independent ctrl work, done ONCE.
// Block j: am slice [j*80, j*80+80) from QPART, then h1part[j] = am_slice · W1b_slice.
__global__ __launch_bounds__(320) void k_amw1(const float* __restrict__ W1, float* ws) {
  __shared__ float part_am[4][80];
  __shared__ float am_s[80];
  __shared__ float h1part[2][128];
  int j = blockIdx.x, t = threadIdx.x;
  {
    int c = t % 80, pg = t / 80;   // 4 p-groups x 32
    const float* base = ws + OFF_QPART + j * 80 + c;
    int p0 = pg * 32;
    float a0 = 0.f, a1 = 0.f, a2 = 0.f, a3 = 0.f;
#pragma unroll 8
    for (int p = 0; p < 32; p += 4) {
      a0 += base[(size_t)(p0 + p + 0) * DIM];
      a1 += base[(size_t)(p0 + p + 1) * DIM];
      a2 += base[(size_t)(p0 + p + 2) * DIM];
      a3 += base[(size_t)(p0 + p + 3) * DIM];
    }
    part_am[pg][c] = (a0 + a1) + (a2 + a3);
  }
  __syncthreads();
  if (t < 80)
    am_s[t] = (part_am[0][t] + part_am[1][t] + part_am[2][t] + part_am[3][t]) * (1.f / 4256.f);
  __syncthreads();
  if (t < 256) {
    int n = t & 127, kh = t >> 7;      // 2 k-halves x 40
    int kbase = j * 80 + kh * 40;
    float acc = 0.f;
#pragma unroll 8
    for (int k = 0; k < 40; ++k)
      acc = fmaf(am_s[kh * 40 + k], W1[(size_t)(DIM + kbase + k) * 128 + n], acc);
    h1part[kh][n] = acc;
  }
  __syncthreads();
  if (t < 128) ws[OFF_H1PART + j * 128 + t] = h1part[0][t] + h1part[1][t];
}

// grid 32 x 128: per-way MLP tail: h1 -> h2 -> logits -> softmax -> C/BETA/X2D
__global__ __launch_bounds__(128) void k_ctrl2(const float* __restrict__ b1,
                                               const float* __restrict__ W2, const float* __restrict__ b2,
                                               const float* __restrict__ W3, const float* __restrict__ b3,
                                               float* ws) {
  __shared__ float h1s[128];
  __shared__ float h2p[2][64];
  __shared__ float h2s[64], lg[5];
  int w = blockIdx.x, t = threadIdx.x;
  {
    float a = ws[OFF_H1P + w * 128 + t] + b1[t];
#pragma unroll
    for (int j = 0; j < 8; ++j) a += ws[OFF_H1PART + j * 128 + t];
    h1s[t] = fmaxf(a, 0.f);
  }
  __syncthreads();
  {
    int n = t & 63, kh = t >> 6;       // 2 k-halves x 64
    int k0 = kh * 64;
    float acc = 0.f;
#pragma unroll 8
    for (int k = 0; k < 64; ++k)
      acc = fmaf(h1s[k0 + k], W2[(size_t)(k0 + k) * 64 + n], acc);
    h2p[kh][n] = acc;
  }
  __syncthreads();
  if (t < 64) h2s[t] = fmaxf(h2p[0][t] + h2p[1][t] + b2[t], 0.f);
  __syncthreads();
  if (t < 5) {
    float acc = b3[t];
    for (int k = 0; k < 64; ++k) acc = fmaf(h2s[k], W3[k * 5 + t], acc);
    lg[t] = acc;
  }
  __syncthreads();
  if (t == 0) {
    double m = lg[0];
    for (int i = 1; i < 5; ++i) m = fmax(m, (double)lg[i]);
    double se = 0.0, cv = 0.0;
    for (int i = 0; i < 5; ++i) { double e = exp((double)lg[i] - m); se += e; cv += e * 0.2 * (double)(i + 1); }
    double c = cv / se;
    ws[OFF_C + w] = (float)c;
    double p2 = ((const double*)(ws + OFF_P2RAW))[w];
    double u2;
    double beta = expmap_scale(c, p2, &u2);
    ws[OFF_BETA + w] = (float)beta;
    ((double*)(ws + OFF_X2D))[w] = u2;
  }
}

// grid 512 x 256: GEMM (X rows 0..31) vs 8 q-rows.
// mode 0: f32 dist epilogue -> DIS (selection path). mode 1: f64 dist -> out.
__global__ __launch_bounds__(256) void k_gemm(const float* __restrict__ X, const float* __restrict__ Qm,
                                              float* __restrict__ ws, int mode, float* __restrict__ out) {
  __shared__ float S[2][40][68];
  int t = threadIdx.x;
  int q0 = blockIdx.x * 8;
  int rowA = t >> 4, quadA = t & 15;
  int rowB = (t + 256) >> 4;
  int rowC = (t + 512) >> 4;
  bool hasC = (t < 128);
  const float* srcA = (rowA < 8 ? Qm + (size_t)(q0 + rowA) * DIM : X + (size_t)(rowA - 8) * DIM) + quadA * 4;
  const float* srcB = X + (size_t)(rowB - 8) * DIM + quadA * 4;
  const float* srcC = X + (size_t)(rowC - 8) * DIM + quadA * 4;
  float4 pA = *(const float4*)srcA;
  float4 pB = *(const float4*)srcB;
  float4 pC = {0.f, 0.f, 0.f, 0.f};
  if (hasC) pC = *(const float4*)srcC;
  *(float4*)&S[0][rowA][quadA * 4] = pA;
  *(float4*)&S[0][rowB][quadA * 4] = pB;
  if (hasC) *(float4*)&S[0][rowC][quadA * 4] = pC;
  __syncthreads();
  int q = t & 7, w = t >> 3;
  float ax = 0.f, ay = 0.f, az = 0.f, aw = 0.f;
  for (int c = 0; c < 10; ++c) {
    int bsel = c & 1;
    if (c < 9) {
      size_t kc = (size_t)(c + 1) * 64;
      pA = *(const float4*)(srcA + kc);
      pB = *(const float4*)(srcB + kc);
      if (hasC) pC = *(const float4*)(srcC + kc);
    }
    const float* qr = &S[bsel][q][0];
    const float* xr = &S[bsel][8 + w][0];
#pragma unroll
    for (int kk = 0; kk < 64; kk += 4) {
      float4 qv = *(const float4*)(qr + kk);
      float4 xv = *(const float4*)(xr + kk);
      ax = fmaf(qv.x, xv.x, ax);
      ay = fmaf(qv.y, xv.y, ay);
      az = fmaf(qv.z, xv.z, az);
      aw = fmaf(qv.w, xv.w, aw);
    }
    if (c < 9) {
      int nb = bsel ^ 1;
      *(float4*)&S[nb][rowA][quadA * 4] = pA;
      *(float4*)&S[nb][rowB][quadA * 4] = pB;
      if (hasC) *(float4*)&S[nb][rowC][quadA * 4] = pC;
      __syncthreads();
    }
  }
  float acc = (ax + ay) + (az + aw);
  int qq = q0 + q;
  const double* q2d = (const double*)(ws + OFF_Q2D);
  if (mode == 0) {
    const double* x2d = (const double*)(ws + OFF_X2D);
    float d = dist_f32(ws[OFF_C + w], ws[OFF_BETA + w] * acc, (float)x2d[w], (float)q2d[qq]);
    ws[OFF_G + (size_t)w * NQ + qq] = d;
  } else {
    const double* u2arr = (const double*)(ws + OFF_X2D2);
    double d = dist_hyp((double)ws[OFF_C + w], (double)acc, u2arr[w], q2d[qq]);
    out[(size_t)qq * WAY + w] = (float)(-d / 16.0);
  }
}

// grid 32 x 1024: per-way top-10 + S/U + stats from precomputed DIS (no transcendentals)
__global__ __launch_bounds__(1024) void k_topkA(float* __restrict__ ws) {
  __shared__ double sredS[16], sredU[16];
  __shared__ float cval[160];
  __shared__ int cidx[160];
  __shared__ float qvsh[RNEAR];
  __shared__ int qjsh[RNEAR];
  __shared__ float colsh[RNEAR][33];
  __shared__ float pcpart[RNEAR];
  int w = blockIdx.x, t = threadIdx.x;
  int lane = t & 63, wid = t >> 6;
  int* nidx = (int*)(ws + OFF_NIDX);
  const float* gb = ws + OFF_G + (size_t)w * NQ;
  float v0 = gb[t], v1 = gb[1024 + t], v2 = gb[2048 + t], v3 = gb[3072 + t];
  unsigned tk = 0;
  double s = (double)v0 + (double)v1 + (double)v2 + (double)v3;
  double u = (t < RNEAR) ? (double)v0 : 0.0;
  s = wave_sum_d(s);
  u = wave_sum_d(u);
  if (lane == 0) { sredS[wid] = s; sredU[wid] = u; }
  for (int r = 0; r < RNEAR; ++r) {
    float lv = INFINITY; int li = 0x7fffffff;
    if (!(tk & 1u) && (v0 < lv || (v0 == lv && t < li)))        { lv = v0; li = t; }
    if (!(tk & 2u) && (v1 < lv || (v1 == lv && 1024 + t < li))) { lv = v1; li = 1024 + t; }
    if (!(tk & 4u) && (v2 < lv || (v2 == lv && 2048 + t < li))) { lv = v2; li = 2048 + t; }
    if (!(tk & 8u) && (v3 < lv || (v3 == lv && 3072 + t < li))) { lv = v3; li = 3072 + t; }
#pragma unroll
    for (int o = 32; o > 0; o >>= 1) {
      float ov = __shfl_xor(lv, o, 64);
      int oi = __shfl_xor(li, o, 64);
      if (ov < lv || (ov == lv && oi < li)) { lv = ov; li = oi; }
    }
    if (lane == 0) { cval[wid * RNEAR + r] = lv; cidx[wid * RNEAR + r] = li; }
    if ((li & 1023) == t) tk |= 1u << (li >> 10);
  }
  __syncthreads();
  if (t == 0) {
    double S = 0.0, U = 0.0;
    for (int k = 0; k < 16; ++k) { S += sredS[k]; U += sredU[k]; }
    ws[OFF_S + w] = (float)S;
    ws[OFF_U + w] = (float)U;
  }
  if (t < 64) {
    float c0 = cval[t], c1 = cval[t + 64];
    int i0 = cidx[t], i1 = cidx[t + 64];
    float c2 = (t < 32) ? cval[t + 128] : INFINITY;
    int i2 = (t < 32) ? cidx[t + 128] : 0x7fffffff;
    unsigned m = 0;
    for (int r = 0; r < RNEAR; ++r) {
      float lv = INFINITY; int li = 0x7fffffff;
      if (!(m & 1u) && (c0 < lv || (c0 == lv && i0 < li))) { lv = c0; li = i0; }
      if (!(m & 2u) && (c1 < lv || (c1 == lv && i1 < li))) { lv = c1; li = i1; }
      if (!(m & 4u) && (c2 < lv || (c2 == lv && i2 < li))) { lv = c2; li = i2; }
#pragma unroll
      for (int o = 32; o > 0; o >>= 1) {
        float ov = __shfl_xor(lv, o, 64);
        int oi = __shfl_xor(li, o, 64);
        if (ov < lv || (ov == lv && oi < li)) { lv = ov; li = oi; }
      }
      if (lane == 0) { qvsh[r] = lv; qjsh[r] = li; }
      if (i0 == li) m |= 1u;
      if (i1 == li) m |= 2u;
      if (i2 == li) m |= 4u;
    }
  }
  __syncthreads();
  if (t < WAY * RNEAR) {
    int j = t >> 5, w2 = t & 31;
    colsh[j][w2] = ws[OFF_G + (size_t)w2 * NQ + qjsh[j]];
  }
  __syncthreads();
  if (t < RNEAR) {
    double cs = 0.0, pc = 0.0;
    for (int w2 = 0; w2 < WAY; ++w2) {
      float dv = colsh[t][w2];
      cs += dv;
      if (w2 < w) pc += dv;
    }
    ws[OFF_RR + w * 22 + t] = qvsh[t];
    ws[OFF_RR + w * 22 + RNEAR + t] = (float)((cs - qvsh[t]) / (double)(WAY - 1));
    ws[OFF_NID + w * RNEAR + t] = qvsh[t];
    nidx[w * RNEAR + t] = qjsh[t];
    pcpart[t] = (float)pc;
  }
  __syncthreads();
  if (t == 0) {
    double spc = 0.0, sn = 0.0;
    for (int j = 0; j < RNEAR; ++j) { spc += pcpart[j]; sn += qvsh[j]; }
    double S = (double)ws[OFF_S + w];
    ws[OFF_RR + w * 22 + 20] = (float)((S - sn) / (double)(NQ - RNEAR));
    ws[OFF_SPC + w] = (float)spc;
  }
}

// grid 32 x 640: per-way refine MLP + tmp/expmap -> TP
__global__ __launch_bounds__(640) void k_refB(const float* __restrict__ Qm,
                                              const float* __restrict__ Wr1, const float* __restrict__ br1,
                                              const float* __restrict__ Wr2, const float* __restrict__ br2,
                                              float* __restrict__ ws) {
  __shared__ float Ssh[WAY], Ush[WAY];
  __shared__ float rrl[22];
  __shared__ int qj[RNEAR];
  __shared__ float hr[RNEAR], orsh[11], iw[RNEAR];
  __shared__ float onw_sh;
  __shared__ double p2red[10];
  __shared__ double gshd;
  int w = blockIdx.x, t = threadIdx.x;
  int lane = t & 63, wid = t >> 6;  // 10 waves
  const int* nidx = (const int*)(ws + OFF_NIDX);
  if (t < WAY) { Ssh[t] = ws[OFF_S + t]; Ush[t] = ws[OFF_U + t]; }
  if (t >= 64 && t < 64 + 22) rrl[t - 64] = ws[OFF_RR + w * 22 + (t - 64)];
  if (t >= 96 && t < 96 + RNEAR) qj[t - 96] = nidx[w * RNEAR + (t - 96)];
  __syncthreads();
  if (t == 0) {
    double pref = 0.0, suf = 0.0;
    for (int j = 0; j < w; ++j) pref += (double)Ssh[j];
    for (int j = w + 1; j < WAY; ++j) suf += (double)Ssh[j] - (double)Ush[j];
    double spc = (double)ws[OFF_SPC + w];
    rrl[21] = (float)((pref - spc + suf) / ((double)(WAY - 1) * (double)(NQ - RNEAR)));
  }
  __syncthreads();
  if (t < RNEAR) {
    float a = br1[t];
    for (int k = 0; k < 22; ++k) a = fmaf(rrl[k], Wr1[k * RNEAR + t], a);
    hr[t] = fmaxf(a, 0.f);
  }
  __syncthreads();
  if (t < 11) {
    float a = br2[t];
    for (int k = 0; k < RNEAR; ++k) a = fmaf(hr[k], Wr2[k * 11 + t], a);
    orsh[t] = a;
  }
  __syncthreads();
  if (t == 0) {
    double m = orsh[0];
    for (int i = 1; i < RNEAR; ++i) m = fmax(m, (double)orsh[i]);
    double se = 0.0; double e[RNEAR];
    for (int i = 0; i < RNEAR; ++i) { e[i] = exp((double)orsh[i] - m); se += e[i]; }
    for (int i = 0; i < RNEAR; ++i) iw[i] = (float)(e[i] / se);
    onw_sh = (float)(1.0 / (1.0 + exp(-(double)orsh[10])));
  }
  __syncthreads();
  float onwv = onw_sh;
  float wd = 0.f;
#pragma unroll
  for (int j = 0; j < RNEAR; ++j)
    wd = fmaf(Qm[(size_t)qj[j] * DIM + t], iw[j], wd);
  float a0 = ws[OFF_PROTOS + w * DIM + t] * onwv + wd * (1.f - onwv);
  double ls = (double)a0 * a0;
  ls = wave_sum_d(ls);
  if (lane == 0) p2red[wid] = ls;
  __syncthreads();
  if (t == 0) {
    double p2 = 0.0;
#pragma unroll
    for (int k = 0; k < 10; ++k) p2 += p2red[k];
    double u22;
    gshd = expmap_scale((double)ws[OFF_C + w], p2, &u22);
    ((double*)(ws + OFF_X2D2))[w] = u22;
  }
  __syncthreads();
  ws[OFF_TP + w * DIM + t] = (float)gshd * a0;
}

extern "C" void kernel_launch(void* const* d_in, const int* in_sizes, int n_in,
                              void* d_out, int out_size, void* d_ws, size_t ws_size,
                              hipStream_t stream) {
  (void)in_sizes; (void)n_in; (void)out_size; (void)ws_size;
  const float* shot = (const float*)d_in[0];
  const float* qry  = (const float*)d_in[1];
  const float* W1   = (const float*)d_in[2];
  const float* b1   = (const float*)d_in[3];
  const float* W2   = (const float*)d_in[4];
  const float* b2   = (const float*)d_in[5];
  const float* W3   = (const float*)d_in[6];
  const float* b3   = (const float*)d_in[7];
  const float* Wr1  = (const float*)d_in[8];
  const float* br1  = (const float*)d_in[9];
  const float* Wr2  = (const float*)d_in[10];
  const float* br2  = (const float*)d_in[11];
  float* ws = (float*)d_ws;
  float* out = (float*)d_out;

  hipLaunchKernelGGL(k_fuse1, dim3(128), dim3(640), 0, stream, qry, shot, W1, ws);
  hipLaunchKernelGGL(k_amw1,  dim3(8), dim3(320), 0, stream, W1, ws);
  hipLaunchKernelGGL(k_ctrl2, dim3(32), dim3(128), 0, stream, b1, W2, b2, W3, b3, ws);
  hipLaunchKernelGGL(k_gemm,  dim3(512), dim3(256), 0, stream, ws + OFF_PROTOS, qry, ws, 0, out);
  hipLaunchKernelGGL(k_topkA, dim3(32), dim3(1024), 0, stream, ws);
  hipLaunchKernelGGL(k_refB,  dim3(32), dim3(640), 0, stream, qry, Wr1, br1, Wr2, br2, ws);
  hipLaunchKernelGGL(k_gemm,  dim3(512), dim3(256), 0, stream, ws + OFF_TP, qry, ws, 1, out);
}

// Round 20
// 81.629 us; speedup vs baseline: 1.6534x; 1.0003x over previous
//
#include <hip/hip_runtime.h>
#include <math.h>

#define NSHOT 5
#define WAY 32
#define DIM 640
#define NQ 4096
#define RNEAR 10

// ---- workspace layout (float offsets), ~1.08 MB ----
constexpr int OFF_PROTOS = 0;        // 32*640
constexpr int OFF_QPART  = 20480;    // 128*640 column partial sums (incl. shot fold)
constexpr int OFF_C      = 102400;   // 32
constexpr int OFF_BETA   = 102432;   // 32
constexpr int OFF_S      = 102464;   // 32
constexpr int OFF_U      = 102496;   // 32
constexpr int OFF_NID    = 102528;   // 32*10
constexpr int OFF_RR     = 102848;   // 32*22
constexpr int OFF_SPC    = 103552;   // 32
constexpr int OFF_H1P    = 103584;   // 32*128 (per-way pr·W1a)
constexpr int OFF_TP     = 107680;   // 32*640
constexpr int OFF_G      = 128160;   // 32*4096 f32 DISTANCES (written by gemm mode 0)
constexpr int OFF_NIDX   = 259232;   // 32*10 ints
constexpr int OFF_Q2D    = 259556;   // double[4096] (byte-offset %8 == 0)
constexpr int OFF_X2D    = 267748;   // double[32] (proto_p norm^2)
constexpr int OFF_X2D2   = 267812;   // double[32] (test_proto norm^2)
constexpr int OFF_P2RAW  = 267876;   // double[32] (raw proto norm^2)
constexpr int OFF_H1PART = 268000;   // 8*128 way-independent h1 partials

__device__ __forceinline__ double wave_sum_d(double v) {
#pragma unroll
  for (int o = 32; o > 0; o >>= 1) v += __shfl_down(v, o, 64);
  return v;
}

// f64 distance — OUTPUT path only (gemm mode 1 epilogue)
__device__ __forceinline__ double dist_hyp(double c, double xdotq, double u2, double q2) {
  const double EPSd = 1e-5;
  double sc = sqrt(c);
  double nq = sqrt(q2);
  double nf = fmax(nq, EPSd);
  double th = tanh(sc * nf);
  double al = th / (sc * nf);
  double ny = fmax(al * nq, EPSd);
  double mx = 0.999 / sc;
  if (ny > mx) al *= mx / ny;
  double y2 = al * al * q2;
  double uy = -al * xdotq;
  double A = 1.0 + 2.0 * c * uy + c * y2;
  double B = 1.0 - c * u2;
  double den = fmax(1.0 + 2.0 * c * uy + c * c * u2 * y2, EPSd);
  double num2 = fmax(A * A * u2 + 2.0 * A * B * uy + B * B * y2, 0.0);
  double n = sqrt(num2) / den;
  double arg = sc * n;
  const double CLIP = (double)(1.0f - 1e-5f);
  arg = fmin(fmax(arg, 0.0), CLIP);
  return (1.0 / sc) * log((1.0 + arg) / (1.0 - arg));
}

// f32 fast distance — selection/stats path (gemm mode 0 epilogue)
__device__ __forceinline__ float dist_f32(float c, float xdotq, float u2, float q2) {
  const float EPSf = 1e-5f;
  float sc = sqrtf(c);
  float nq = sqrtf(q2);
  float nf = fmaxf(nq, EPSf);
  float th = tanhf(sc * nf);
  float al = th / (sc * nf);
  float ny = fmaxf(al * nq, EPSf);
  float mx = 0.999f / sc;
  if (ny > mx) al *= mx / ny;
  float y2 = al * al * q2;
  float uy = -al * xdotq;
  float A = 1.f + 2.f * c * uy + c * y2;
  float B = 1.f - c * u2;
  float den = fmaxf(1.f + 2.f * c * uy + c * c * u2 * y2, EPSf);
  float num2 = fmaxf(A * A * u2 + 2.f * A * B * uy + B * B * y2, 0.f);
  float n = sqrtf(num2) / den;
  float arg = sc * n;
  arg = fminf(fmaxf(arg, 0.f), 1.f - 1e-5f);
  return (1.f / sc) * logf((1.f + arg) / (1.f - arg));
}

__device__ __forceinline__ double expmap_scale(double c, double p2, double* u2out) {
  double sc = sqrt(c);
  double ntrue = sqrt(p2);
  double nf = fmax(ntrue, 1e-5);
  double th = tanh(sc * nf);
  double s0 = th / (sc * nf);
  double ny = fmax(s0 * ntrue, 1e-5);
  double mx = 0.999 / sc;
  if (ny > mx) s0 *= mx / ny;
  *u2out = s0 * s0 * p2;
  return s0;
}

// grid 128 x 640: protos + P2RAW + H1P (b<32), per-row q2, QPART (+shot fold)
__global__ __launch_bounds__(640) void k_fuse1(const float* __restrict__ Qm,
                                               const float* __restrict__ shot,
                                               const float* __restrict__ W1, float* ws) {
  __shared__ double q2w[32][10];
  __shared__ double psred[10];
  __shared__ float pr[DIM];
  __shared__ float h1pp[5][128];
  int b = blockIdx.x, t = threadIdx.x;
  int lane = t & 63, wid = t >> 6;  // 10 waves
  float protoval = 0.f;
  if (b < WAY) {
    float s = 0.f;
#pragma unroll
    for (int s5 = 0; s5 < NSHOT; ++s5) s += shot[(size_t)(s5 * WAY + b) * DIM + t];
    protoval = s * 0.2f;
    pr[t] = protoval;
    ws[OFF_PROTOS + b * DIM + t] = protoval;
    double pv2 = (double)protoval * protoval;
    pv2 = wave_sum_d(pv2);
    if (lane == 0) psred[wid] = pv2;
  }
  int r0 = b * 32;
  float colacc = 0.f;
  for (int r = 0; r < 32; ++r) {
    float v = Qm[(size_t)(r0 + r) * DIM + t];
    colacc += v;
    double sq = (double)v * v;
    sq = wave_sum_d(sq);
    if (lane == 0) q2w[r][wid] = sq;
  }
  ws[OFF_QPART + b * DIM + t] = colacc + 5.f * protoval;
  __syncthreads();
  if (t < 32) {
    double s = 0.0;
#pragma unroll
    for (int k = 0; k < 10; ++k) s += q2w[t][k];
    ((double*)(ws + OFF_Q2D))[r0 + t] = s;
  }
  if (b < WAY) {
    int n = t & 127, s = t >> 7;
    int k0 = s * 128;
    float acc = 0.f;
#pragma unroll 8
    for (int k = k0; k < k0 + 128; ++k) acc = fmaf(pr[k], W1[(size_t)k * 128 + n], acc);
    h1pp[s][n] = acc;
    __syncthreads();
    if (t < 128)
      ws[OFF_H1P + b * 128 + t] = h1pp[0][t] + h1pp[1][t] + h1pp[2][t] + h1pp[3][t] + h1pp[4][t];
    if (t == 0) {
      double p2 = 0.0;
#pragma unroll
      for (int k = 0; k < 10; ++k) p2 += psred[k];
      ((double*)(ws + OFF_P2RAW))[b] = p2;
    }
  }
}

// grid 8 x 320: way-independent ctrl work, done ONCE.
__global__ __launch_bounds__(320) void k_amw1(const float* __restrict__ W1, float* ws) {
  __shared__ float part_am[4][80];
  __shared__ float am_s[80];
  __shared__ float h1part[2][128];
  int j = blockIdx.x, t = threadIdx.x;
  {
    int c = t % 80, pg = t / 80;   // 4 p-groups x 32
    const float* base = ws + OFF_QPART + j * 80 + c;
    int p0 = pg * 32;
    float a0 = 0.f, a1 = 0.f, a2 = 0.f, a3 = 0.f;
#pragma unroll 8
    for (int p = 0; p < 32; p += 4) {
      a0 += base[(size_t)(p0 + p + 0) * DIM];
      a1 += base[(size_t)(p0 + p + 1) * DIM];
      a2 += base[(size_t)(p0 + p + 2) * DIM];
      a3 += base[(size_t)(p0 + p + 3) * DIM];
    }
    part_am[pg][c] = (a0 + a1) + (a2 + a3);
  }
  __syncthreads();
  if (t < 80)
    am_s[t] = (part_am[0][t] + part_am[1][t] + part_am[2][t] + part_am[3][t]) * (1.f / 4256.f);
  __syncthreads();
  if (t < 256) {
    int n = t & 127, kh = t >> 7;      // 2 k-halves x 40
    int kbase = j * 80 + kh * 40;
    float acc = 0.f;
#pragma unroll 8
    for (int k = 0; k < 40; ++k)
      acc = fmaf(am_s[kh * 40 + k], W1[(size_t)(DIM + kbase + k) * 128 + n], acc);
    h1part[kh][n] = acc;
  }
  __syncthreads();
  if (t < 128) ws[OFF_H1PART + j * 128 + t] = h1part[0][t] + h1part[1][t];
}

// grid 32 x 128: per-way MLP tail
__global__ __launch_bounds__(128) void k_ctrl2(const float* __restrict__ b1,
                                               const float* __restrict__ W2, const float* __restrict__ b2,
                                               const float* __restrict__ W3, const float* __restrict__ b3,
                                               float* ws) {
  __shared__ float h1s[128];
  __shared__ float h2p[2][64];
  __shared__ float h2s[64], lg[5];
  int w = blockIdx.x, t = threadIdx.x;
  {
    float a = ws[OFF_H1P + w * 128 + t] + b1[t];
#pragma unroll
    for (int j = 0; j < 8; ++j) a += ws[OFF_H1PART + j * 128 + t];
    h1s[t] = fmaxf(a, 0.f);
  }
  __syncthreads();
  {
    int n = t & 63, kh = t >> 6;       // 2 k-halves x 64
    int k0 = kh * 64;
    float acc = 0.f;
#pragma unroll 8
    for (int k = 0; k < 64; ++k)
      acc = fmaf(h1s[k0 + k], W2[(size_t)(k0 + k) * 64 + n], acc);
    h2p[kh][n] = acc;
  }
  __syncthreads();
  if (t < 64) h2s[t] = fmaxf(h2p[0][t] + h2p[1][t] + b2[t], 0.f);
  __syncthreads();
  if (t < 5) {
    float acc = b3[t];
    for (int k = 0; k < 64; ++k) acc = fmaf(h2s[k], W3[k * 5 + t], acc);
    lg[t] = acc;
  }
  __syncthreads();
  if (t == 0) {
    double m = lg[0];
    for (int i = 1; i < 5; ++i) m = fmax(m, (double)lg[i]);
    double se = 0.0, cv = 0.0;
    for (int i = 0; i < 5; ++i) { double e = exp((double)lg[i] - m); se += e; cv += e * 0.2 * (double)(i + 1); }
    double c = cv / se;
    ws[OFF_C + w] = (float)c;
    double p2 = ((const double*)(ws + OFF_P2RAW))[w];
    double u2;
    double beta = expmap_scale(c, p2, &u2);
    ws[OFF_BETA + w] = (float)beta;
    ((double*)(ws + OFF_X2D))[w] = u2;
  }
}

#define GEMM_COMPUTE(BUF)                                             \
  {                                                                   \
    const float* qr = &S[BUF][q][0];                                  \
    const float* xr = &S[BUF][8 + w][0];                              \
    _Pragma("unroll")                                                 \
    for (int kk = 0; kk < 64; kk += 4) {                              \
      float4 qv = *(const float4*)(qr + kk);                          \
      float4 xv = *(const float4*)(xr + kk);                          \
      ax = fmaf(qv.x, xv.x, ax);                                      \
      ay = fmaf(qv.y, xv.y, ay);                                      \
      az = fmaf(qv.z, xv.z, az);                                      \
      aw = fmaf(qv.w, xv.w, aw);                                      \
    }                                                                 \
  }

// grid 512 x 256: GEMM (X rows 0..31) vs 8 q-rows, depth-2 register prefetch.
// mode 0: f32 dist epilogue -> DIS. mode 1: f64 dist -> out.
__global__ __launch_bounds__(256) void k_gemm(const float* __restrict__ X, const float* __restrict__ Qm,
                                              float* __restrict__ ws, int mode, float* __restrict__ out) {
  __shared__ float S[2][40][68];
  int t = threadIdx.x;
  int q0 = blockIdx.x * 8;
  int rowA = t >> 4, quadA = t & 15;
  int rowB = (t + 256) >> 4;
  int rowC = (t + 512) >> 4;
  bool hasC = (t < 128);
  const float* srcA = (rowA < 8 ? Qm + (size_t)(q0 + rowA) * DIM : X + (size_t)(rowA - 8) * DIM) + quadA * 4;
  const float* srcB = X + (size_t)(rowB - 8) * DIM + quadA * 4;
  const float* srcC = X + (size_t)(rowC - 8) * DIM + quadA * 4;
  // stage chunk 0 directly
  float4 a0 = *(const float4*)srcA;
  float4 a1 = *(const float4*)srcB;
  float4 a2 = {0.f, 0.f, 0.f, 0.f};
  if (hasC) a2 = *(const float4*)srcC;
  *(float4*)&S[0][rowA][quadA * 4] = a0;
  *(float4*)&S[0][rowB][quadA * 4] = a1;
  if (hasC) *(float4*)&S[0][rowC][quadA * 4] = a2;
  __syncthreads();
  // preload chunk 1 into set A
  a0 = *(const float4*)(srcA + 64);
  a1 = *(const float4*)(srcB + 64);
  if (hasC) a2 = *(const float4*)(srcC + 64);
  float4 b0 = {0.f,0.f,0.f,0.f}, b1 = b0, b2 = b0;
  int q = t & 7, w = t >> 3;
  float ax = 0.f, ay = 0.f, az = 0.f, aw = 0.f;
#pragma unroll
  for (int c = 0; c < 10; c += 2) {
    // even chunk c: compute S[0]; prefetch chunk c+2 into set B; publish A -> S[1]
    GEMM_COMPUTE(0)
    if (c + 2 < 10) {
      size_t kc = (size_t)(c + 2) * 64;
      b0 = *(const float4*)(srcA + kc);
      b1 = *(const float4*)(srcB + kc);
      if (hasC) b2 = *(const float4*)(srcC + kc);
    }
    if (c + 1 < 10) {
      *(float4*)&S[1][rowA][quadA * 4] = a0;
      *(float4*)&S[1][rowB][quadA * 4] = a1;
      if (hasC) *(float4*)&S[1][rowC][quadA * 4] = a2;
      __syncthreads();
      // odd chunk c+1: compute S[1]; prefetch chunk c+3 into set A; publish B -> S[0]
      GEMM_COMPUTE(1)
      if (c + 3 < 10) {
        size_t kc = (size_t)(c + 3) * 64;
        a0 = *(const float4*)(srcA + kc);
        a1 = *(const float4*)(srcB + kc);
        if (hasC) a2 = *(const float4*)(srcC + kc);
      }
      if (c + 2 < 10) {
        *(float4*)&S[0][rowA][quadA * 4] = b0;
        *(float4*)&S[0][rowB][quadA * 4] = b1;
        if (hasC) *(float4*)&S[0][rowC][quadA * 4] = b2;
        __syncthreads();
      }
    }
  }
  float acc = (ax + ay) + (az + aw);
  int qq = q0 + q;
  const double* q2d = (const double*)(ws + OFF_Q2D);
  if (mode == 0) {
    const double* x2d = (const double*)(ws + OFF_X2D);
    float d = dist_f32(ws[OFF_C + w], ws[OFF_BETA + w] * acc, (float)x2d[w], (float)q2d[qq]);
    ws[OFF_G + (size_t)w * NQ + qq] = d;
  } else {
    const double* u2arr = (const double*)(ws + OFF_X2D2);
    double d = dist_hyp((double)ws[OFF_C + w], (double)acc, u2arr[w], q2d[qq]);
    out[(size_t)qq * WAY + w] = (float)(-d / 16.0);
  }
}

// grid 32 x 1024: per-way top-10 + S/U + stats from precomputed DIS
__global__ __launch_bounds__(1024) void k_topkA(float* __restrict__ ws) {
  __shared__ double sredS[16], sredU[16];
  __shared__ float cval[160];
  __shared__ int cidx[160];
  __shared__ float qvsh[RNEAR];
  __shared__ int qjsh[RNEAR];
  __shared__ float colsh[RNEAR][33];
  __shared__ float pcpart[RNEAR];
  int w = blockIdx.x, t = threadIdx.x;
  int lane = t & 63, wid = t >> 6;
  int* nidx = (int*)(ws + OFF_NIDX);
  const float* gb = ws + OFF_G + (size_t)w * NQ;
  float v0 = gb[t], v1 = gb[1024 + t], v2 = gb[2048 + t], v3 = gb[3072 + t];
  unsigned tk = 0;
  double s = (double)v0 + (double)v1 + (double)v2 + (double)v3;
  double u = (t < RNEAR) ? (double)v0 : 0.0;
  s = wave_sum_d(s);
  u = wave_sum_d(u);
  if (lane == 0) { sredS[wid] = s; sredU[wid] = u; }
  for (int r = 0; r < RNEAR; ++r) {
    float lv = INFINITY; int li = 0x7fffffff;
    if (!(tk & 1u) && (v0 < lv || (v0 == lv && t < li)))        { lv = v0; li = t; }
    if (!(tk & 2u) && (v1 < lv || (v1 == lv && 1024 + t < li))) { lv = v1; li = 1024 + t; }
    if (!(tk & 4u) && (v2 < lv || (v2 == lv && 2048 + t < li))) { lv = v2; li = 2048 + t; }
    if (!(tk & 8u) && (v3 < lv || (v3 == lv && 3072 + t < li))) { lv = v3; li = 3072 + t; }
#pragma unroll
    for (int o = 32; o > 0; o >>= 1) {
      float ov = __shfl_xor(lv, o, 64);
      int oi = __shfl_xor(li, o, 64);
      if (ov < lv || (ov == lv && oi < li)) { lv = ov; li = oi; }
    }
    if (lane == 0) { cval[wid * RNEAR + r] = lv; cidx[wid * RNEAR + r] = li; }
    if ((li & 1023) == t) tk |= 1u << (li >> 10);
  }
  __syncthreads();
  if (t == 0) {
    double S = 0.0, U = 0.0;
    for (int k = 0; k < 16; ++k) { S += sredS[k]; U += sredU[k]; }
    ws[OFF_S + w] = (float)S;
    ws[OFF_U + w] = (float)U;
  }
  if (t < 64) {
    float c0 = cval[t], c1 = cval[t + 64];
    int i0 = cidx[t], i1 = cidx[t + 64];
    float c2 = (t < 32) ? cval[t + 128] : INFINITY;
    int i2 = (t < 32) ? cidx[t + 128] : 0x7fffffff;
    unsigned m = 0;
    for (int r = 0; r < RNEAR; ++r) {
      float lv = INFINITY; int li = 0x7fffffff;
      if (!(m & 1u) && (c0 < lv || (c0 == lv && i0 < li))) { lv = c0; li = i0; }
      if (!(m & 2u) && (c1 < lv || (c1 == lv && i1 < li))) { lv = c1; li = i1; }
      if (!(m & 4u) && (c2 < lv || (c2 == lv && i2 < li))) { lv = c2; li = i2; }
#pragma unroll
      for (int o = 32; o > 0; o >>= 1) {
        float ov = __shfl_xor(lv, o, 64);
        int oi = __shfl_xor(li, o, 64);
        if (ov < lv || (ov == lv && oi < li)) { lv = ov; li = oi; }
      }
      if (lane == 0) { qvsh[r] = lv; qjsh[r] = li; }
      if (i0 == li) m |= 1u;
      if (i1 == li) m |= 2u;
      if (i2 == li) m |= 4u;
    }
  }
  __syncthreads();
  if (t < WAY * RNEAR) {
    int j = t >> 5, w2 = t & 31;
    colsh[j][w2] = ws[OFF_G + (size_t)w2 * NQ + qjsh[j]];
  }
  __syncthreads();
  if (t < RNEAR) {
    double cs = 0.0, pc = 0.0;
    for (int w2 = 0; w2 < WAY; ++w2) {
      float dv = colsh[t][w2];
      cs += dv;
      if (w2 < w) pc += dv;
    }
    ws[OFF_RR + w * 22 + t] = qvsh[t];
    ws[OFF_RR + w * 22 + RNEAR + t] = (float)((cs - qvsh[t]) / (double)(WAY - 1));
    ws[OFF_NID + w * RNEAR + t] = qvsh[t];
    nidx[w * RNEAR + t] = qjsh[t];
    pcpart[t] = (float)pc;
  }
  __syncthreads();
  if (t == 0) {
    double spc = 0.0, sn = 0.0;
    for (int j = 0; j < RNEAR; ++j) { spc += pcpart[j]; sn += qvsh[j]; }
    double S = (double)ws[OFF_S + w];
    ws[OFF_RR + w * 22 + 20] = (float)((S - sn) / (double)(NQ - RNEAR));
    ws[OFF_SPC + w] = (float)spc;
  }
}

// grid 32 x 640: per-way refine MLP + tmp/expmap -> TP
__global__ __launch_bounds__(640) void k_refB(const float* __restrict__ Qm,
                                              const float* __restrict__ Wr1, const float* __restrict__ br1,
                                              const float* __restrict__ Wr2, const float* __restrict__ br2,
                                              float* __restrict__ ws) {
  __shared__ float Ssh[WAY], Ush[WAY];
  __shared__ float rrl[22];
  __shared__ int qj[RNEAR];
  __shared__ float hr[RNEAR], orsh[11], iw[RNEAR];
  __shared__ float onw_sh;
  __shared__ double p2red[10];
  __shared__ double gshd;
  int w = blockIdx.x, t = threadIdx.x;
  int lane = t & 63, wid = t >> 6;  // 10 waves
  const int* nidx = (const int*)(ws + OFF_NIDX);
  if (t < WAY) { Ssh[t] = ws[OFF_S + t]; Ush[t] = ws[OFF_U + t]; }
  if (t >= 64 && t < 64 + 22) rrl[t - 64] = ws[OFF_RR + w * 22 + (t - 64)];
  if (t >= 96 && t < 96 + RNEAR) qj[t - 96] = nidx[w * RNEAR + (t - 96)];
  __syncthreads();
  if (t == 0) {
    double pref = 0.0, suf = 0.0;
    for (int j = 0; j < w; ++j) pref += (double)Ssh[j];
    for (int j = w + 1; j < WAY; ++j) suf += (double)Ssh[j] - (double)Ush[j];
    double spc = (double)ws[OFF_SPC + w];
    rrl[21] = (float)((pref - spc + suf) / ((double)(WAY - 1) * (double)(NQ - RNEAR)));
  }
  __syncthreads();
  if (t < RNEAR) {
    float a = br1[t];
    for (int k = 0; k < 22; ++k) a = fmaf(rrl[k], Wr1[k * RNEAR + t], a);
    hr[t] = fmaxf(a, 0.f);
  }
  __syncthreads();
  if (t < 11) {
    float a = br2[t];
    for (int k = 0; k < RNEAR; ++k) a = fmaf(hr[k], Wr2[k * 11 + t], a);
    orsh[t] = a;
  }
  __syncthreads();
  if (t == 0) {
    double m = orsh[0];
    for (int i = 1; i < RNEAR; ++i) m = fmax(m, (double)orsh[i]);
    double se = 0.0; double e[RNEAR];
    for (int i = 0; i < RNEAR; ++i) { e[i] = exp((double)orsh[i] - m); se += e[i]; }
    for (int i = 0; i < RNEAR; ++i) iw[i] = (float)(e[i] / se);
    onw_sh = (float)(1.0 / (1.0 + exp(-(double)orsh[10])));
  }
  __syncthreads();
  float onwv = onw_sh;
  float wd = 0.f;
#pragma unroll
  for (int j = 0; j < RNEAR; ++j)
    wd = fmaf(Qm[(size_t)qj[j] * DIM + t], iw[j], wd);
  float a0 = ws[OFF_PROTOS + w * DIM + t] * onwv + wd * (1.f - onwv);
  double ls = (double)a0 * a0;
  ls = wave_sum_d(ls);
  if (lane == 0) p2red[wid] = ls;
  __syncthreads();
  if (t == 0) {
    double p2 = 0.0;
#pragma unroll
    for (int k = 0; k < 10; ++k) p2 += p2red[k];
    double u22;
    gshd = expmap_scale((double)ws[OFF_C + w], p2, &u22);
    ((double*)(ws + OFF_X2D2))[w] = u22;
  }
  __syncthreads();
  ws[OFF_TP + w * DIM + t] = (float)gshd * a0;
}

extern "C" void kernel_launch(void* const* d_in, const int* in_sizes, int n_in,
                              void* d_out, int out_size, void* d_ws, size_t ws_size,
                              hipStream_t stream) {
  (void)in_sizes; (void)n_in; (void)out_size; (void)ws_size;
  const float* shot = (const float*)d_in[0];
  const float* qry  = (const float*)d_in[1];
  const float* W1   = (const float*)d_in[2];
  const float* b1   = (const float*)d_in[3];
  const float* W2   = (const float*)d_in[4];
  const float* b2   = (const float*)d_in[5];
  const float* W3   = (const float*)d_in[6];
  const float* b3   = (const float*)d_in[7];
  const float* Wr1  = (const float*)d_in[8];
  const float* br1  = (const float*)d_in[9];
  const float* Wr2  = (const float*)d_in[10];
  const float* br2  = (const float*)d_in[11];
  float* ws = (float*)d_ws;
  float* out = (float*)d_out;

  hipLaunchKernelGGL(k_fuse1, dim3(128), dim3(640), 0, stream, qry, shot, W1, ws);
  hipLaunchKernelGGL(k_amw1,  dim3(8), dim3(320), 0, stream, W1, ws);
  hipLaunchKernelGGL(k_ctrl2, dim3(32), dim3(128), 0, stream, b1, W2, b2, W3, b3, ws);
  hipLaunchKernelGGL(k_gemm,  dim3(512), dim3(256), 0, stream, ws + OFF_PROTOS, qry, ws, 0, out);
  hipLaunchKernelGGL(k_topkA, dim3(32), dim3(1024), 0, stream, ws);
  hipLaunchKernelGGL(k_refB,  dim3(32), dim3(640), 0, stream, qry, Wr1, br1, Wr2, br2, ws);
  hipLaunchKernelGGL(k_gemm,  dim3(512), dim3(256), 0, stream, ws + OFF_TP, qry, ws, 1, out);
}

// Round 21
// 80.925 us; speedup vs baseline: 1.6677x; 1.0087x over previous
//
#include <hip/hip_runtime.h>
#include <math.h>

#define NSHOT 5
#define WAY 32
#define DIM 640
#define NQ 4096
#define RNEAR 10

// ---- workspace layout (float offsets), ~1.08 MB ----
constexpr int OFF_PROTOS = 0;        // 32*640
constexpr int OFF_QPART  = 20480;    // 128*640 column partial sums (incl. shot fold)
constexpr int OFF_C      = 102400;   // 32
constexpr int OFF_BETA   = 102432;   // 32
constexpr int OFF_S      = 102464;   // 32
constexpr int OFF_U      = 102496;   // 32
constexpr int OFF_NID    = 102528;   // 32*10
constexpr int OFF_RR     = 102848;   // 32*22
constexpr int OFF_SPC    = 103552;   // 32
constexpr int OFF_H1P    = 103584;   // 32*128 (per-way pr·W1a)
constexpr int OFF_TP     = 107680;   // 32*640
constexpr int OFF_G      = 128160;   // 32*4096 f32 DISTANCES (written by gemm mode 0)
constexpr int OFF_NIDX   = 259232;   // 32*10 ints
constexpr int OFF_Q2D    = 259556;   // double[4096] (byte-offset %8 == 0)
constexpr int OFF_X2D    = 267748;   // double[32] (proto_p norm^2)
constexpr int OFF_X2D2   = 267812;   // double[32] (test_proto norm^2)
constexpr int OFF_P2RAW  = 267876;   // double[32] (raw proto norm^2)
constexpr int OFF_H1PART = 268000;   // 8*128 way-independent h1 partials

__device__ __forceinline__ double wave_sum_d(double v) {
#pragma unroll
  for (int o = 32; o > 0; o >>= 1) v += __shfl_down(v, o, 64);
  return v;
}

// f64 distance — OUTPUT path only (gemm mode 1 epilogue)
__device__ __forceinline__ double dist_hyp(double c, double xdotq, double u2, double q2) {
  const double EPSd = 1e-5;
  double sc = sqrt(c);
  double nq = sqrt(q2);
  double nf = fmax(nq, EPSd);
  double th = tanh(sc * nf);
  double al = th / (sc * nf);
  double ny = fmax(al * nq, EPSd);
  double mx = 0.999 / sc;
  if (ny > mx) al *= mx / ny;
  double y2 = al * al * q2;
  double uy = -al * xdotq;
  double A = 1.0 + 2.0 * c * uy + c * y2;
  double B = 1.0 - c * u2;
  double den = fmax(1.0 + 2.0 * c * uy + c * c * u2 * y2, EPSd);
  double num2 = fmax(A * A * u2 + 2.0 * A * B * uy + B * B * y2, 0.0);
  double n = sqrt(num2) / den;
  double arg = sc * n;
  const double CLIP = (double)(1.0f - 1e-5f);
  arg = fmin(fmax(arg, 0.0), CLIP);
  return (1.0 / sc) * log((1.0 + arg) / (1.0 - arg));
}

// f32 fast distance — selection/stats path (gemm mode 0 epilogue)
__device__ __forceinline__ float dist_f32(float c, float xdotq, float u2, float q2) {
  const float EPSf = 1e-5f;
  float sc = sqrtf(c);
  float nq = sqrtf(q2);
  float nf = fmaxf(nq, EPSf);
  float th = tanhf(sc * nf);
  float al = th / (sc * nf);
  float ny = fmaxf(al * nq, EPSf);
  float mx = 0.999f / sc;
  if (ny > mx) al *= mx / ny;
  float y2 = al * al * q2;
  float uy = -al * xdotq;
  float A = 1.f + 2.f * c * uy + c * y2;
  float B = 1.f - c * u2;
  float den = fmaxf(1.f + 2.f * c * uy + c * c * u2 * y2, EPSf);
  float num2 = fmaxf(A * A * u2 + 2.f * A * B * uy + B * B * y2, 0.f);
  float n = sqrtf(num2) / den;
  float arg = sc * n;
  arg = fminf(fmaxf(arg, 0.f), 1.f - 1e-5f);
  return (1.f / sc) * logf((1.f + arg) / (1.f - arg));
}

__device__ __forceinline__ double expmap_scale(double c, double p2, double* u2out) {
  double sc = sqrt(c);
  double ntrue = sqrt(p2);
  double nf = fmax(ntrue, 1e-5);
  double th = tanh(sc * nf);
  double s0 = th / (sc * nf);
  double ny = fmax(s0 * ntrue, 1e-5);
  double mx = 0.999 / sc;
  if (ny > mx) s0 *= mx / ny;
  *u2out = s0 * s0 * p2;
  return s0;
}

// grid 128 x 640: protos + P2RAW + H1P (b<32), per-row q2, QPART (+shot fold)
__global__ __launch_bounds__(640) void k_fuse1(const float* __restrict__ Qm,
                                               const float* __restrict__ shot,
                                               const float* __restrict__ W1, float* ws) {
  __shared__ double q2w[32][10];
  __shared__ double psred[10];
  __shared__ float pr[DIM];
  __shared__ float h1pp[5][128];
  int b = blockIdx.x, t = threadIdx.x;
  int lane = t & 63, wid = t >> 6;  // 10 waves
  float protoval = 0.f;
  if (b < WAY) {
    float s = 0.f;
#pragma unroll
    for (int s5 = 0; s5 < NSHOT; ++s5) s += shot[(size_t)(s5 * WAY + b) * DIM + t];
    protoval = s * 0.2f;
    pr[t] = protoval;
    ws[OFF_PROTOS + b * DIM + t] = protoval;
    double pv2 = (double)protoval * protoval;
    pv2 = wave_sum_d(pv2);
    if (lane == 0) psred[wid] = pv2;
  }
  int r0 = b * 32;
  float colacc = 0.f;
  for (int r = 0; r < 32; ++r) {
    float v = Qm[(size_t)(r0 + r) * DIM + t];
    colacc += v;
    double sq = (double)v * v;
    sq = wave_sum_d(sq);
    if (lane == 0) q2w[r][wid] = sq;
  }
  ws[OFF_QPART + b * DIM + t] = colacc + 5.f * protoval;
  __syncthreads();
  if (t < 32) {
    double s = 0.0;
#pragma unroll
    for (int k = 0; k < 10; ++k) s += q2w[t][k];
    ((double*)(ws + OFF_Q2D))[r0 + t] = s;
  }
  if (b < WAY) {
    int n = t & 127, s = t >> 7;
    int k0 = s * 128;
    float acc = 0.f;
#pragma unroll 8
    for (int k = k0; k < k0 + 128; ++k) acc = fmaf(pr[k], W1[(size_t)k * 128 + n], acc);
    h1pp[s][n] = acc;
    __syncthreads();
    if (t < 128)
      ws[OFF_H1P + b * 128 + t] = h1pp[0][t] + h1pp[1][t] + h1pp[2][t] + h1pp[3][t] + h1pp[4][t];
    if (t == 0) {
      double p2 = 0.0;
#pragma unroll
      for (int k = 0; k < 10; ++k) p2 += psred[k];
      ((double*)(ws + OFF_P2RAW))[b] = p2;
    }
  }
}

// grid 8 x 320: way-independent ctrl work, done ONCE.
__global__ __launch_bounds__(320) void k_amw1(const float* __restrict__ W1, float* ws) {
  __shared__ float part_am[4][80];
  __shared__ float am_s[80];
  __shared__ float h1part[2][128];
  int j = blockIdx.x, t = threadIdx.x;
  {
    int c = t % 80, pg = t / 80;   // 4 p-groups x 32
    const float* base = ws + OFF_QPART + j * 80 + c;
    int p0 = pg * 32;
    float a0 = 0.f, a1 = 0.f, a2 = 0.f, a3 = 0.f;
#pragma unroll 8
    for (int p = 0; p < 32; p += 4) {
      a0 += base[(size_t)(p0 + p + 0) * DIM];
      a1 += base[(size_t)(p0 + p + 1) * DIM];
      a2 += base[(size_t)(p0 + p + 2) * DIM];
      a3 += base[(size_t)(p0 + p + 3) * DIM];
    }
    part_am[pg][c] = (a0 + a1) + (a2 + a3);
  }
  __syncthreads();
  if (t < 80)
    am_s[t] = (part_am[0][t] + part_am[1][t] + part_am[2][t] + part_am[3][t]) * (1.f / 4256.f);
  __syncthreads();
  if (t < 256) {
    int n = t & 127, kh = t >> 7;      // 2 k-halves x 40
    int kbase = j * 80 + kh * 40;
    float acc = 0.f;
#pragma unroll 8
    for (int k = 0; k < 40; ++k)
      acc = fmaf(am_s[kh * 40 + k], W1[(size_t)(DIM + kbase + k) * 128 + n], acc);
    h1part[kh][n] = acc;
  }
  __syncthreads();
  if (t < 128) ws[OFF_H1PART + j * 128 + t] = h1part[0][t] + h1part[1][t];
}

// grid 32 x 128: per-way MLP tail
__global__ __launch_bounds__(128) void k_ctrl2(const float* __restrict__ b1,
                                               const float* __restrict__ W2, const float* __restrict__ b2,
                                               const float* __restrict__ W3, const float* __restrict__ b3,
                                               float* ws) {
  __shared__ float h1s[128];
  __shared__ float h2p[2][64];
  __shared__ float h2s[64], lg[5];
  int w = blockIdx.x, t = threadIdx.x;
  {
    float a = ws[OFF_H1P + w * 128 + t] + b1[t];
#pragma unroll
    for (int j = 0; j < 8; ++j) a += ws[OFF_H1PART + j * 128 + t];
    h1s[t] = fmaxf(a, 0.f);
  }
  __syncthreads();
  {
    int n = t & 63, kh = t >> 6;       // 2 k-halves x 64
    int k0 = kh * 64;
    float acc = 0.f;
#pragma unroll 8
    for (int k = 0; k < 64; ++k)
      acc = fmaf(h1s[k0 + k], W2[(size_t)(k0 + k) * 64 + n], acc);
    h2p[kh][n] = acc;
  }
  __syncthreads();
  if (t < 64) h2s[t] = fmaxf(h2p[0][t] + h2p[1][t] + b2[t], 0.f);
  __syncthreads();
  if (t < 5) {
    float acc = b3[t];
    for (int k = 0; k < 64; ++k) acc = fmaf(h2s[k], W3[k * 5 + t], acc);
    lg[t] = acc;
  }
  __syncthreads();
  if (t == 0) {
    double m = lg[0];
    for (int i = 1; i < 5; ++i) m = fmax(m, (double)lg[i]);
    double se = 0.0, cv = 0.0;
    for (int i = 0; i < 5; ++i) { double e = exp((double)lg[i] - m); se += e; cv += e * 0.2 * (double)(i + 1); }
    double c = cv / se;
    ws[OFF_C + w] = (float)c;
    double p2 = ((const double*)(ws + OFF_P2RAW))[w];
    double u2;
    double beta = expmap_scale(c, p2, &u2);
    ws[OFF_BETA + w] = (float)beta;
    ((double*)(ws + OFF_X2D))[w] = u2;
  }
}

#define GEMM_COMPUTE2(BUF)                                            \
  {                                                                   \
    const float* qr = &S[BUF][q][0];                                  \
    const float* x0r = &S[BUF][16 + w0][0];                           \
    const float* x1r = &S[BUF][16 + w1][0];                           \
    _Pragma("unroll")                                                 \
    for (int kk = 0; kk < 64; kk += 4) {                              \
      float4 qv = *(const float4*)(qr + kk);                          \
      float4 x0v = *(const float4*)(x0r + kk);                        \
      float4 x1v = *(const float4*)(x1r + kk);                       \
      c0x = fmaf(qv.x, x0v.x, c0x); c0y = fmaf(qv.y, x0v.y, c0y);     \
      c0z = fmaf(qv.z, x0v.z, c0z); c0w = fmaf(qv.w, x0v.w, c0w);     \
      c1x = fmaf(qv.x, x1v.x, c1x); c1y = fmaf(qv.y, x1v.y, c1y);     \
      c1z = fmaf(qv.z, x1v.z, c1z); c1w = fmaf(qv.w, x1v.w, c1w);     \
    }                                                                 \
  }

// grid 256 x 256: block = 16 q-rows x 32 ways; thread = (q = t&15, wpair = t>>4)
// computes outputs (q, 2*wp) and (q, 2*wp+1). Depth-2 register prefetch.
// mode 0: f32 dist epilogue -> DIS. mode 1: f64 dist -> out.
__global__ __launch_bounds__(256) void k_gemm(const float* __restrict__ X, const float* __restrict__ Qm,
                                              float* __restrict__ ws, int mode, float* __restrict__ out) {
  __shared__ float S[2][48][68];   // rows 0..15 = Q tile, rows 16..47 = X (32 ways)
  int t = threadIdx.x;
  int q0 = blockIdx.x * 16;
  int rr = t >> 4, qd = t & 15;    // staging: 3 slots/thread, rows rr, rr+16, rr+32
  const float* srcA = Qm + (size_t)(q0 + rr) * DIM + qd * 4;   // Q row rr
  const float* srcB = X + (size_t)rr * DIM + qd * 4;           // X row rr
  const float* srcC = X + (size_t)(rr + 16) * DIM + qd * 4;    // X row rr+16
  // stage chunk 0
  float4 a0 = *(const float4*)srcA;
  float4 a1 = *(const float4*)srcB;
  float4 a2 = *(const float4*)srcC;
  *(float4*)&S[0][rr][qd * 4] = a0;
  *(float4*)&S[0][16 + rr][qd * 4] = a1;
  *(float4*)&S[0][32 + rr][qd * 4] = a2;
  __syncthreads();
  // preload chunk 1 into set A
  a0 = *(const float4*)(srcA + 64);
  a1 = *(const float4*)(srcB + 64);
  a2 = *(const float4*)(srcC + 64);
  float4 b0 = {0.f,0.f,0.f,0.f}, b1 = b0, b2 = b0;
  int q = t & 15, wp = t >> 4;
  int w0 = wp * 2, w1 = wp * 2 + 1;
  float c0x = 0.f, c0y = 0.f, c0z = 0.f, c0w = 0.f;
  float c1x = 0.f, c1y = 0.f, c1z = 0.f, c1w = 0.f;
#pragma unroll
  for (int c = 0; c < 10; c += 2) {
    GEMM_COMPUTE2(0)
    if (c + 2 < 10) {
      size_t kc = (size_t)(c + 2) * 64;
      b0 = *(const float4*)(srcA + kc);
      b1 = *(const float4*)(srcB + kc);
      b2 = *(const float4*)(srcC + kc);
    }
    if (c + 1 < 10) {
      *(float4*)&S[1][rr][qd * 4] = a0;
      *(float4*)&S[1][16 + rr][qd * 4] = a1;
      *(float4*)&S[1][32 + rr][qd * 4] = a2;
      __syncthreads();
      GEMM_COMPUTE2(1)
      if (c + 3 < 10) {
        size_t kc = (size_t)(c + 3) * 64;
        a0 = *(const float4*)(srcA + kc);
        a1 = *(const float4*)(srcB + kc);
        a2 = *(const float4*)(srcC + kc);
      }
      if (c + 2 < 10) {
        *(float4*)&S[0][rr][qd * 4] = b0;
        *(float4*)&S[0][16 + rr][qd * 4] = b1;
        *(float4*)&S[0][32 + rr][qd * 4] = b2;
        __syncthreads();
      }
    }
  }
  float acc0 = (c0x + c0y) + (c0z + c0w);
  float acc1 = (c1x + c1y) + (c1z + c1w);
  int qq = q0 + q;
  const double* q2d = (const double*)(ws + OFF_Q2D);
  if (mode == 0) {
    const double* x2d = (const double*)(ws + OFF_X2D);
    float q2f = (float)q2d[qq];
    float d0 = dist_f32(ws[OFF_C + w0], ws[OFF_BETA + w0] * acc0, (float)x2d[w0], q2f);
    float d1 = dist_f32(ws[OFF_C + w1], ws[OFF_BETA + w1] * acc1, (float)x2d[w1], q2f);
    ws[OFF_G + (size_t)w0 * NQ + qq] = d0;
    ws[OFF_G + (size_t)w1 * NQ + qq] = d1;
  } else {
    const double* u2arr = (const double*)(ws + OFF_X2D2);
    double q2 = q2d[qq];
    double d0 = dist_hyp((double)ws[OFF_C + w0], (double)acc0, u2arr[w0], q2);
    double d1 = dist_hyp((double)ws[OFF_C + w1], (double)acc1, u2arr[w1], q2);
    out[(size_t)qq * WAY + w0] = (float)(-d0 / 16.0);
    out[(size_t)qq * WAY + w1] = (float)(-d1 / 16.0);
  }
}

// grid 32 x 1024: per-way top-10 + S/U + stats from precomputed DIS
__global__ __launch_bounds__(1024) void k_topkA(float* __restrict__ ws) {
  __shared__ double sredS[16], sredU[16];
  __shared__ float cval[160];
  __shared__ int cidx[160];
  __shared__ float qvsh[RNEAR];
  __shared__ int qjsh[RNEAR];
  __shared__ float colsh[RNEAR][33];
  __shared__ float pcpart[RNEAR];
  int w = blockIdx.x, t = threadIdx.x;
  int lane = t & 63, wid = t >> 6;
  int* nidx = (int*)(ws + OFF_NIDX);
  const float* gb = ws + OFF_G + (size_t)w * NQ;
  float v0 = gb[t], v1 = gb[1024 + t], v2 = gb[2048 + t], v3 = gb[3072 + t];
  unsigned tk = 0;
  double s = (double)v0 + (double)v1 + (double)v2 + (double)v3;
  double u = (t < RNEAR) ? (double)v0 : 0.0;
  s = wave_sum_d(s);
  u = wave_sum_d(u);
  if (lane == 0) { sredS[wid] = s; sredU[wid] = u; }
  for (int r = 0; r < RNEAR; ++r) {
    float lv = INFINITY; int li = 0x7fffffff;
    if (!(tk & 1u) && (v0 < lv || (v0 == lv && t < li)))        { lv = v0; li = t; }
    if (!(tk & 2u) && (v1 < lv || (v1 == lv && 1024 + t < li))) { lv = v1; li = 1024 + t; }
    if (!(tk & 4u) && (v2 < lv || (v2 == lv && 2048 + t < li))) { lv = v2; li = 2048 + t; }
    if (!(tk & 8u) && (v3 < lv || (v3 == lv && 3072 + t < li))) { lv = v3; li = 3072 + t; }
#pragma unroll
    for (int o = 32; o > 0; o >>= 1) {
      float ov = __shfl_xor(lv, o, 64);
      int oi = __shfl_xor(li, o, 64);
      if (ov < lv || (ov == lv && oi < li)) { lv = ov; li = oi; }
    }
    if (lane == 0) { cval[wid * RNEAR + r] = lv; cidx[wid * RNEAR + r] = li; }
    if ((li & 1023) == t) tk |= 1u << (li >> 10);
  }
  __syncthreads();
  if (t == 0) {
    double S = 0.0, U = 0.0;
    for (int k = 0; k < 16; ++k) { S += sredS[k]; U += sredU[k]; }
    ws[OFF_S + w] = (float)S;
    ws[OFF_U + w] = (float)U;
  }
  if (t < 64) {
    float c0 = cval[t], c1 = cval[t + 64];
    int i0 = cidx[t], i1 = cidx[t + 64];
    float c2 = (t < 32) ? cval[t + 128] : INFINITY;
    int i2 = (t < 32) ? cidx[t + 128] : 0x7fffffff;
    unsigned m = 0;
    for (int r = 0; r < RNEAR; ++r) {
      float lv = INFINITY; int li = 0x7fffffff;
      if (!(m & 1u) && (c0 < lv || (c0 == lv && i0 < li))) { lv = c0; li = i0; }
      if (!(m & 2u) && (c1 < lv || (c1 == lv && i1 < li))) { lv = c1; li = i1; }
      if (!(m & 4u) && (c2 < lv || (c2 == lv && i2 < li))) { lv = c2; li = i2; }
#pragma unroll
      for (int o = 32; o > 0; o >>= 1) {
        float ov = __shfl_xor(lv, o, 64);
        int oi = __shfl_xor(li, o, 64);
        if (ov < lv || (ov == lv && oi < li)) { lv = ov; li = oi; }
      }
      if (lane == 0) { qvsh[r] = lv; qjsh[r] = li; }
      if (i0 == li) m |= 1u;
      if (i1 == li) m |= 2u;
      if (i2 == li) m |= 4u;
    }
  }
  __syncthreads();
  if (t < WAY * RNEAR) {
    int j = t >> 5, w2 = t & 31;
    colsh[j][w2] = ws[OFF_G + (size_t)w2 * NQ + qjsh[j]];
  }
  __syncthreads();
  if (t < RNEAR) {
    double cs = 0.0, pc = 0.0;
    for (int w2 = 0; w2 < WAY; ++w2) {
      float dv = colsh[t][w2];
      cs += dv;
      if (w2 < w) pc += dv;
    }
    ws[OFF_RR + w * 22 + t] = qvsh[t];
    ws[OFF_RR + w * 22 + RNEAR + t] = (float)((cs - qvsh[t]) / (double)(WAY - 1));
    ws[OFF_NID + w * RNEAR + t] = qvsh[t];
    nidx[w * RNEAR + t] = qjsh[t];
    pcpart[t] = (float)pc;
  }
  __syncthreads();
  if (t == 0) {
    double spc = 0.0, sn = 0.0;
    for (int j = 0; j < RNEAR; ++j) { spc += pcpart[j]; sn += qvsh[j]; }
    double S = (double)ws[OFF_S + w];
    ws[OFF_RR + w * 22 + 20] = (float)((S - sn) / (double)(NQ - RNEAR));
    ws[OFF_SPC + w] = (float)spc;
  }
}

// grid 32 x 640: per-way refine MLP + tmp/expmap -> TP
__global__ __launch_bounds__(640) void k_refB(const float* __restrict__ Qm,
                                              const float* __restrict__ Wr1, const float* __restrict__ br1,
                                              const float* __restrict__ Wr2, const float* __restrict__ br2,
                                              float* __restrict__ ws) {
  __shared__ float Ssh[WAY], Ush[WAY];
  __shared__ float rrl[22];
  __shared__ int qj[RNEAR];
  __shared__ float hr[RNEAR], orsh[11], iw[RNEAR];
  __shared__ float onw_sh;
  __shared__ double p2red[10];
  __shared__ double gshd;
  int w = blockIdx.x, t = threadIdx.x;
  int lane = t & 63, wid = t >> 6;  // 10 waves
  const int* nidx = (const int*)(ws + OFF_NIDX);
  if (t < WAY) { Ssh[t] = ws[OFF_S + t]; Ush[t] = ws[OFF_U + t]; }
  if (t >= 64 && t < 64 + 22) rrl[t - 64] = ws[OFF_RR + w * 22 + (t - 64)];
  if (t >= 96 && t < 96 + RNEAR) qj[t - 96] = nidx[w * RNEAR + (t - 96)];
  __syncthreads();
  if (t == 0) {
    double pref = 0.0, suf = 0.0;
    for (int j = 0; j < w; ++j) pref += (double)Ssh[j];
    for (int j = w + 1; j < WAY; ++j) suf += (double)Ssh[j] - (double)Ush[j];
    double spc = (double)ws[OFF_SPC + w];
    rrl[21] = (float)((pref - spc + suf) / ((double)(WAY - 1) * (double)(NQ - RNEAR)));
  }
  __syncthreads();
  if (t < RNEAR) {
    float a = br1[t];
    for (int k = 0; k < 22; ++k) a = fmaf(rrl[k], Wr1[k * RNEAR + t], a);
    hr[t] = fmaxf(a, 0.f);
  }
  __syncthreads();
  if (t < 11) {
    float a = br2[t];
    for (int k = 0; k < RNEAR; ++k) a = fmaf(hr[k], Wr2[k * 11 + t], a);
    orsh[t] = a;
  }
  __syncthreads();
  if (t == 0) {
    double m = orsh[0];
    for (int i = 1; i < RNEAR; ++i) m = fmax(m, (double)orsh[i]);
    double se = 0.0; double e[RNEAR];
    for (int i = 0; i < RNEAR; ++i) { e[i] = exp((double)orsh[i] - m); se += e[i]; }
    for (int i = 0; i < RNEAR; ++i) iw[i] = (float)(e[i] / se);
    onw_sh = (float)(1.0 / (1.0 + exp(-(double)orsh[10])));
  }
  __syncthreads();
  float onwv = onw_sh;
  float wd = 0.f;
#pragma unroll
  for (int j = 0; j < RNEAR; ++j)
    wd = fmaf(Qm[(size_t)qj[j] * DIM + t], iw[j], wd);
  float a0 = ws[OFF_PROTOS + w * DIM + t] * onwv + wd * (1.f - onwv);
  double ls = (double)a0 * a0;
  ls = wave_sum_d(ls);
  if (lane == 0) p2red[wid] = ls;
  __syncthreads();
  if (t == 0) {
    double p2 = 0.0;
#pragma unroll
    for (int k = 0; k < 10; ++k) p2 += p2red[k];
    double u22;
    gshd = expmap_scale((double)ws[OFF_C + w], p2, &u22);
    ((double*)(ws + OFF_X2D2))[w] = u22;
  }
  __syncthreads();
  ws[OFF_TP + w * DIM + t] = (float)gshd * a0;
}

extern "C" void kernel_launch(void* const* d_in, const int* in_sizes, int n_in,
                              void* d_out, int out_size, void* d_ws, size_t ws_size,
                              hipStream_t stream) {
  (void)in_sizes; (void)n_in; (void)out_size; (void)ws_size;
  const float* shot = (const float*)d_in[0];
  const float* qry  = (const float*)d_in[1];
  const float* W1   = (const float*)d_in[2];
  const float* b1   = (const float*)d_in[3];
  const float* W2   = (const float*)d_in[4];
  const float* b2   = (const float*)d_in[5];
  const float* W3   = (const float*)d_in[6];
  const float* b3   = (const float*)d_in[7];
  const float* Wr1  = (const float*)d_in[8];
  const float* br1  = (const float*)d_in[9];
  const float* Wr2  = (const float*)d_in[10];
  const float* br2  = (const float*)d_in[11];
  float* ws = (float*)d_ws;
  float* out = (float*)d_out;

  hipLaunchKernelGGL(k_fuse1, dim3(128), dim3(640), 0, stream, qry, shot, W1, ws);
  hipLaunchKernelGGL(k_amw1,  dim3(8), dim3(320), 0, stream, W1, ws);
  hipLaunchKernelGGL(k_ctrl2, dim3(32), dim3(128), 0, stream, b1, W2, b2, W3, b3, ws);
  hipLaunchKernelGGL(k_gemm,  dim3(256), dim3(256), 0, stream, ws + OFF_PROTOS, qry, ws, 0, out);
  hipLaunchKernelGGL(k_topkA, dim3(32), dim3(1024), 0, stream, ws);
  hipLaunchKernelGGL(k_refB,  dim3(32), dim3(640), 0, stream, qry, Wr1, br1, Wr2, br2, ws);
  hipLaunchKernelGGL(k_gemm,  dim3(256), dim3(256), 0, stream, ws + OFF_TP, qry, ws, 1, out);
}